// Round 1
// baseline (2024.293 us; speedup 1.0000x reference)
//
#include <hip/hip_runtime.h>
#include <math.h>

// DirPNAConv: N=50000 nodes, E=800000 edges, D=64, T=4 towers, FI=FO=16.
// Algebra: m[e] = Q[recv] + P[send]  (pre-layer splits across the concat),
// so aggregations reduce to gather-stats of P plus per-node Q shift.

__global__ void k_count(const int* __restrict__ ei, int* cnt_dst, int* cnt_src, int nE) {
    int e = blockIdx.x * blockDim.x + threadIdx.x;
    if (e < nE) {
        int sN = ei[e];        // edge_index[0] = src
        int dN = ei[nE + e];   // edge_index[1] = dst
        atomicAdd(&cnt_dst[dN], 1);
        atomicAdd(&cnt_src[sN], 1);
    }
}

// Exclusive scan of two count arrays (block 0 -> a, block 1 -> b).
// Writes off[i]=excl, off[n]=total, and overwrites cnt[i]=excl (scatter cursor).
__global__ void k_scan(int* cnt_a, int* off_a, int* cnt_b, int* off_b, int n) {
    int* cnt = blockIdx.x ? cnt_b : cnt_a;
    int* off = blockIdx.x ? off_b : off_a;
    __shared__ int buf[1024];
    __shared__ int carry_s;
    if (threadIdx.x == 0) carry_s = 0;
    __syncthreads();
    for (int base = 0; base < n; base += 1024) {
        int i = base + threadIdx.x;
        int v = (i < n) ? cnt[i] : 0;
        buf[threadIdx.x] = v;
        __syncthreads();
        for (int ofs = 1; ofs < 1024; ofs <<= 1) {
            int tv = (threadIdx.x >= ofs) ? buf[threadIdx.x - ofs] : 0;
            __syncthreads();
            buf[threadIdx.x] += tv;
            __syncthreads();
        }
        int incl = buf[threadIdx.x];
        int carry = carry_s;
        if (i < n) { off[i] = carry + incl - v; cnt[i] = carry + incl - v; }
        __syncthreads();
        if (threadIdx.x == 1023) carry_s = carry + incl;
        __syncthreads();
    }
    if (threadIdx.x == 0) off[n] = carry_s;
}

__global__ void k_scatter(const int* __restrict__ ei, int* cur_dst, int* cur_src,
                          int* adj_dst, int* adj_src, int nE) {
    int e = blockIdx.x * blockDim.x + threadIdx.x;
    if (e < nE) {
        int sN = ei[e];
        int dN = ei[nE + e];
        int p = atomicAdd(&cur_dst[dN], 1);
        adj_dst[p] = sN;
        int q = atomicAdd(&cur_src[sN], 1);
        adj_src[q] = dN;
    }
}

// Per node: y_self = x@Wself + bself ; P1 = x@preW_s2d[:,16:32,:] ; P2 likewise d2s.
__global__ __launch_bounds__(256) void k_prep(
    const float* __restrict__ x, const float* __restrict__ Wself, const float* __restrict__ bself,
    const float* __restrict__ preW1, const float* __restrict__ preW2,
    float* __restrict__ out, float* __restrict__ P1, float* __restrict__ P2, int nN) {
    __shared__ float wl[64 * 64];
    int tid = threadIdx.x;
    for (int i = tid; i < 64 * 64; i += 256) wl[i] = Wself[i];
    __syncthreads();
    const int lane = tid & 63;
    const int t = lane >> 4, g = lane & 15;
    const int base = t << 4;
    float ws1[16], ws2[16];
#pragma unroll
    for (int f = 0; f < 16; ++f) {
        ws1[f] = preW1[t * 512 + (16 + f) * 16 + g];
        ws2[f] = preW2[t * 512 + (16 + f) * 16 + g];
    }
    const float bs = bself[lane];
    int node = (blockIdx.x * blockDim.x + tid) >> 6;
    int stride = (gridDim.x * blockDim.x) >> 6;
    for (; node < nN; node += stride) {
        float xv = x[node * 64 + lane];
        float ys = bs, p1 = 0.f, p2 = 0.f;
#pragma unroll
        for (int k = 0; k < 64; ++k)
            ys = fmaf(__shfl(xv, k, 64), wl[k * 64 + lane], ys);
#pragma unroll
        for (int f = 0; f < 16; ++f) {
            float v = __shfl(xv, base + f, 64);
            p1 = fmaf(v, ws1[f], p1);
            p2 = fmaf(v, ws2[f], p2);
        }
        out[node * 64 + lane] = ys;
        P1[node * 64 + lane] = p1;
        P2[node * 64 + lane] = p2;
    }
}

// One PNA direction: gather-aggregate P over CSR, Q on the fly, post layer with
// degree-scalers folded into weights, final lin, accumulate scale*y into out.
__global__ __launch_bounds__(256) void k_pna(
    const float* __restrict__ x, const float* __restrict__ P,
    const int* __restrict__ off, const int* __restrict__ adj,
    const float* __restrict__ preW, const float* __restrict__ preb,
    const float* __restrict__ postW, const float* __restrict__ postb,
    const float* __restrict__ linW, const float* __restrict__ linb,
    const float* __restrict__ alpha, int dir, float* __restrict__ out, int nN) {
    __shared__ float pw[208 * 64];  // [pos][t*16+g] : conflict-free reads
    int tid = threadIdx.x;
    for (int i = tid; i < 208 * 64; i += 256) {
        int pos = i >> 6; int l = i & 63; int tt = l >> 4; int gg = l & 15;
        pw[i] = postW[tt * 3328 + pos * 16 + gg];
    }
    __syncthreads();
    const int lane = tid & 63;
    const int t = lane >> 4, g = lane & 15;
    const int base = t << 4;
    float wr[16];
#pragma unroll
    for (int f = 0; f < 16; ++f) wr[f] = preW[t * 512 + f * 16 + g];
    const float pbq = preb[lane];
    const float pbv = postb[lane];
    const float lbv = linb[lane];
    const float a = alpha[0];
    const float scale = dir ? a : (1.0f - a);
    int node = (blockIdx.x * blockDim.x + tid) >> 6;
    int stride = (gridDim.x * blockDim.x) >> 6;
    for (; node < nN; node += stride) {
        const float xv = x[node * 64 + lane];
        float q = pbq;
#pragma unroll
        for (int f = 0; f < 16; ++f) q = fmaf(__shfl(xv, base + f, 64), wr[f], q);
        int beg = off[node], end = off[node + 1];
        int cnt = end - beg;
        float s = 0.f, ss = 0.f, mn = 3.0e38f, mx = -3.0e38f;
        for (int i = beg; i < end; ++i) {
            int nb = adj[i];
            float pv = P[nb * 64 + lane];
            s += pv;
            ss = fmaf(pv, pv, ss);
            mn = fminf(mn, pv);
            mx = fmaxf(mx, pv);
        }
        float deg = (cnt > 0) ? (float)cnt : 1.0f;
        float inv = 1.0f / deg;
        float meanP = s * inv;
        float stdv = sqrtf(fmaxf(ss * inv - meanP * meanP, 0.f) + 1e-5f);
        float mean, mnv, mxv;
        if (cnt > 0) { mean = q + meanP; mnv = q + mn; mxv = q + mx; }
        else { mean = 0.f; mnv = 0.f; mxv = 0.f; stdv = 3.1622776601e-3f; }
        float amp = logf(deg + 1.0f) / 2.8332133440562162f;  // / log(17)
        float ramp = 1.0f / amp;
        // post layer: pos = k*16+f ; k: 0=xt 1..4=agg 5..8=agg*amp 9..12=agg/amp
        float o = pbv;
#pragma unroll
        for (int f = 0; f < 16; ++f) {
            int sl = base + f;
            float xf = __shfl(xv, sl, 64);
            float b1 = __shfl(mean, sl, 64);
            float b2 = __shfl(mnv, sl, 64);
            float b3 = __shfl(mxv, sl, 64);
            float b4 = __shfl(stdv, sl, 64);
            o = fmaf(xf, pw[f * 64 + lane], o);
            float w1 = fmaf(amp, pw[(80 + f) * 64 + lane], pw[(16 + f) * 64 + lane]);
            w1 = fmaf(ramp, pw[(144 + f) * 64 + lane], w1);
            float w2 = fmaf(amp, pw[(96 + f) * 64 + lane], pw[(32 + f) * 64 + lane]);
            w2 = fmaf(ramp, pw[(160 + f) * 64 + lane], w2);
            float w3 = fmaf(amp, pw[(112 + f) * 64 + lane], pw[(48 + f) * 64 + lane]);
            w3 = fmaf(ramp, pw[(176 + f) * 64 + lane], w3);
            float w4 = fmaf(amp, pw[(128 + f) * 64 + lane], pw[(64 + f) * 64 + lane]);
            w4 = fmaf(ramp, pw[(192 + f) * 64 + lane], w4);
            o = fmaf(b1, w1, o);
            o = fmaf(b2, w2, o);
            o = fmaf(b3, w3, o);
            o = fmaf(b4, w4, o);
        }
        // final lin: y = o @ linW + linb (linW read through cache, coalesced)
        float y = lbv;
#pragma unroll
        for (int k = 0; k < 64; ++k)
            y = fmaf(__shfl(o, k, 64), linW[k * 64 + lane], y);
        out[node * 64 + lane] += scale * y;
    }
}

extern "C" void kernel_launch(void* const* d_in, const int* in_sizes, int n_in,
                              void* d_out, int out_size, void* d_ws, size_t ws_size,
                              hipStream_t stream) {
    const float* x      = (const float*)d_in[0];
    const int*   ei     = (const int*)d_in[1];
    const float* alpha  = (const float*)d_in[2];
    const float* Wself  = (const float*)d_in[3];
    const float* bself  = (const float*)d_in[4];
    const float* preW1  = (const float*)d_in[5];
    const float* preb1  = (const float*)d_in[6];
    const float* postW1 = (const float*)d_in[7];
    const float* postb1 = (const float*)d_in[8];
    const float* linW1  = (const float*)d_in[9];
    const float* linb1  = (const float*)d_in[10];
    const float* preW2  = (const float*)d_in[11];
    const float* preb2  = (const float*)d_in[12];
    const float* postW2 = (const float*)d_in[13];
    const float* postb2 = (const float*)d_in[14];
    const float* linW2  = (const float*)d_in[15];
    const float* linb2  = (const float*)d_in[16];
    float* out = (float*)d_out;
    const int nN = in_sizes[0] / 64;
    const int nE = in_sizes[1] / 2;

    char* w = (char*)d_ws;
    size_t ofs = 0;
    auto alloc = [&](size_t bytes) {
        char* p = w + ofs;
        ofs = (ofs + bytes + 255) & ~(size_t)255;
        return p;
    };
    float* P1      = (float*)alloc((size_t)nN * 64 * 4);
    float* P2      = (float*)alloc((size_t)nN * 64 * 4);
    int*   off_dst = (int*)alloc((size_t)(nN + 1) * 4);
    int*   off_src = (int*)alloc((size_t)(nN + 1) * 4);
    int*   cnt_dst = (int*)alloc((size_t)nN * 4);
    int*   cnt_src = (int*)alloc((size_t)nN * 4);
    int*   adj_dst = (int*)alloc((size_t)nE * 4);
    int*   adj_src = (int*)alloc((size_t)nE * 4);

    hipMemsetAsync(cnt_dst, 0, (size_t)nN * 4, stream);
    hipMemsetAsync(cnt_src, 0, (size_t)nN * 4, stream);

    int eb = (nE + 255) / 256;
    k_count<<<eb, 256, 0, stream>>>(ei, cnt_dst, cnt_src, nE);
    k_scan<<<2, 1024, 0, stream>>>(cnt_dst, off_dst, cnt_src, off_src, nN);
    k_scatter<<<eb, 256, 0, stream>>>(ei, cnt_dst, cnt_src, adj_dst, adj_src, nE);

    int nb = (nN + 3) / 4;  // 4 waves per block, one node per wave
    k_prep<<<nb, 256, 0, stream>>>(x, Wself, bself, preW1, preW2, out, P1, P2, nN);
    k_pna<<<nb, 256, 0, stream>>>(x, P1, off_dst, adj_dst, preW1, preb1, postW1, postb1,
                                  linW1, linb1, alpha, 0, out, nN);
    k_pna<<<nb, 256, 0, stream>>>(x, P2, off_src, adj_src, preW2, preb2, postW2, postb2,
                                  linW2, linb2, alpha, 1, out, nN);
}

// Round 2
// 1628.977 us; speedup vs baseline: 1.2427x; 1.2427x over previous
//
#include <hip/hip_runtime.h>
#include <math.h>

// DirPNAConv: N=50000 nodes, E=800000 edges, D=64, T=4 towers, FI=FO=16.
// Algebra: m[e] = Q[recv] + P[send]  (pre-layer splits across the concat),
// so aggregations reduce to gather-stats of P plus per-node Q shift.

__global__ void k_count(const int* __restrict__ ei, int* cnt_dst, int* cnt_src, int nE) {
    int e = blockIdx.x * blockDim.x + threadIdx.x;
    if (e < nE) {
        int sN = ei[e];        // edge_index[0] = src
        int dN = ei[nE + e];   // edge_index[1] = dst
        atomicAdd(&cnt_dst[dN], 1);
        atomicAdd(&cnt_src[sN], 1);
    }
}

// Exclusive scan of two count arrays (block 0 -> a, block 1 -> b), shfl-based.
__global__ __launch_bounds__(1024) void k_scan(int* cnt_a, int* off_a, int* cnt_b, int* off_b, int n) {
    int* cnt = blockIdx.x ? cnt_b : cnt_a;
    int* off = blockIdx.x ? off_b : off_a;
    __shared__ int wsum[16];
    __shared__ int carry_s;
    int tid = threadIdx.x;
    int lane = tid & 63, wid = tid >> 6;
    if (tid == 0) carry_s = 0;
    __syncthreads();
    for (int base = 0; base < n; base += 1024) {
        int i = base + tid;
        int v = (i < n) ? cnt[i] : 0;
        int s = v;
#pragma unroll
        for (int d = 1; d < 64; d <<= 1) {
            int t = __shfl_up(s, d, 64);
            if (lane >= d) s += t;
        }
        if (lane == 63) wsum[wid] = s;
        __syncthreads();
        if (wid == 0) {
            int ws = (lane < 16) ? wsum[lane] : 0;
#pragma unroll
            for (int d = 1; d < 16; d <<= 1) {
                int t = __shfl_up(ws, d, 64);
                if (lane >= d) ws += t;
            }
            if (lane < 16) wsum[lane] = ws;
        }
        __syncthreads();
        int wbase = (wid > 0) ? wsum[wid - 1] : 0;
        int carry = carry_s;
        if (i < n) { int excl = carry + wbase + s - v; off[i] = excl; cnt[i] = excl; }
        __syncthreads();
        if (tid == 0) carry_s = carry + wsum[15];
        __syncthreads();
    }
    if (threadIdx.x == 0) off[n] = carry_s;
}

__global__ void k_scatter(const int* __restrict__ ei, int* cur_dst, int* cur_src,
                          int* adj_dst, int* adj_src, int nE) {
    int e = blockIdx.x * blockDim.x + threadIdx.x;
    if (e < nE) {
        int sN = ei[e];
        int dN = ei[nE + e];
        int p = atomicAdd(&cur_dst[dN], 1);
        adj_dst[p] = sN;
        int q = atomicAdd(&cur_src[sN], 1);
        adj_src[q] = dN;
    }
}

// Per node: y_self = x@Wself + bself ; P1 = x@preW_s2d[:,16:32,:] ; P2 likewise d2s.
__global__ __launch_bounds__(512, 4) void k_prep(
    const float* __restrict__ x, const float* __restrict__ Wself, const float* __restrict__ bself,
    const float* __restrict__ preW1, const float* __restrict__ preW2,
    float* __restrict__ out, float* __restrict__ P1, float* __restrict__ P2, int nN) {
    __shared__ float wl[64 * 64];
    int tid = threadIdx.x;
    for (int i = tid; i < 64 * 64; i += 512) wl[i] = Wself[i];
    __syncthreads();
    const int lane = tid & 63;
    const int t = lane >> 4, g = lane & 15;
    const int base = t << 4;
    float ws1[16], ws2[16];
#pragma unroll
    for (int f = 0; f < 16; ++f) {
        ws1[f] = preW1[t * 512 + (16 + f) * 16 + g];
        ws2[f] = preW2[t * 512 + (16 + f) * 16 + g];
    }
    const float bs = bself[lane];
    int node = (blockIdx.x * blockDim.x + tid) >> 6;
    int stride = (gridDim.x * blockDim.x) >> 6;
    for (; node < nN; node += stride) {
        float xv = x[node * 64 + lane];
        float ys = bs, p1 = 0.f, p2 = 0.f;
#pragma unroll
        for (int k = 0; k < 64; ++k)
            ys = fmaf(__shfl(xv, k, 64), wl[k * 64 + lane], ys);
#pragma unroll
        for (int f = 0; f < 16; ++f) {
            float v = __shfl(xv, base + f, 64);
            p1 = fmaf(v, ws1[f], p1);
            p2 = fmaf(v, ws2[f], p2);
        }
        out[node * 64 + lane] = ys;
        P1[node * 64 + lane] = p1;
        P2[node * 64 + lane] = p2;
    }
}

// One PNA direction: gather-aggregate P over CSR (unroll-8, loads grouped),
// Q on the fly, post layer with degree-scalers folded into LDS weights,
// final lin from LDS, accumulate scale*y into out.
__global__ __launch_bounds__(512, 4) void k_pna(
    const float* __restrict__ x, const float* __restrict__ P,
    const int* __restrict__ off, const int* __restrict__ adj,
    const float* __restrict__ preW, const float* __restrict__ preb,
    const float* __restrict__ postW, const float* __restrict__ postb,
    const float* __restrict__ linW, const float* __restrict__ linb,
    const float* __restrict__ alpha, int dir, float* __restrict__ out, int nN) {
    // pw3[(f*13 + k)*64 + lane]: the 13 weights needed per f are 256B-spaced
    // (ds_read2-mergeable), lane-consecutive (bank-conflict-free).
    __shared__ float pw3[208 * 64];
    __shared__ float lw[64 * 64];
    int tid = threadIdx.x;
    for (int i = tid; i < 208 * 64; i += 512) {
        int row = i >> 6; int l = i & 63;
        int f = row / 13, k = row - f * 13;
        int tt = l >> 4, gg = l & 15;
        pw3[i] = postW[tt * 3328 + (k * 16 + f) * 16 + gg];
    }
    for (int i = tid; i < 64 * 64; i += 512) lw[i] = linW[i];
    __syncthreads();
    const int lane = tid & 63;
    const int t = lane >> 4, g = lane & 15;
    const int base = t << 4;
    float wr[16];
#pragma unroll
    for (int f = 0; f < 16; ++f) wr[f] = preW[t * 512 + f * 16 + g];
    const float pbq = preb[lane];
    const float pbv = postb[lane];
    const float lbv = linb[lane];
    const float a = alpha[0];
    const float scale = dir ? a : (1.0f - a);
    int node = (blockIdx.x * blockDim.x + tid) >> 6;
    int stride = (gridDim.x * blockDim.x) >> 6;
    for (; node < nN; node += stride) {
        const float xv = x[node * 64 + lane];
        float q = pbq;
#pragma unroll
        for (int f = 0; f < 16; ++f) q = fmaf(__shfl(xv, base + f, 64), wr[f], q);
        int beg = off[node], end = off[node + 1];
        int cnt = end - beg;
        float s = 0.f, ss = 0.f, mn = 3.0e38f, mx = -3.0e38f;
        int i = beg;
        for (; i + 8 <= end; i += 8) {
            int n0 = adj[i + 0], n1 = adj[i + 1], n2 = adj[i + 2], n3 = adj[i + 3];
            int n4 = adj[i + 4], n5 = adj[i + 5], n6 = adj[i + 6], n7 = adj[i + 7];
            float p0 = P[(size_t)n0 * 64 + lane];
            float p1 = P[(size_t)n1 * 64 + lane];
            float p2 = P[(size_t)n2 * 64 + lane];
            float p3 = P[(size_t)n3 * 64 + lane];
            float p4 = P[(size_t)n4 * 64 + lane];
            float p5 = P[(size_t)n5 * 64 + lane];
            float p6 = P[(size_t)n6 * 64 + lane];
            float p7 = P[(size_t)n7 * 64 + lane];
            s += ((p0 + p1) + (p2 + p3)) + ((p4 + p5) + (p6 + p7));
            ss = fmaf(p0, p0, ss); ss = fmaf(p1, p1, ss);
            ss = fmaf(p2, p2, ss); ss = fmaf(p3, p3, ss);
            ss = fmaf(p4, p4, ss); ss = fmaf(p5, p5, ss);
            ss = fmaf(p6, p6, ss); ss = fmaf(p7, p7, ss);
            mn = fminf(mn, fminf(fminf(p0, p1), fminf(p2, p3)));
            mn = fminf(mn, fminf(fminf(p4, p5), fminf(p6, p7)));
            mx = fmaxf(mx, fmaxf(fmaxf(p0, p1), fmaxf(p2, p3)));
            mx = fmaxf(mx, fmaxf(fmaxf(p4, p5), fmaxf(p6, p7)));
        }
        for (; i < end; ++i) {
            int nb = adj[i];
            float pv = P[(size_t)nb * 64 + lane];
            s += pv;
            ss = fmaf(pv, pv, ss);
            mn = fminf(mn, pv);
            mx = fmaxf(mx, pv);
        }
        float deg = (cnt > 0) ? (float)cnt : 1.0f;
        float inv = 1.0f / deg;
        float meanP = s * inv;
        float stdv = sqrtf(fmaxf(ss * inv - meanP * meanP, 0.f) + 1e-5f);
        float mean, mnv, mxv;
        if (cnt > 0) { mean = q + meanP; mnv = q + mn; mxv = q + mx; }
        else { mean = 0.f; mnv = 0.f; mxv = 0.f; stdv = 3.1622776601e-3f; }
        float amp = logf(deg + 1.0f) / 2.8332133440562162f;  // / log(17)
        float ramp = 1.0f / amp;
        float o = pbv;
#pragma unroll
        for (int f = 0; f < 16; ++f) {
            int sl = base + f;
            float xf = __shfl(xv, sl, 64);
            float b1 = __shfl(mean, sl, 64);
            float b2 = __shfl(mnv, sl, 64);
            float b3 = __shfl(mxv, sl, 64);
            float b4 = __shfl(stdv, sl, 64);
            const float* pwf = &pw3[(f * 13) * 64 + lane];
            o = fmaf(xf, pwf[0], o);
            float w1 = fmaf(amp, pwf[5 * 64], pwf[1 * 64]);
            w1 = fmaf(ramp, pwf[9 * 64], w1);
            float w2 = fmaf(amp, pwf[6 * 64], pwf[2 * 64]);
            w2 = fmaf(ramp, pwf[10 * 64], w2);
            float w3 = fmaf(amp, pwf[7 * 64], pwf[3 * 64]);
            w3 = fmaf(ramp, pwf[11 * 64], w3);
            float w4 = fmaf(amp, pwf[8 * 64], pwf[4 * 64]);
            w4 = fmaf(ramp, pwf[12 * 64], w4);
            o = fmaf(b1, w1, o);
            o = fmaf(b2, w2, o);
            o = fmaf(b3, w3, o);
            o = fmaf(b4, w4, o);
        }
        float y = lbv;
#pragma unroll
        for (int k = 0; k < 64; ++k)
            y = fmaf(__shfl(o, k, 64), lw[k * 64 + lane], y);
        out[node * 64 + lane] += scale * y;
    }
}

extern "C" void kernel_launch(void* const* d_in, const int* in_sizes, int n_in,
                              void* d_out, int out_size, void* d_ws, size_t ws_size,
                              hipStream_t stream) {
    const float* x      = (const float*)d_in[0];
    const int*   ei     = (const int*)d_in[1];
    const float* alpha  = (const float*)d_in[2];
    const float* Wself  = (const float*)d_in[3];
    const float* bself  = (const float*)d_in[4];
    const float* preW1  = (const float*)d_in[5];
    const float* preb1  = (const float*)d_in[6];
    const float* postW1 = (const float*)d_in[7];
    const float* postb1 = (const float*)d_in[8];
    const float* linW1  = (const float*)d_in[9];
    const float* linb1  = (const float*)d_in[10];
    const float* preW2  = (const float*)d_in[11];
    const float* preb2  = (const float*)d_in[12];
    const float* postW2 = (const float*)d_in[13];
    const float* postb2 = (const float*)d_in[14];
    const float* linW2  = (const float*)d_in[15];
    const float* linb2  = (const float*)d_in[16];
    float* out = (float*)d_out;
    const int nN = in_sizes[0] / 64;
    const int nE = in_sizes[1] / 2;

    char* w = (char*)d_ws;
    size_t ofs = 0;
    auto alloc = [&](size_t bytes) {
        char* p = w + ofs;
        ofs = (ofs + bytes + 255) & ~(size_t)255;
        return p;
    };
    float* P1      = (float*)alloc((size_t)nN * 64 * 4);
    float* P2      = (float*)alloc((size_t)nN * 64 * 4);
    int*   off_dst = (int*)alloc((size_t)(nN + 1) * 4);
    int*   off_src = (int*)alloc((size_t)(nN + 1) * 4);
    int*   cnt_dst = (int*)alloc((size_t)nN * 4);
    int*   cnt_src = (int*)alloc((size_t)nN * 4);
    int*   adj_dst = (int*)alloc((size_t)nE * 4);
    int*   adj_src = (int*)alloc((size_t)nE * 4);

    hipMemsetAsync(cnt_dst, 0, (size_t)nN * 4, stream);
    hipMemsetAsync(cnt_src, 0, (size_t)nN * 4, stream);

    int eb = (nE + 255) / 256;
    k_count<<<eb, 256, 0, stream>>>(ei, cnt_dst, cnt_src, nE);
    k_scan<<<2, 1024, 0, stream>>>(cnt_dst, off_dst, cnt_src, off_src, nN);
    k_scatter<<<eb, 256, 0, stream>>>(ei, cnt_dst, cnt_src, adj_dst, adj_src, nE);

    k_prep<<<1024, 512, 0, stream>>>(x, Wself, bself, preW1, preW2, out, P1, P2, nN);
    k_pna<<<512, 512, 0, stream>>>(x, P1, off_dst, adj_dst, preW1, preb1, postW1, postb1,
                                   linW1, linb1, alpha, 0, out, nN);
    k_pna<<<512, 512, 0, stream>>>(x, P2, off_src, adj_src, preW2, preb2, postW2, postb2,
                                   linW2, linb2, alpha, 1, out, nN);
}

// Round 3
// 502.597 us; speedup vs baseline: 4.0277x; 3.2411x over previous
//
#include <hip/hip_runtime.h>
#include <math.h>

// DirPNAConv: N=50000, E=800000, D=64, T=4, FI=FO=16.
// m[e] = Q[recv] + P[send]  ->  gather-stats of P + per-node Q shift.
// post and lin are linear: per dir y = x@Wx + agg@WA + amp*(agg@WB) + ramp*(agg@WE),
// then y_total = [o1,o2,x] @ Wfin (+bias), all via f16 MFMA. Weights are scatter
// copies of postW/linW (prepw kernel), no on-device weight folding GEMMs.

typedef _Float16 half_t;
typedef __attribute__((ext_vector_type(8))) _Float16 half8;
typedef __attribute__((ext_vector_type(4))) float f32x4;

__global__ void k_count(const int* __restrict__ ei, int* cnt_dst, int* cnt_src, int nE) {
    int e = blockIdx.x * blockDim.x + threadIdx.x;
    if (e < nE) {
        int sN = ei[e];        // edge_index[0] = src
        int dN = ei[nE + e];   // edge_index[1] = dst
        atomicAdd(&cnt_dst[dN], 1);
        atomicAdd(&cnt_src[sN], 1);
    }
}

__global__ __launch_bounds__(1024) void k_scan(int* cnt_a, int* off_a, int* cnt_b, int* off_b, int n) {
    int* cnt = blockIdx.x ? cnt_b : cnt_a;
    int* off = blockIdx.x ? off_b : off_a;
    __shared__ int wsum[16];
    __shared__ int carry_s;
    int tid = threadIdx.x;
    int lane = tid & 63, wid = tid >> 6;
    if (tid == 0) carry_s = 0;
    __syncthreads();
    for (int base = 0; base < n; base += 1024) {
        int i = base + tid;
        int v = (i < n) ? cnt[i] : 0;
        int s = v;
#pragma unroll
        for (int d = 1; d < 64; d <<= 1) {
            int t = __shfl_up(s, d, 64);
            if (lane >= d) s += t;
        }
        if (lane == 63) wsum[wid] = s;
        __syncthreads();
        if (wid == 0) {
            int ws = (lane < 16) ? wsum[lane] : 0;
#pragma unroll
            for (int d = 1; d < 16; d <<= 1) {
                int t = __shfl_up(ws, d, 64);
                if (lane >= d) ws += t;
            }
            if (lane < 16) wsum[lane] = ws;
        }
        __syncthreads();
        int wbase = (wid > 0) ? wsum[wid - 1] : 0;
        int carry = carry_s;
        if (i < n) { int excl = carry + wbase + s - v; off[i] = excl; cnt[i] = excl; }
        __syncthreads();
        if (tid == 0) carry_s = carry + wsum[15];
        __syncthreads();
    }
    if (threadIdx.x == 0) off[n] = carry_s;
}

__global__ void k_scatter(const int* __restrict__ ei, int* cur_dst, int* cur_src,
                          int* adj_dst, int* adj_src, int nE) {
    int e = blockIdx.x * blockDim.x + threadIdx.x;
    if (e < nE) {
        int sN = ei[e];
        int dN = ei[nE + e];
        int p = atomicAdd(&cur_dst[dN], 1);
        adj_dst[p] = sN;
        int q = atomicAdd(&cur_src[sN], 1);
        adj_src[q] = dN;
    }
}

// Scatter/copy weight prep: WA/WB/WE [64c][256k], Wx [64c][64k], Wfin [64c][192k], bfin.
__global__ __launch_bounds__(256) void k_prepw(
    const float* __restrict__ postW1, const float* __restrict__ postW2,
    const float* __restrict__ linW1, const float* __restrict__ linW2,
    const float* __restrict__ Wself, const float* __restrict__ bself,
    const float* __restrict__ linb1, const float* __restrict__ linb2,
    const float* __restrict__ alpha,
    half_t* WA1, half_t* WB1, half_t* WE1,
    half_t* WA2, half_t* WB2, half_t* WE2,
    half_t* Wx1, half_t* Wx2, half_t* Wfin, float* bfin) {
    const float a = alpha[0];
    int id = blockIdx.x * blockDim.x + threadIdx.x;
    int stride = gridDim.x * blockDim.x;
    for (int i = id; i < 6 * 16384; i += stride) {
        int m = i >> 14;
        int j = i & 16383;
        int c = j >> 8, k = j & 255;
        int t = c >> 4, go = c & 15;
        int t2 = k >> 6, stat = (k >> 4) & 3, g = k & 15;
        const float* pw = (m < 3) ? postW1 : postW2;
        int grp = m % 3;                       // 0=identity 1=amp 2=att
        int baseRow = (grp == 0) ? 1 : (grp == 1 ? 5 : 9);
        float v = (t2 == t) ? pw[t * 3328 + ((baseRow + stat) * 16 + g) * 16 + go] : 0.f;
        half_t* dst = (m == 0) ? WA1 : (m == 1) ? WB1 : (m == 2) ? WE1
                    : (m == 3) ? WA2 : (m == 4) ? WB2 : WE2;
        dst[j] = (half_t)v;
    }
    for (int i = id; i < 2 * 4096; i += stride) {
        int m = i >> 12; int j = i & 4095;
        int c = j >> 6, k = j & 63;
        int t = c >> 4, go = c & 15;
        int t2 = k >> 4, g = k & 15;
        const float* pw = m ? postW2 : postW1;
        float v = (t2 == t) ? pw[t * 3328 + g * 16 + go] : 0.f;
        (m ? Wx2 : Wx1)[j] = (half_t)v;
    }
    for (int i = id; i < 64 * 192; i += stride) {
        int c = i / 192, k = i - c * 192;
        float v;
        if (k < 64)       v = (1.f - a) * linW1[k * 64 + c];
        else if (k < 128) v = a * linW2[(k - 64) * 64 + c];
        else              v = Wself[(k - 128) * 64 + c];
        Wfin[i] = (half_t)v;
    }
    for (int i = id; i < 64; i += stride)
        bfin[i] = bself[i] + (1.f - a) * linb1[i] + a * linb2[i];
}

// P1 = x @ preW1[:,16:32,:], P2 likewise (f16 out).
__global__ __launch_bounds__(256) void k_prep(
    const float* __restrict__ x,
    const float* __restrict__ preW1, const float* __restrict__ preW2,
    half_t* __restrict__ P1, half_t* __restrict__ P2, int nN) {
    int tid = threadIdx.x;
    const int lane = tid & 63;
    const int t = lane >> 4, g = lane & 15;
    const int base = t << 4;
    float ws1[16], ws2[16];
#pragma unroll
    for (int f = 0; f < 16; ++f) {
        ws1[f] = preW1[t * 512 + (16 + f) * 16 + g];
        ws2[f] = preW2[t * 512 + (16 + f) * 16 + g];
    }
    int node = (blockIdx.x * blockDim.x + tid) >> 6;
    int stride = (gridDim.x * blockDim.x) >> 6;
    for (; node < nN; node += stride) {
        float xv = x[(size_t)node * 64 + lane];
        float p1 = 0.f, p2 = 0.f;
#pragma unroll
        for (int f = 0; f < 16; ++f) {
            float v = __shfl(xv, base + f, 64);
            p1 = fmaf(v, ws1[f], p1);
            p2 = fmaf(v, ws2[f], p2);
        }
        P1[(size_t)node * 64 + lane] = (half_t)p1;
        P2[(size_t)node * 64 + lane] = (half_t)p2;
    }
}

// Lean gather pass: both dirs per node. agg[n,256] = [mean|min|max|std] per tower (+Q).
__global__ __launch_bounds__(256) void k_gather(
    const float* __restrict__ x,
    const half_t* __restrict__ P1, const half_t* __restrict__ P2,
    const int* __restrict__ off1, const int* __restrict__ adj1,
    const int* __restrict__ off2, const int* __restrict__ adj2,
    const float* __restrict__ preW1, const float* __restrict__ preb1,
    const float* __restrict__ preW2, const float* __restrict__ preb2,
    half_t* __restrict__ agg1, half_t* __restrict__ agg2,
    float* __restrict__ amp1, float* __restrict__ ramp1,
    float* __restrict__ amp2, float* __restrict__ ramp2, int nN) {
    int tid = threadIdx.x;
    const int lane = tid & 63;
    const int t = lane >> 4, g = lane & 15;
    const int base = t << 4;
    float wr1[16], wr2[16];
#pragma unroll
    for (int f = 0; f < 16; ++f) {
        wr1[f] = preW1[t * 512 + f * 16 + g];
        wr2[f] = preW2[t * 512 + f * 16 + g];
    }
    const float pb1 = preb1[lane], pb2 = preb2[lane];
    int node = (blockIdx.x * blockDim.x + tid) >> 6;
    int stride = (gridDim.x * blockDim.x) >> 6;
    for (; node < nN; node += stride) {
        float xv = x[(size_t)node * 64 + lane];
        float q1 = pb1, q2 = pb2;
#pragma unroll
        for (int f = 0; f < 16; ++f) {
            float v = __shfl(xv, base + f, 64);
            q1 = fmaf(v, wr1[f], q1);
            q2 = fmaf(v, wr2[f], q2);
        }
#pragma unroll
        for (int d = 0; d < 2; ++d) {
            const int* off = d ? off2 : off1;
            const int* adj = d ? adj2 : adj1;
            const half_t* P = d ? P2 : P1;
            float q = d ? q2 : q1;
            int beg = off[node], end = off[node + 1];
            int cnt = end - beg;
            float s = 0.f, ss = 0.f, mn = 3.0e38f, mx = -3.0e38f;
            int i = beg;
            for (; i + 8 <= end; i += 8) {
                int n0 = adj[i + 0], n1 = adj[i + 1], n2 = adj[i + 2], n3 = adj[i + 3];
                int n4 = adj[i + 4], n5 = adj[i + 5], n6 = adj[i + 6], n7 = adj[i + 7];
                float p0 = (float)P[(size_t)n0 * 64 + lane];
                float p1 = (float)P[(size_t)n1 * 64 + lane];
                float p2 = (float)P[(size_t)n2 * 64 + lane];
                float p3 = (float)P[(size_t)n3 * 64 + lane];
                float p4 = (float)P[(size_t)n4 * 64 + lane];
                float p5 = (float)P[(size_t)n5 * 64 + lane];
                float p6 = (float)P[(size_t)n6 * 64 + lane];
                float p7 = (float)P[(size_t)n7 * 64 + lane];
                s += ((p0 + p1) + (p2 + p3)) + ((p4 + p5) + (p6 + p7));
                ss = fmaf(p0, p0, ss); ss = fmaf(p1, p1, ss);
                ss = fmaf(p2, p2, ss); ss = fmaf(p3, p3, ss);
                ss = fmaf(p4, p4, ss); ss = fmaf(p5, p5, ss);
                ss = fmaf(p6, p6, ss); ss = fmaf(p7, p7, ss);
                mn = fminf(mn, fminf(fminf(p0, p1), fminf(p2, p3)));
                mn = fminf(mn, fminf(fminf(p4, p5), fminf(p6, p7)));
                mx = fmaxf(mx, fmaxf(fmaxf(p0, p1), fmaxf(p2, p3)));
                mx = fmaxf(mx, fmaxf(fmaxf(p4, p5), fmaxf(p6, p7)));
            }
            for (; i < end; ++i) {
                int nb = adj[i];
                float pv = (float)P[(size_t)nb * 64 + lane];
                s += pv;
                ss = fmaf(pv, pv, ss);
                mn = fminf(mn, pv);
                mx = fmaxf(mx, pv);
            }
            float deg = (cnt > 0) ? (float)cnt : 1.0f;
            float inv = 1.0f / deg;
            float meanP = s * inv;
            float stdv = sqrtf(fmaxf(ss * inv - meanP * meanP, 0.f) + 1e-5f);
            float meanv = cnt ? (q + meanP) : 0.f;
            float mnv = cnt ? (q + mn) : 0.f;
            float mxv = cnt ? (q + mx) : 0.f;
            half_t* arow = (d ? agg2 : agg1) + (size_t)node * 256 + t * 64 + g;
            arow[0]  = (half_t)meanv;
            arow[16] = (half_t)mnv;
            arow[32] = (half_t)mxv;
            arow[48] = (half_t)stdv;
            if (lane == 0) {
                float ampv = logf(deg + 1.0f) / 2.8332133440562162f;  // log(17)
                (d ? amp2 : amp1)[node] = ampv;
                (d ? ramp2 : ramp1)[node] = 1.0f / ampv;
            }
        }
    }
}

// MFMA pass: per wave 16 nodes. Phase1 (per dir): o = agg@WA + amp*(agg@WB)
// + ramp*(agg@WE) + x@Wx + postb -> LDS(f16). Phase2: y = [o1,o2,x]@Wfin + bfin.
__global__ __launch_bounds__(256) void k_c(
    const float* __restrict__ x,
    const half_t* __restrict__ agg1, const half_t* __restrict__ agg2,
    const float* __restrict__ amp1, const float* __restrict__ ramp1,
    const float* __restrict__ amp2, const float* __restrict__ ramp2,
    const half_t* __restrict__ WA1, const half_t* __restrict__ WB1, const half_t* __restrict__ WE1,
    const half_t* __restrict__ WA2, const half_t* __restrict__ WB2, const half_t* __restrict__ WE2,
    const half_t* __restrict__ Wx1, const half_t* __restrict__ Wx2,
    const half_t* __restrict__ Wfin, const float* __restrict__ bfin,
    const float* __restrict__ postb1, const float* __restrict__ postb2,
    float* __restrict__ out, int nN) {
    __shared__ half_t lds_o[64 * 136];  // stride 136 halves = 272B (16B-aligned, bank-spread)
    int tid = threadIdx.x;
    int w = tid >> 6, lane = tid & 63;
    int l15 = lane & 15, g4 = lane >> 4;
    int tb = blockIdx.x * 64 + w * 16;
    int arow = tb + l15;
    int arowc = (arow < nN) ? arow : (nN - 1);
    // x fragments (A-layout: row=l15, k=(g4*8..+8)+ks*32), reused in both phases
    half8 xf[2];
#pragma unroll
    for (int ks = 0; ks < 2; ++ks) {
        const float4* xp = (const float4*)(x + (size_t)arowc * 64 + ks * 32 + g4 * 8);
        float4 x0 = xp[0], x1 = xp[1];
        half8 h;
        h[0] = (half_t)x0.x; h[1] = (half_t)x0.y; h[2] = (half_t)x0.z; h[3] = (half_t)x0.w;
        h[4] = (half_t)x1.x; h[5] = (half_t)x1.y; h[6] = (half_t)x1.z; h[7] = (half_t)x1.w;
        xf[ks] = h;
    }
#pragma unroll
    for (int d = 0; d < 2; ++d) {
        const half_t* agg = d ? agg2 : agg1;
        const half_t* WA = d ? WA2 : WA1;
        const half_t* WB = d ? WB2 : WB1;
        const half_t* WE = d ? WE2 : WE1;
        const half_t* Wx = d ? Wx2 : Wx1;
        const float* ampd = d ? amp2 : amp1;
        const float* rampd = d ? ramp2 : ramp1;
        const float* pbd = d ? postb2 : postb1;
        f32x4 accA[4] = {{0,0,0,0},{0,0,0,0},{0,0,0,0},{0,0,0,0}};
        f32x4 accB[4] = {{0,0,0,0},{0,0,0,0},{0,0,0,0},{0,0,0,0}};
        f32x4 accE[4] = {{0,0,0,0},{0,0,0,0},{0,0,0,0},{0,0,0,0}};
        for (int ks = 0; ks < 8; ++ks) {
            half8 af = *(const half8*)(agg + (size_t)arowc * 256 + ks * 32 + g4 * 8);
#pragma unroll
            for (int ct = 0; ct < 4; ++ct) {
                half8 bA = *(const half8*)(WA + (ct * 16 + l15) * 256 + ks * 32 + g4 * 8);
                half8 bB = *(const half8*)(WB + (ct * 16 + l15) * 256 + ks * 32 + g4 * 8);
                half8 bE = *(const half8*)(WE + (ct * 16 + l15) * 256 + ks * 32 + g4 * 8);
                accA[ct] = __builtin_amdgcn_mfma_f32_16x16x32_f16(af, bA, accA[ct], 0, 0, 0);
                accB[ct] = __builtin_amdgcn_mfma_f32_16x16x32_f16(af, bB, accB[ct], 0, 0, 0);
                accE[ct] = __builtin_amdgcn_mfma_f32_16x16x32_f16(af, bE, accE[ct], 0, 0, 0);
            }
        }
#pragma unroll
        for (int ks = 0; ks < 2; ++ks) {
#pragma unroll
            for (int ct = 0; ct < 4; ++ct) {
                half8 bX = *(const half8*)(Wx + (ct * 16 + l15) * 64 + ks * 32 + g4 * 8);
                accA[ct] = __builtin_amdgcn_mfma_f32_16x16x32_f16(xf[ks], bX, accA[ct], 0, 0, 0);
            }
        }
        float ampv[4], rampv[4];
#pragma unroll
        for (int r = 0; r < 4; ++r) {
            int nrow = tb + g4 * 4 + r;
            if (nrow >= nN) nrow = nN - 1;
            ampv[r] = ampd[nrow];
            rampv[r] = rampd[nrow];
        }
#pragma unroll
        for (int ct = 0; ct < 4; ++ct) {
            float pb = pbd[ct * 16 + l15];
#pragma unroll
            for (int r = 0; r < 4; ++r) {
                float o = accA[ct][r] + ampv[r] * accB[ct][r] + rampv[r] * accE[ct][r] + pb;
                lds_o[(w * 16 + g4 * 4 + r) * 136 + d * 64 + ct * 16 + l15] = (half_t)o;
            }
        }
    }
    __syncthreads();
    f32x4 accY[4] = {{0,0,0,0},{0,0,0,0},{0,0,0,0},{0,0,0,0}};
    for (int ks = 0; ks < 4; ++ks) {
        half8 af = *(const half8*)(&lds_o[(w * 16 + l15) * 136 + ks * 32 + g4 * 8]);
#pragma unroll
        for (int ct = 0; ct < 4; ++ct) {
            half8 bf = *(const half8*)(Wfin + (ct * 16 + l15) * 192 + ks * 32 + g4 * 8);
            accY[ct] = __builtin_amdgcn_mfma_f32_16x16x32_f16(af, bf, accY[ct], 0, 0, 0);
        }
    }
#pragma unroll
    for (int ks = 0; ks < 2; ++ks) {
#pragma unroll
        for (int ct = 0; ct < 4; ++ct) {
            half8 bf = *(const half8*)(Wfin + (ct * 16 + l15) * 192 + 128 + ks * 32 + g4 * 8);
            accY[ct] = __builtin_amdgcn_mfma_f32_16x16x32_f16(xf[ks], bf, accY[ct], 0, 0, 0);
        }
    }
#pragma unroll
    for (int ct = 0; ct < 4; ++ct) {
        float bv = bfin[ct * 16 + l15];
#pragma unroll
        for (int r = 0; r < 4; ++r) {
            int nrow = tb + g4 * 4 + r;
            if (nrow < nN) out[(size_t)nrow * 64 + ct * 16 + l15] = accY[ct][r] + bv;
        }
    }
}

extern "C" void kernel_launch(void* const* d_in, const int* in_sizes, int n_in,
                              void* d_out, int out_size, void* d_ws, size_t ws_size,
                              hipStream_t stream) {
    const float* x      = (const float*)d_in[0];
    const int*   ei     = (const int*)d_in[1];
    const float* alpha  = (const float*)d_in[2];
    const float* Wself  = (const float*)d_in[3];
    const float* bself  = (const float*)d_in[4];
    const float* preW1  = (const float*)d_in[5];
    const float* preb1  = (const float*)d_in[6];
    const float* postW1 = (const float*)d_in[7];
    const float* postb1 = (const float*)d_in[8];
    const float* linW1  = (const float*)d_in[9];
    const float* linb1  = (const float*)d_in[10];
    const float* preW2  = (const float*)d_in[11];
    const float* preb2  = (const float*)d_in[12];
    const float* postW2 = (const float*)d_in[13];
    const float* postb2 = (const float*)d_in[14];
    const float* linW2  = (const float*)d_in[15];
    const float* linb2  = (const float*)d_in[16];
    float* out = (float*)d_out;
    const int nN = in_sizes[0] / 64;
    const int nE = in_sizes[1] / 2;

    char* w = (char*)d_ws;
    size_t ofs = 0;
    auto alloc = [&](size_t bytes) {
        char* p = w + ofs;
        ofs = (ofs + bytes + 255) & ~(size_t)255;
        return p;
    };
    half_t* P1   = (half_t*)alloc((size_t)nN * 64 * 2);
    half_t* P2   = (half_t*)alloc((size_t)nN * 64 * 2);
    half_t* agg1 = (half_t*)alloc((size_t)nN * 256 * 2);
    half_t* agg2 = (half_t*)alloc((size_t)nN * 256 * 2);
    float* amp1  = (float*)alloc((size_t)nN * 4);
    float* ramp1 = (float*)alloc((size_t)nN * 4);
    float* amp2  = (float*)alloc((size_t)nN * 4);
    float* ramp2 = (float*)alloc((size_t)nN * 4);
    half_t* WA1  = (half_t*)alloc(16384 * 2);
    half_t* WB1  = (half_t*)alloc(16384 * 2);
    half_t* WE1  = (half_t*)alloc(16384 * 2);
    half_t* WA2  = (half_t*)alloc(16384 * 2);
    half_t* WB2  = (half_t*)alloc(16384 * 2);
    half_t* WE2  = (half_t*)alloc(16384 * 2);
    half_t* Wx1  = (half_t*)alloc(4096 * 2);
    half_t* Wx2  = (half_t*)alloc(4096 * 2);
    half_t* Wfin = (half_t*)alloc(12288 * 2);
    float* bfin  = (float*)alloc(64 * 4);
    int* off_dst = (int*)alloc((size_t)(nN + 1) * 4);
    int* off_src = (int*)alloc((size_t)(nN + 1) * 4);
    int* cnt_dst = (int*)alloc((size_t)nN * 4);
    int* cnt_src = (int*)alloc((size_t)nN * 4);
    int* adj_dst = (int*)alloc((size_t)nE * 4);
    int* adj_src = (int*)alloc((size_t)nE * 4);

    hipMemsetAsync(cnt_dst, 0, (size_t)nN * 4, stream);
    hipMemsetAsync(cnt_src, 0, (size_t)nN * 4, stream);

    int eb = (nE + 255) / 256;
    k_count<<<eb, 256, 0, stream>>>(ei, cnt_dst, cnt_src, nE);
    k_scan<<<2, 1024, 0, stream>>>(cnt_dst, off_dst, cnt_src, off_src, nN);
    k_scatter<<<eb, 256, 0, stream>>>(ei, cnt_dst, cnt_src, adj_dst, adj_src, nE);

    k_prepw<<<128, 256, 0, stream>>>(postW1, postW2, linW1, linW2, Wself, bself,
                                     linb1, linb2, alpha,
                                     WA1, WB1, WE1, WA2, WB2, WE2, Wx1, Wx2, Wfin, bfin);
    k_prep<<<1024, 256, 0, stream>>>(x, preW1, preW2, P1, P2, nN);
    k_gather<<<2048, 256, 0, stream>>>(x, P1, P2, off_dst, adj_dst, off_src, adj_src,
                                       preW1, preb1, preW2, preb2,
                                       agg1, agg2, amp1, ramp1, amp2, ramp2, nN);
    k_c<<<(nN + 63) / 64, 256, 0, stream>>>(x, agg1, agg2, amp1, ramp1, amp2, ramp2,
                                            WA1, WB1, WE1, WA2, WB2, WE2, Wx1, Wx2,
                                            Wfin, bfin, postb1, postb2, out, nN);
}

// Round 4
// 421.990 us; speedup vs baseline: 4.7970x; 1.1910x over previous
//
#include <hip/hip_runtime.h>
#include <math.h>

// DirPNAConv: N=50000, E=800000, D=64, T=4, FI=FO=16.
// m[e] = Q[recv] + P[send] -> gather-stats of P + per-node Q shift.
// post/lin are linear: per dir y = x@Wx + agg@WA + amp*(agg@WB) + ramp*(agg@WE),
// then y = [o1,o2,x]@Wfin + bfin via f16 MFMA.
// Graph build uses XCD-ownership (blockIdx&7 owns a node range) so cnt atomics
// and adj writes stay XCD-L2-local; adj stored as ushort (N < 65536).

typedef _Float16 half_t;
typedef __attribute__((ext_vector_type(8))) _Float16 half8;
typedef __attribute__((ext_vector_type(2))) _Float16 half2v;
typedef __attribute__((ext_vector_type(4))) float f32x4;

// ---- fused: XCD-ownership edge count | weight prep | P projection ----
__global__ __launch_bounds__(256) void k_phase1(
    const int* __restrict__ ei, int nE, int nN,
    int* __restrict__ cnt_dst, int* __restrict__ cnt_src,
    const float* __restrict__ postW1, const float* __restrict__ postW2,
    const float* __restrict__ linW1, const float* __restrict__ linW2,
    const float* __restrict__ Wself, const float* __restrict__ bself,
    const float* __restrict__ linb1, const float* __restrict__ linb2,
    const float* __restrict__ alpha,
    half_t* WA1, half_t* WB1, half_t* WE1,
    half_t* WA2, half_t* WB2, half_t* WE2,
    half_t* Wx1, half_t* Wx2, half_t* Wfin, float* bfin,
    const float* __restrict__ x,
    const float* __restrict__ preW1, const float* __restrict__ preW2,
    half_t* __restrict__ P1, half_t* __restrict__ P2) {
    int tid = threadIdx.x;
    int b = blockIdx.x;
    if (b < 1024) {
        // ---- edge count with XCD ownership ----
        int group = b & 7;
        int gblk = b >> 3;
        int rs = (nN + 7) >> 3;
        int lo = group * rs;
        int hi = lo + rs; if (hi > nN) hi = nN;
        unsigned range = (unsigned)(hi - lo);
        int nquad = (nE + 3) >> 2;
        for (int qi = gblk * 256 + tid; qi < nquad; qi += 128 * 256) {
            int e = qi << 2;
            if (e + 4 <= nE) {
                int4 sv = *reinterpret_cast<const int4*>(ei + e);
                int4 dv = *reinterpret_cast<const int4*>(ei + nE + e);
                int ss[4] = {sv.x, sv.y, sv.z, sv.w};
                int dd[4] = {dv.x, dv.y, dv.z, dv.w};
#pragma unroll
                for (int k = 0; k < 4; ++k) {
                    if ((unsigned)(dd[k] - lo) < range) atomicAdd(&cnt_dst[dd[k]], 1);
                    if ((unsigned)(ss[k] - lo) < range) atomicAdd(&cnt_src[ss[k]], 1);
                }
            } else {
                for (int k = 0; k < 4 && e + k < nE; ++k) {
                    int s = ei[e + k], d2 = ei[nE + e + k];
                    if ((unsigned)(d2 - lo) < range) atomicAdd(&cnt_dst[d2], 1);
                    if ((unsigned)(s - lo) < range) atomicAdd(&cnt_src[s], 1);
                }
            }
        }
    } else if (b < 1152) {
        // ---- weight prep ----
        const float a = alpha[0];
        int id = (b - 1024) * 256 + tid;
        const int stride = 128 * 256;
        for (int i = id; i < 6 * 16384; i += stride) {
            int m = i >> 14;
            int j = i & 16383;
            int c = j >> 8, k = j & 255;
            int t = c >> 4, go = c & 15;
            int t2 = k >> 6, stat = (k >> 4) & 3, g = k & 15;
            const float* pw = (m < 3) ? postW1 : postW2;
            int grp = m % 3;  // 0=identity 1=amp 2=att
            int baseRow = (grp == 0) ? 1 : (grp == 1 ? 5 : 9);
            float v = (t2 == t) ? pw[t * 3328 + ((baseRow + stat) * 16 + g) * 16 + go] : 0.f;
            half_t* dst = (m == 0) ? WA1 : (m == 1) ? WB1 : (m == 2) ? WE1
                        : (m == 3) ? WA2 : (m == 4) ? WB2 : WE2;
            dst[j] = (half_t)v;
        }
        for (int i = id; i < 2 * 4096; i += stride) {
            int m = i >> 12; int j = i & 4095;
            int c = j >> 6, k = j & 63;
            int t = c >> 4, go = c & 15;
            int t2 = k >> 4, g = k & 15;
            const float* pw = m ? postW2 : postW1;
            float v = (t2 == t) ? pw[t * 3328 + g * 16 + go] : 0.f;
            (m ? Wx2 : Wx1)[j] = (half_t)v;
        }
        for (int i = id; i < 64 * 192; i += stride) {
            int c = i / 192, k = i - c * 192;
            float v;
            if (k < 64)       v = (1.f - a) * linW1[k * 64 + c];
            else if (k < 128) v = a * linW2[(k - 64) * 64 + c];
            else              v = Wself[(k - 128) * 64 + c];
            Wfin[i] = (half_t)v;
        }
        for (int i = id; i < 64; i += stride)
            bfin[i] = bself[i] + (1.f - a) * linb1[i] + a * linb2[i];
    } else {
        // ---- P projection: P = x @ preW[:,16:32,:] ----
        int vb = b - 1152;
        const int lane = tid & 63;
        const int t = lane >> 4, g = lane & 15;
        const int base = t << 4;
        float ws1[16], ws2[16];
#pragma unroll
        for (int f = 0; f < 16; ++f) {
            ws1[f] = preW1[t * 512 + (16 + f) * 16 + g];
            ws2[f] = preW2[t * 512 + (16 + f) * 16 + g];
        }
        int node = (vb * 256 + tid) >> 6;
        const int stride = (1024 * 256) >> 6;
        for (; node < nN; node += stride) {
            float xv = x[(size_t)node * 64 + lane];
            float p1 = 0.f, p2 = 0.f;
#pragma unroll
            for (int f = 0; f < 16; ++f) {
                float v = __shfl(xv, base + f, 64);
                p1 = fmaf(v, ws1[f], p1);
                p2 = fmaf(v, ws2[f], p2);
            }
            P1[(size_t)node * 64 + lane] = (half_t)p1;
            P2[(size_t)node * 64 + lane] = (half_t)p2;
        }
    }
}

__global__ __launch_bounds__(1024) void k_scan(int* cnt_a, int* off_a, int* cnt_b, int* off_b, int n) {
    int* cnt = blockIdx.x ? cnt_b : cnt_a;
    int* off = blockIdx.x ? off_b : off_a;
    __shared__ int wsum[16];
    __shared__ int carry_s;
    int tid = threadIdx.x;
    int lane = tid & 63, wid = tid >> 6;
    if (tid == 0) carry_s = 0;
    __syncthreads();
    for (int base = 0; base < n; base += 1024) {
        int i = base + tid;
        int v = (i < n) ? cnt[i] : 0;
        int s = v;
#pragma unroll
        for (int d = 1; d < 64; d <<= 1) {
            int t = __shfl_up(s, d, 64);
            if (lane >= d) s += t;
        }
        if (lane == 63) wsum[wid] = s;
        __syncthreads();
        if (wid == 0) {
            int ws = (lane < 16) ? wsum[lane] : 0;
#pragma unroll
            for (int d = 1; d < 16; d <<= 1) {
                int t = __shfl_up(ws, d, 64);
                if (lane >= d) ws += t;
            }
            if (lane < 16) wsum[lane] = ws;
        }
        __syncthreads();
        int wbase = (wid > 0) ? wsum[wid - 1] : 0;
        int carry = carry_s;
        if (i < n) { int excl = carry + wbase + s - v; off[i] = excl; cnt[i] = excl; }
        __syncthreads();
        if (tid == 0) carry_s = carry + wsum[15];
        __syncthreads();
    }
    if (threadIdx.x == 0) off[n] = carry_s;
}

// XCD-ownership scatter: cursor atomics + ushort adj writes stay L2-local.
__global__ __launch_bounds__(256) void k_scatter(
    const int* __restrict__ ei, int nE, int nN,
    int* __restrict__ cur_dst, int* __restrict__ cur_src,
    unsigned short* __restrict__ adj_dst, unsigned short* __restrict__ adj_src) {
    int tid = threadIdx.x;
    int group = blockIdx.x & 7;
    int gblk = blockIdx.x >> 3;
    int rs = (nN + 7) >> 3;
    int lo = group * rs;
    int hi = lo + rs; if (hi > nN) hi = nN;
    unsigned range = (unsigned)(hi - lo);
    int nquad = (nE + 3) >> 2;
    for (int qi = gblk * 256 + tid; qi < nquad; qi += 128 * 256) {
        int e = qi << 2;
        if (e + 4 <= nE) {
            int4 sv = *reinterpret_cast<const int4*>(ei + e);
            int4 dv = *reinterpret_cast<const int4*>(ei + nE + e);
            int ss[4] = {sv.x, sv.y, sv.z, sv.w};
            int dd[4] = {dv.x, dv.y, dv.z, dv.w};
#pragma unroll
            for (int k = 0; k < 4; ++k) {
                if ((unsigned)(dd[k] - lo) < range) {
                    int p = atomicAdd(&cur_dst[dd[k]], 1);
                    adj_dst[p] = (unsigned short)ss[k];
                }
                if ((unsigned)(ss[k] - lo) < range) {
                    int p = atomicAdd(&cur_src[ss[k]], 1);
                    adj_src[p] = (unsigned short)dd[k];
                }
            }
        } else {
            for (int k = 0; k < 4 && e + k < nE; ++k) {
                int s = ei[e + k], d2 = ei[nE + e + k];
                if ((unsigned)(d2 - lo) < range) {
                    int p = atomicAdd(&cur_dst[d2], 1);
                    adj_dst[p] = (unsigned short)s;
                }
                if ((unsigned)(s - lo) < range) {
                    int p = atomicAdd(&cur_src[s], 1);
                    adj_src[p] = (unsigned short)d2;
                }
            }
        }
    }
}

// Paired gather: lanes 0-31 handle even neighbors, 32-63 odd; each lane loads
// half2 (4B) -> full 256B per wave instruction; combine halves via shfl_xor(32).
__global__ __launch_bounds__(256) void k_gather(
    const float* __restrict__ x,
    const half_t* __restrict__ P1, const half_t* __restrict__ P2,
    const int* __restrict__ off1, const unsigned short* __restrict__ adj1,
    const int* __restrict__ off2, const unsigned short* __restrict__ adj2,
    const float* __restrict__ preW1, const float* __restrict__ preb1,
    const float* __restrict__ preW2, const float* __restrict__ preb2,
    half_t* __restrict__ agg1, half_t* __restrict__ agg2,
    float* __restrict__ amp1, float* __restrict__ ramp1,
    float* __restrict__ amp2, float* __restrict__ ramp2, int nN) {
    int tid = threadIdx.x;
    const int lane = tid & 63;
    const int t = lane >> 4, g = lane & 15;
    const int base = t << 4;
    const int half_id = lane >> 5;
    const int fl = lane & 31;
    float wr1[16], wr2[16];
#pragma unroll
    for (int f = 0; f < 16; ++f) {
        wr1[f] = preW1[t * 512 + f * 16 + g];
        wr2[f] = preW2[t * 512 + f * 16 + g];
    }
    const float pb1 = preb1[lane], pb2 = preb2[lane];
    int node = (blockIdx.x * blockDim.x + tid) >> 6;
    int stride = (gridDim.x * blockDim.x) >> 6;
    for (; node < nN; node += stride) {
        float xv = x[(size_t)node * 64 + lane];
        float q1 = pb1, q2 = pb2;
#pragma unroll
        for (int f = 0; f < 16; ++f) {
            float v = __shfl(xv, base + f, 64);
            q1 = fmaf(v, wr1[f], q1);
            q2 = fmaf(v, wr2[f], q2);
        }
#pragma unroll
        for (int d = 0; d < 2; ++d) {
            const int* off = d ? off2 : off1;
            const unsigned short* adj = d ? adj2 : adj1;
            const half_t* P = d ? P2 : P1;
            float q = d ? q2 : q1;
            int beg = off[node], end = off[node + 1];
            int cnt = end - beg;
            float s0 = 0.f, s1 = 0.f, ss0 = 0.f, ss1 = 0.f;
            float mn0 = 3.0e38f, mn1 = 3.0e38f, mx0 = -3.0e38f, mx1 = -3.0e38f;
            int j = beg;
            for (; j + 8 <= end; j += 8) {
                int n0 = adj[j + 0 + half_id];
                int n1 = adj[j + 2 + half_id];
                int n2 = adj[j + 4 + half_id];
                int n3 = adj[j + 6 + half_id];
                half2v h0 = *(const half2v*)(P + (size_t)n0 * 64 + (fl << 1));
                half2v h1 = *(const half2v*)(P + (size_t)n1 * 64 + (fl << 1));
                half2v h2 = *(const half2v*)(P + (size_t)n2 * 64 + (fl << 1));
                half2v h3 = *(const half2v*)(P + (size_t)n3 * 64 + (fl << 1));
                float a0 = (float)h0[0], b0 = (float)h0[1];
                float a1 = (float)h1[0], b1 = (float)h1[1];
                float a2 = (float)h2[0], b2 = (float)h2[1];
                float a3 = (float)h3[0], b3 = (float)h3[1];
                s0 += (a0 + a1) + (a2 + a3);
                s1 += (b0 + b1) + (b2 + b3);
                ss0 = fmaf(a0, a0, ss0); ss0 = fmaf(a1, a1, ss0);
                ss0 = fmaf(a2, a2, ss0); ss0 = fmaf(a3, a3, ss0);
                ss1 = fmaf(b0, b0, ss1); ss1 = fmaf(b1, b1, ss1);
                ss1 = fmaf(b2, b2, ss1); ss1 = fmaf(b3, b3, ss1);
                mn0 = fminf(mn0, fminf(fminf(a0, a1), fminf(a2, a3)));
                mn1 = fminf(mn1, fminf(fminf(b0, b1), fminf(b2, b3)));
                mx0 = fmaxf(mx0, fmaxf(fmaxf(a0, a1), fmaxf(a2, a3)));
                mx1 = fmaxf(mx1, fmaxf(fmaxf(b0, b1), fmaxf(b2, b3)));
            }
            for (; j < end; j += 2) {
                int idx = j + half_id;
                if (idx < end) {
                    int n0 = adj[idx];
                    half2v h0 = *(const half2v*)(P + (size_t)n0 * 64 + (fl << 1));
                    float a0 = (float)h0[0], b0 = (float)h0[1];
                    s0 += a0; s1 += b0;
                    ss0 = fmaf(a0, a0, ss0); ss1 = fmaf(b0, b0, ss1);
                    mn0 = fminf(mn0, a0); mn1 = fminf(mn1, b0);
                    mx0 = fmaxf(mx0, a0); mx1 = fmaxf(mx1, b0);
                }
            }
            // combine the two neighbor-halves
            s0 += __shfl_xor(s0, 32, 64);  s1 += __shfl_xor(s1, 32, 64);
            ss0 += __shfl_xor(ss0, 32, 64); ss1 += __shfl_xor(ss1, 32, 64);
            mn0 = fminf(mn0, __shfl_xor(mn0, 32, 64));
            mn1 = fminf(mn1, __shfl_xor(mn1, 32, 64));
            mx0 = fmaxf(mx0, __shfl_xor(mx0, 32, 64));
            mx1 = fmaxf(mx1, __shfl_xor(mx1, 32, 64));
            float deg = (cnt > 0) ? (float)cnt : 1.0f;
            float inv = 1.0f / deg;
            float qa = __shfl(q, fl * 2, 64);
            float qb = __shfl(q, fl * 2 + 1, 64);
            float mean0 = s0 * inv, mean1 = s1 * inv;
            float std0 = sqrtf(fmaxf(ss0 * inv - mean0 * mean0, 0.f) + 1e-5f);
            float std1 = sqrtf(fmaxf(ss1 * inv - mean1 * mean1, 0.f) + 1e-5f);
            float m0, m1, l0, l1, h0v, h1v;
            if (cnt > 0) {
                m0 = qa + mean0; m1 = qb + mean1;
                l0 = qa + mn0;   l1 = qb + mn1;
                h0v = qa + mx0;  h1v = qb + mx1;
            } else {
                m0 = m1 = l0 = l1 = h0v = h1v = 0.f;
                std0 = std1 = 3.1622776601e-3f;
            }
            if (lane < 32) {
                int f0 = fl << 1;
                int tt = f0 >> 4, gg = f0 & 15;
                half_t* arow = (d ? agg2 : agg1) + (size_t)node * 256 + tt * 64 + gg;
                half2v hm; hm[0] = (half_t)m0;  hm[1] = (half_t)m1;
                half2v hl; hl[0] = (half_t)l0;  hl[1] = (half_t)l1;
                half2v hh; hh[0] = (half_t)h0v; hh[1] = (half_t)h1v;
                half2v hs; hs[0] = (half_t)std0; hs[1] = (half_t)std1;
                *(half2v*)(arow + 0)  = hm;
                *(half2v*)(arow + 16) = hl;
                *(half2v*)(arow + 32) = hh;
                *(half2v*)(arow + 48) = hs;
            }
            if (lane == 0) {
                float ampv = logf(deg + 1.0f) / 2.8332133440562162f;  // log(17)
                (d ? amp2 : amp1)[node] = ampv;
                (d ? ramp2 : ramp1)[node] = 1.0f / ampv;
            }
        }
    }
}

// MFMA pass: per wave 16 nodes. Phase1 (per dir): o = agg@WA + amp*(agg@WB)
// + ramp*(agg@WE) + x@Wx + postb -> LDS(f16). Phase2: y = [o1,o2,x]@Wfin + bfin.
__global__ __launch_bounds__(256) void k_c(
    const float* __restrict__ x,
    const half_t* __restrict__ agg1, const half_t* __restrict__ agg2,
    const float* __restrict__ amp1, const float* __restrict__ ramp1,
    const float* __restrict__ amp2, const float* __restrict__ ramp2,
    const half_t* __restrict__ WA1, const half_t* __restrict__ WB1, const half_t* __restrict__ WE1,
    const half_t* __restrict__ WA2, const half_t* __restrict__ WB2, const half_t* __restrict__ WE2,
    const half_t* __restrict__ Wx1, const half_t* __restrict__ Wx2,
    const half_t* __restrict__ Wfin, const float* __restrict__ bfin,
    const float* __restrict__ postb1, const float* __restrict__ postb2,
    float* __restrict__ out, int nN) {
    __shared__ half_t lds_o[64 * 136];
    int tid = threadIdx.x;
    int w = tid >> 6, lane = tid & 63;
    int l15 = lane & 15, g4 = lane >> 4;
    int tb = blockIdx.x * 64 + w * 16;
    int arow = tb + l15;
    int arowc = (arow < nN) ? arow : (nN - 1);
    half8 xf[2];
#pragma unroll
    for (int ks = 0; ks < 2; ++ks) {
        const float4* xp = (const float4*)(x + (size_t)arowc * 64 + ks * 32 + g4 * 8);
        float4 x0 = xp[0], x1 = xp[1];
        half8 h;
        h[0] = (half_t)x0.x; h[1] = (half_t)x0.y; h[2] = (half_t)x0.z; h[3] = (half_t)x0.w;
        h[4] = (half_t)x1.x; h[5] = (half_t)x1.y; h[6] = (half_t)x1.z; h[7] = (half_t)x1.w;
        xf[ks] = h;
    }
#pragma unroll
    for (int d = 0; d < 2; ++d) {
        const half_t* agg = d ? agg2 : agg1;
        const half_t* WA = d ? WA2 : WA1;
        const half_t* WB = d ? WB2 : WB1;
        const half_t* WE = d ? WE2 : WE1;
        const half_t* Wx = d ? Wx2 : Wx1;
        const float* ampd = d ? amp2 : amp1;
        const float* rampd = d ? ramp2 : ramp1;
        const float* pbd = d ? postb2 : postb1;
        f32x4 accA[4] = {{0,0,0,0},{0,0,0,0},{0,0,0,0},{0,0,0,0}};
        f32x4 accB[4] = {{0,0,0,0},{0,0,0,0},{0,0,0,0},{0,0,0,0}};
        f32x4 accE[4] = {{0,0,0,0},{0,0,0,0},{0,0,0,0},{0,0,0,0}};
        for (int ks = 0; ks < 8; ++ks) {
            half8 af = *(const half8*)(agg + (size_t)arowc * 256 + ks * 32 + g4 * 8);
#pragma unroll
            for (int ct = 0; ct < 4; ++ct) {
                half8 bA = *(const half8*)(WA + (ct * 16 + l15) * 256 + ks * 32 + g4 * 8);
                half8 bB = *(const half8*)(WB + (ct * 16 + l15) * 256 + ks * 32 + g4 * 8);
                half8 bE = *(const half8*)(WE + (ct * 16 + l15) * 256 + ks * 32 + g4 * 8);
                accA[ct] = __builtin_amdgcn_mfma_f32_16x16x32_f16(af, bA, accA[ct], 0, 0, 0);
                accB[ct] = __builtin_amdgcn_mfma_f32_16x16x32_f16(af, bB, accB[ct], 0, 0, 0);
                accE[ct] = __builtin_amdgcn_mfma_f32_16x16x32_f16(af, bE, accE[ct], 0, 0, 0);
            }
        }
#pragma unroll
        for (int ks = 0; ks < 2; ++ks) {
#pragma unroll
            for (int ct = 0; ct < 4; ++ct) {
                half8 bX = *(const half8*)(Wx + (ct * 16 + l15) * 64 + ks * 32 + g4 * 8);
                accA[ct] = __builtin_amdgcn_mfma_f32_16x16x32_f16(xf[ks], bX, accA[ct], 0, 0, 0);
            }
        }
        float ampv[4], rampv[4];
#pragma unroll
        for (int r = 0; r < 4; ++r) {
            int nrow = tb + g4 * 4 + r;
            if (nrow >= nN) nrow = nN - 1;
            ampv[r] = ampd[nrow];
            rampv[r] = rampd[nrow];
        }
#pragma unroll
        for (int ct = 0; ct < 4; ++ct) {
            float pb = pbd[ct * 16 + l15];
#pragma unroll
            for (int r = 0; r < 4; ++r) {
                float o = accA[ct][r] + ampv[r] * accB[ct][r] + rampv[r] * accE[ct][r] + pb;
                lds_o[(w * 16 + g4 * 4 + r) * 136 + d * 64 + ct * 16 + l15] = (half_t)o;
            }
        }
    }
    __syncthreads();
    f32x4 accY[4] = {{0,0,0,0},{0,0,0,0},{0,0,0,0},{0,0,0,0}};
    for (int ks = 0; ks < 4; ++ks) {
        half8 af = *(const half8*)(&lds_o[(w * 16 + l15) * 136 + ks * 32 + g4 * 8]);
#pragma unroll
        for (int ct = 0; ct < 4; ++ct) {
            half8 bf = *(const half8*)(Wfin + (ct * 16 + l15) * 192 + ks * 32 + g4 * 8);
            accY[ct] = __builtin_amdgcn_mfma_f32_16x16x32_f16(af, bf, accY[ct], 0, 0, 0);
        }
    }
#pragma unroll
    for (int ks = 0; ks < 2; ++ks) {
#pragma unroll
        for (int ct = 0; ct < 4; ++ct) {
            half8 bf = *(const half8*)(Wfin + (ct * 16 + l15) * 192 + 128 + ks * 32 + g4 * 8);
            accY[ct] = __builtin_amdgcn_mfma_f32_16x16x32_f16(xf[ks], bf, accY[ct], 0, 0, 0);
        }
    }
#pragma unroll
    for (int ct = 0; ct < 4; ++ct) {
        float bv = bfin[ct * 16 + l15];
#pragma unroll
        for (int r = 0; r < 4; ++r) {
            int nrow = tb + g4 * 4 + r;
            if (nrow < nN) out[(size_t)nrow * 64 + ct * 16 + l15] = accY[ct][r] + bv;
        }
    }
}

extern "C" void kernel_launch(void* const* d_in, const int* in_sizes, int n_in,
                              void* d_out, int out_size, void* d_ws, size_t ws_size,
                              hipStream_t stream) {
    const float* x      = (const float*)d_in[0];
    const int*   ei     = (const int*)d_in[1];
    const float* alpha  = (const float*)d_in[2];
    const float* Wself  = (const float*)d_in[3];
    const float* bself  = (const float*)d_in[4];
    const float* preW1  = (const float*)d_in[5];
    const float* preb1  = (const float*)d_in[6];
    const float* postW1 = (const float*)d_in[7];
    const float* postb1 = (const float*)d_in[8];
    const float* linW1  = (const float*)d_in[9];
    const float* linb1  = (const float*)d_in[10];
    const float* preW2  = (const float*)d_in[11];
    const float* preb2  = (const float*)d_in[12];
    const float* postW2 = (const float*)d_in[13];
    const float* postb2 = (const float*)d_in[14];
    const float* linW2  = (const float*)d_in[15];
    const float* linb2  = (const float*)d_in[16];
    float* out = (float*)d_out;
    const int nN = in_sizes[0] / 64;
    const int nE = in_sizes[1] / 2;

    char* w = (char*)d_ws;
    size_t ofs = 0;
    auto alloc = [&](size_t bytes) {
        char* p = w + ofs;
        ofs = (ofs + bytes + 255) & ~(size_t)255;
        return p;
    };
    half_t* P1   = (half_t*)alloc((size_t)nN * 64 * 2);
    half_t* P2   = (half_t*)alloc((size_t)nN * 64 * 2);
    half_t* agg1 = (half_t*)alloc((size_t)nN * 256 * 2);
    half_t* agg2 = (half_t*)alloc((size_t)nN * 256 * 2);
    float* amp1  = (float*)alloc((size_t)nN * 4);
    float* ramp1 = (float*)alloc((size_t)nN * 4);
    float* amp2  = (float*)alloc((size_t)nN * 4);
    float* ramp2 = (float*)alloc((size_t)nN * 4);
    half_t* WA1  = (half_t*)alloc(16384 * 2);
    half_t* WB1  = (half_t*)alloc(16384 * 2);
    half_t* WE1  = (half_t*)alloc(16384 * 2);
    half_t* WA2  = (half_t*)alloc(16384 * 2);
    half_t* WB2  = (half_t*)alloc(16384 * 2);
    half_t* WE2  = (half_t*)alloc(16384 * 2);
    half_t* Wx1  = (half_t*)alloc(4096 * 2);
    half_t* Wx2  = (half_t*)alloc(4096 * 2);
    half_t* Wfin = (half_t*)alloc(12288 * 2);
    float* bfin  = (float*)alloc(64 * 4);
    int* off_dst = (int*)alloc((size_t)(nN + 1) * 4);
    int* off_src = (int*)alloc((size_t)(nN + 1) * 4);
    int* cnt_dst = (int*)alloc((size_t)nN * 4);
    int* cnt_src = (int*)alloc((size_t)nN * 4);
    unsigned short* adj_dst = (unsigned short*)alloc((size_t)nE * 2);
    unsigned short* adj_src = (unsigned short*)alloc((size_t)nE * 2);

    hipMemsetAsync(cnt_dst, 0, (size_t)nN * 4, stream);
    hipMemsetAsync(cnt_src, 0, (size_t)nN * 4, stream);

    k_phase1<<<2176, 256, 0, stream>>>(ei, nE, nN, cnt_dst, cnt_src,
                                       postW1, postW2, linW1, linW2, Wself, bself,
                                       linb1, linb2, alpha,
                                       WA1, WB1, WE1, WA2, WB2, WE2, Wx1, Wx2, Wfin, bfin,
                                       x, preW1, preW2, P1, P2);
    k_scan<<<2, 1024, 0, stream>>>(cnt_dst, off_dst, cnt_src, off_src, nN);
    k_scatter<<<1024, 256, 0, stream>>>(ei, nE, nN, cnt_dst, cnt_src, adj_dst, adj_src);
    k_gather<<<2048, 256, 0, stream>>>(x, P1, P2, off_dst, adj_dst, off_src, adj_src,
                                       preW1, preb1, preW2, preb2,
                                       agg1, agg2, amp1, ramp1, amp2, ramp2, nN);
    k_c<<<(nN + 63) / 64, 256, 0, stream>>>(x, agg1, agg2, amp1, ramp1, amp2, ramp2,
                                            WA1, WB1, WE1, WA2, WB2, WE2, Wx1, Wx2,
                                            Wfin, bfin, postb1, postb2, out, nN);
}

// Round 5
// 346.762 us; speedup vs baseline: 5.8377x; 1.2169x over previous
//
#include <hip/hip_runtime.h>
#include <math.h>

// DirPNAConv: N=50000, E=800000, D=64, T=4, FI=FO=16.
// m[e] = Q[recv] + P[send] -> gather-stats of P + per-node Q shift.
// Tower block-diagonality: post layer = per-tower K=64 GEMMs (A/B/E mats);
// x@Wx and postb are folded through lin into Wfin/bfin (prepw).
// k_c computes o^T = W @ agg^T per tower (swapped operands: amp/ramp are
// per-lane scalars), bounces o^T via wave-private LDS, then y^T = Wfin^T@[o1,o2,x]^T.

typedef _Float16 half_t;
typedef __attribute__((ext_vector_type(8))) _Float16 half8;
typedef __attribute__((ext_vector_type(2))) _Float16 half2v;
typedef __attribute__((ext_vector_type(4))) float f32x4;

// ---- fused: XCD-ownership edge count | weight prep | P projection ----
__global__ __launch_bounds__(256) void k_phase1(
    const int* __restrict__ ei, int nE, int nN,
    int* __restrict__ cnt_dst, int* __restrict__ cnt_src,
    const float* __restrict__ postW1, const float* __restrict__ postW2,
    const float* __restrict__ linW1, const float* __restrict__ linW2,
    const float* __restrict__ Wself, const float* __restrict__ bself,
    const float* __restrict__ linb1, const float* __restrict__ linb2,
    const float* __restrict__ postb1, const float* __restrict__ postb2,
    const float* __restrict__ alpha,
    half_t* __restrict__ WLg, half_t* __restrict__ WfinTg, float* __restrict__ bfin,
    const float* __restrict__ x,
    const float* __restrict__ preW1, const float* __restrict__ preW2,
    half_t* __restrict__ P1, half_t* __restrict__ P2) {
    int tid = threadIdx.x;
    int b = blockIdx.x;
    if (b < 1024) {
        // ---- edge count with XCD ownership ----
        int group = b & 7;
        int gblk = b >> 3;
        int rs = (nN + 7) >> 3;
        int lo = group * rs;
        int hi = lo + rs; if (hi > nN) hi = nN;
        unsigned range = (unsigned)(hi - lo);
        int nquad = (nE + 3) >> 2;
        for (int qi = gblk * 256 + tid; qi < nquad; qi += 128 * 256) {
            int e = qi << 2;
            if (e + 4 <= nE) {
                int4 sv = *reinterpret_cast<const int4*>(ei + e);
                int4 dv = *reinterpret_cast<const int4*>(ei + nE + e);
                int ss[4] = {sv.x, sv.y, sv.z, sv.w};
                int dd[4] = {dv.x, dv.y, dv.z, dv.w};
#pragma unroll
                for (int k = 0; k < 4; ++k) {
                    if ((unsigned)(dd[k] - lo) < range) atomicAdd(&cnt_dst[dd[k]], 1);
                    if ((unsigned)(ss[k] - lo) < range) atomicAdd(&cnt_src[ss[k]], 1);
                }
            } else {
                for (int k = 0; k < 4 && e + k < nE; ++k) {
                    int s = ei[e + k], d2 = ei[nE + e + k];
                    if ((unsigned)(d2 - lo) < range) atomicAdd(&cnt_dst[d2], 1);
                    if ((unsigned)(s - lo) < range) atomicAdd(&cnt_src[s], 1);
                }
            }
        }
    } else if (b < 1152) {
        // ---- weight prep ----
        const float a = alpha[0];
        int id = (b - 1024) * 256 + tid;
        const int stride = 128 * 256;
        // WL[m][go][k72]: m = d*12 + t*3 + mat (mat: 0=id,1=amp,2=att), k = stat*16+g
        for (int i = id; i < 24 * 16 * 72; i += stride) {
            int m = i / (16 * 72);
            int r = i % (16 * 72);
            int go = r / 72, k = r % 72;
            int d = m / 12, t = (m / 3) % 4, mat = m % 3;
            float v = 0.f;
            if (k < 64) {
                int stat = k >> 4, g = k & 15;
                int basep = (mat == 0) ? 1 : (mat == 1 ? 5 : 9);
                const float* pw = d ? postW2 : postW1;
                v = pw[t * 3328 + ((basep + stat) * 16 + g) * 16 + go];
            }
            WLg[i] = (half_t)v;
        }
        // WfinT[out][k=192]: k<64 o1, k<128 o2, k<192 x-block (Wself + Wx@lin folds)
        for (int i = id; i < 64 * 192; i += stride) {
            int o = i / 192, k = i % 192;
            float v;
            if (k < 64)       v = (1.f - a) * linW1[k * 64 + o];
            else if (k < 128) v = a * linW2[(k - 64) * 64 + o];
            else {
                int kx = k - 128, t = kx >> 4, f = kx & 15;
                v = Wself[kx * 64 + o];
                float s1 = 0.f, s2 = 0.f;
                for (int go = 0; go < 16; ++go) {
                    s1 += postW1[t * 3328 + f * 16 + go] * linW1[(t * 16 + go) * 64 + o];
                    s2 += postW2[t * 3328 + f * 16 + go] * linW2[(t * 16 + go) * 64 + o];
                }
                v += (1.f - a) * s1 + a * s2;
            }
            WfinTg[i] = (half_t)v;
        }
        // bfin = bself + (1-a)(linb1 + postb1@linW1) + a(linb2 + postb2@linW2)
        for (int i = id; i < 64; i += stride) {
            float v = bself[i] + (1.f - a) * linb1[i] + a * linb2[i];
            for (int j = 0; j < 64; ++j)
                v += (1.f - a) * postb1[j] * linW1[j * 64 + i]
                   + a * postb2[j] * linW2[j * 64 + i];
            bfin[i] = v;
        }
    } else {
        // ---- P projection: P = x @ preW[:,16:32,:] ----
        int vb = b - 1152;
        const int lane = tid & 63;
        const int t = lane >> 4, g = lane & 15;
        const int base = t << 4;
        float ws1[16], ws2[16];
#pragma unroll
        for (int f = 0; f < 16; ++f) {
            ws1[f] = preW1[t * 512 + (16 + f) * 16 + g];
            ws2[f] = preW2[t * 512 + (16 + f) * 16 + g];
        }
        int node = (vb * 256 + tid) >> 6;
        const int stride = (1024 * 256) >> 6;
        for (; node < nN; node += stride) {
            float xv = x[(size_t)node * 64 + lane];
            float p1 = 0.f, p2 = 0.f;
#pragma unroll
            for (int f = 0; f < 16; ++f) {
                float v = __shfl(xv, base + f, 64);
                p1 = fmaf(v, ws1[f], p1);
                p2 = fmaf(v, ws2[f], p2);
            }
            P1[(size_t)node * 64 + lane] = (half_t)p1;
            P2[(size_t)node * 64 + lane] = (half_t)p2;
        }
    }
}

__global__ __launch_bounds__(1024) void k_scan(int* cnt_a, int* off_a, int* cnt_b, int* off_b, int n) {
    int* cnt = blockIdx.x ? cnt_b : cnt_a;
    int* off = blockIdx.x ? off_b : off_a;
    __shared__ int wsum[16];
    __shared__ int carry_s;
    int tid = threadIdx.x;
    int lane = tid & 63, wid = tid >> 6;
    if (tid == 0) carry_s = 0;
    __syncthreads();
    for (int base = 0; base < n; base += 1024) {
        int i = base + tid;
        int v = (i < n) ? cnt[i] : 0;
        int s = v;
#pragma unroll
        for (int d = 1; d < 64; d <<= 1) {
            int t = __shfl_up(s, d, 64);
            if (lane >= d) s += t;
        }
        if (lane == 63) wsum[wid] = s;
        __syncthreads();
        if (wid == 0) {
            int ws = (lane < 16) ? wsum[lane] : 0;
#pragma unroll
            for (int d = 1; d < 16; d <<= 1) {
                int t = __shfl_up(ws, d, 64);
                if (lane >= d) ws += t;
            }
            if (lane < 16) wsum[lane] = ws;
        }
        __syncthreads();
        int wbase = (wid > 0) ? wsum[wid - 1] : 0;
        int carry = carry_s;
        if (i < n) { int excl = carry + wbase + s - v; off[i] = excl; cnt[i] = excl; }
        __syncthreads();
        if (tid == 0) carry_s = carry + wsum[15];
        __syncthreads();
    }
    if (threadIdx.x == 0) off[n] = carry_s;
}

// XCD-ownership scatter: cursor atomics + ushort adj writes stay L2-local.
__global__ __launch_bounds__(256) void k_scatter(
    const int* __restrict__ ei, int nE, int nN,
    int* __restrict__ cur_dst, int* __restrict__ cur_src,
    unsigned short* __restrict__ adj_dst, unsigned short* __restrict__ adj_src) {
    int tid = threadIdx.x;
    int group = blockIdx.x & 7;
    int gblk = blockIdx.x >> 3;
    int rs = (nN + 7) >> 3;
    int lo = group * rs;
    int hi = lo + rs; if (hi > nN) hi = nN;
    unsigned range = (unsigned)(hi - lo);
    int nquad = (nE + 3) >> 2;
    for (int qi = gblk * 256 + tid; qi < nquad; qi += 128 * 256) {
        int e = qi << 2;
        if (e + 4 <= nE) {
            int4 sv = *reinterpret_cast<const int4*>(ei + e);
            int4 dv = *reinterpret_cast<const int4*>(ei + nE + e);
            int ss[4] = {sv.x, sv.y, sv.z, sv.w};
            int dd[4] = {dv.x, dv.y, dv.z, dv.w};
#pragma unroll
            for (int k = 0; k < 4; ++k) {
                if ((unsigned)(dd[k] - lo) < range) {
                    int p = atomicAdd(&cur_dst[dd[k]], 1);
                    adj_dst[p] = (unsigned short)ss[k];
                }
                if ((unsigned)(ss[k] - lo) < range) {
                    int p = atomicAdd(&cur_src[ss[k]], 1);
                    adj_src[p] = (unsigned short)dd[k];
                }
            }
        } else {
            for (int k = 0; k < 4 && e + k < nE; ++k) {
                int s = ei[e + k], d2 = ei[nE + e + k];
                if ((unsigned)(d2 - lo) < range) {
                    int p = atomicAdd(&cur_dst[d2], 1);
                    adj_dst[p] = (unsigned short)s;
                }
                if ((unsigned)(s - lo) < range) {
                    int p = atomicAdd(&cur_src[s], 1);
                    adj_src[p] = (unsigned short)d2;
                }
            }
        }
    }
}

// Paired gather: lanes 0-31 even neighbors, 32-63 odd; half2 loads; shfl_xor(32) combine.
__global__ __launch_bounds__(256) void k_gather(
    const float* __restrict__ x,
    const half_t* __restrict__ P1, const half_t* __restrict__ P2,
    const int* __restrict__ off1, const unsigned short* __restrict__ adj1,
    const int* __restrict__ off2, const unsigned short* __restrict__ adj2,
    const float* __restrict__ preW1, const float* __restrict__ preb1,
    const float* __restrict__ preW2, const float* __restrict__ preb2,
    half_t* __restrict__ agg1, half_t* __restrict__ agg2,
    float* __restrict__ amp1, float* __restrict__ ramp1,
    float* __restrict__ amp2, float* __restrict__ ramp2, int nN) {
    int tid = threadIdx.x;
    const int lane = tid & 63;
    const int t = lane >> 4, g = lane & 15;
    const int base = t << 4;
    const int half_id = lane >> 5;
    const int fl = lane & 31;
    float wr1[16], wr2[16];
#pragma unroll
    for (int f = 0; f < 16; ++f) {
        wr1[f] = preW1[t * 512 + f * 16 + g];
        wr2[f] = preW2[t * 512 + f * 16 + g];
    }
    const float pb1 = preb1[lane], pb2 = preb2[lane];
    int node = (blockIdx.x * blockDim.x + tid) >> 6;
    int stride = (gridDim.x * blockDim.x) >> 6;
    for (; node < nN; node += stride) {
        float xv = x[(size_t)node * 64 + lane];
        float q1 = pb1, q2 = pb2;
#pragma unroll
        for (int f = 0; f < 16; ++f) {
            float v = __shfl(xv, base + f, 64);
            q1 = fmaf(v, wr1[f], q1);
            q2 = fmaf(v, wr2[f], q2);
        }
#pragma unroll
        for (int d = 0; d < 2; ++d) {
            const int* off = d ? off2 : off1;
            const unsigned short* adj = d ? adj2 : adj1;
            const half_t* P = d ? P2 : P1;
            float q = d ? q2 : q1;
            int beg = off[node], end = off[node + 1];
            int cnt = end - beg;
            float s0 = 0.f, s1 = 0.f, ss0 = 0.f, ss1 = 0.f;
            float mn0 = 3.0e38f, mn1 = 3.0e38f, mx0 = -3.0e38f, mx1 = -3.0e38f;
            int j = beg;
            for (; j + 8 <= end; j += 8) {
                int n0 = adj[j + 0 + half_id];
                int n1 = adj[j + 2 + half_id];
                int n2 = adj[j + 4 + half_id];
                int n3 = adj[j + 6 + half_id];
                half2v h0 = *(const half2v*)(P + (size_t)n0 * 64 + (fl << 1));
                half2v h1 = *(const half2v*)(P + (size_t)n1 * 64 + (fl << 1));
                half2v h2 = *(const half2v*)(P + (size_t)n2 * 64 + (fl << 1));
                half2v h3 = *(const half2v*)(P + (size_t)n3 * 64 + (fl << 1));
                float a0 = (float)h0[0], b0 = (float)h0[1];
                float a1 = (float)h1[0], b1 = (float)h1[1];
                float a2 = (float)h2[0], b2 = (float)h2[1];
                float a3 = (float)h3[0], b3 = (float)h3[1];
                s0 += (a0 + a1) + (a2 + a3);
                s1 += (b0 + b1) + (b2 + b3);
                ss0 = fmaf(a0, a0, ss0); ss0 = fmaf(a1, a1, ss0);
                ss0 = fmaf(a2, a2, ss0); ss0 = fmaf(a3, a3, ss0);
                ss1 = fmaf(b0, b0, ss1); ss1 = fmaf(b1, b1, ss1);
                ss1 = fmaf(b2, b2, ss1); ss1 = fmaf(b3, b3, ss1);
                mn0 = fminf(mn0, fminf(fminf(a0, a1), fminf(a2, a3)));
                mn1 = fminf(mn1, fminf(fminf(b0, b1), fminf(b2, b3)));
                mx0 = fmaxf(mx0, fmaxf(fmaxf(a0, a1), fmaxf(a2, a3)));
                mx1 = fmaxf(mx1, fmaxf(fmaxf(b0, b1), fmaxf(b2, b3)));
            }
            for (; j < end; j += 2) {
                int idx = j + half_id;
                if (idx < end) {
                    int n0 = adj[idx];
                    half2v h0 = *(const half2v*)(P + (size_t)n0 * 64 + (fl << 1));
                    float a0 = (float)h0[0], b0 = (float)h0[1];
                    s0 += a0; s1 += b0;
                    ss0 = fmaf(a0, a0, ss0); ss1 = fmaf(b0, b0, ss1);
                    mn0 = fminf(mn0, a0); mn1 = fminf(mn1, b0);
                    mx0 = fmaxf(mx0, a0); mx1 = fmaxf(mx1, b0);
                }
            }
            s0 += __shfl_xor(s0, 32, 64);  s1 += __shfl_xor(s1, 32, 64);
            ss0 += __shfl_xor(ss0, 32, 64); ss1 += __shfl_xor(ss1, 32, 64);
            mn0 = fminf(mn0, __shfl_xor(mn0, 32, 64));
            mn1 = fminf(mn1, __shfl_xor(mn1, 32, 64));
            mx0 = fmaxf(mx0, __shfl_xor(mx0, 32, 64));
            mx1 = fmaxf(mx1, __shfl_xor(mx1, 32, 64));
            float deg = (cnt > 0) ? (float)cnt : 1.0f;
            float inv = 1.0f / deg;
            float qa = __shfl(q, fl * 2, 64);
            float qb = __shfl(q, fl * 2 + 1, 64);
            float mean0 = s0 * inv, mean1 = s1 * inv;
            float std0 = sqrtf(fmaxf(ss0 * inv - mean0 * mean0, 0.f) + 1e-5f);
            float std1 = sqrtf(fmaxf(ss1 * inv - mean1 * mean1, 0.f) + 1e-5f);
            float m0, m1, l0, l1, h0v, h1v;
            if (cnt > 0) {
                m0 = qa + mean0; m1 = qb + mean1;
                l0 = qa + mn0;   l1 = qb + mn1;
                h0v = qa + mx0;  h1v = qb + mx1;
            } else {
                m0 = m1 = l0 = l1 = h0v = h1v = 0.f;
                std0 = std1 = 3.1622776601e-3f;
            }
            if (lane < 32) {
                int f0 = fl << 1;
                int tt = f0 >> 4, gg = f0 & 15;
                half_t* arow = (d ? agg2 : agg1) + (size_t)node * 256 + tt * 64 + gg;
                half2v hm; hm[0] = (half_t)m0;  hm[1] = (half_t)m1;
                half2v hl; hl[0] = (half_t)l0;  hl[1] = (half_t)l1;
                half2v hh; hh[0] = (half_t)h0v; hh[1] = (half_t)h1v;
                half2v hs; hs[0] = (half_t)std0; hs[1] = (half_t)std1;
                *(half2v*)(arow + 0)  = hm;
                *(half2v*)(arow + 16) = hl;
                *(half2v*)(arow + 32) = hh;
                *(half2v*)(arow + 48) = hs;
            }
            if (lane == 0) {
                float ampv = logf(deg + 1.0f) / 2.8332133440562162f;  // log(17)
                (d ? amp2 : amp1)[node] = ampv;
                (d ? ramp2 : ramp1)[node] = 1.0f / ampv;
            }
        }
    }
}

// Persistent MFMA pass, swapped operands. Per wave-tile of 16 nodes:
// per dir, per tower: oT[16c x 16n] = WA@aggT + amp*(WB@aggT) + ramp*(WE@aggT),
// oT -> wave-private LDS; then accY += WfinT(regs) @ [oT | xT]. 72 MFMA/tile.
__global__ __launch_bounds__(256, 2) void k_c(
    const float* __restrict__ x,
    const half_t* __restrict__ agg1, const half_t* __restrict__ agg2,
    const float* __restrict__ amp1, const float* __restrict__ ramp1,
    const float* __restrict__ amp2, const float* __restrict__ ramp2,
    const half_t* __restrict__ WLg, const half_t* __restrict__ WfinT,
    const float* __restrict__ bfin, float* __restrict__ out, int nN) {
    __shared__ half_t WLs[24 * 16 * 72];   // [m=d*12+t*3+mat][go=16][k=72pad]
    __shared__ half_t osb[4 * 16 * 72];    // per-wave oT [n=16][c=64 +8pad]
    int tid = threadIdx.x;
    {
        const uint4* src = (const uint4*)WLg;
        uint4* dst = (uint4*)WLs;
        for (int i = tid; i < (24 * 16 * 72) / 8; i += 256) dst[i] = src[i];
    }
    __syncthreads();
    int w = tid >> 6, lane = tid & 63;
    int l15 = lane & 15, g4 = lane >> 4;
    half_t* ow = osb + w * (16 * 72) + l15 * 72;
    // WfinT A-fragments in registers: row = ct*16+l15, k = kk*32 + g4*8 + j
    half8 wfr[4][6];
#pragma unroll
    for (int ct = 0; ct < 4; ++ct)
#pragma unroll
        for (int kk = 0; kk < 6; ++kk)
            wfr[ct][kk] = *(const half8*)(WfinT + (ct * 16 + l15) * 192 + kk * 32 + g4 * 8);
    float4 bf4[4];
#pragma unroll
    for (int ct = 0; ct < 4; ++ct)
        bf4[ct] = *(const float4*)(bfin + ct * 16 + g4 * 4);
    int nwaves = gridDim.x * 4;
    int wgid = blockIdx.x * 4 + w;
    int ntiles = (nN + 15) >> 4;
    for (int tile = wgid; tile < ntiles; tile += nwaves) {
        int nrow = (tile << 4) + l15;
        int nrowc = (nrow < nN) ? nrow : (nN - 1);
        // xT B-fragments (col=node=l15, k=ks*32+g4*8+j)
        half8 xbf[2];
#pragma unroll
        for (int ks = 0; ks < 2; ++ks) {
            const float4* xp = (const float4*)(x + (size_t)nrowc * 64 + ks * 32 + g4 * 8);
            float4 x0 = xp[0], x1 = xp[1];
            half8 h;
            h[0] = (half_t)x0.x; h[1] = (half_t)x0.y; h[2] = (half_t)x0.z; h[3] = (half_t)x0.w;
            h[4] = (half_t)x1.x; h[5] = (half_t)x1.y; h[6] = (half_t)x1.z; h[7] = (half_t)x1.w;
            xbf[ks] = h;
        }
        f32x4 accY[4] = {{0,0,0,0},{0,0,0,0},{0,0,0,0},{0,0,0,0}};
#pragma unroll
        for (int d = 0; d < 2; ++d) {
            const half_t* agg = d ? agg2 : agg1;
            float ampv = (d ? amp2 : amp1)[nrowc];
            float rampv = (d ? ramp2 : ramp1)[nrowc];
#pragma unroll
            for (int t = 0; t < 4; ++t) {
                half8 b0 = *(const half8*)(agg + (size_t)nrowc * 256 + t * 64 + g4 * 8);
                half8 b1 = *(const half8*)(agg + (size_t)nrowc * 256 + t * 64 + 32 + g4 * 8);
                const half_t* wb = WLs + ((d * 12 + t * 3) * 16 + l15) * 72 + g4 * 8;
                half8 aA0 = *(const half8*)(wb);
                half8 aA1 = *(const half8*)(wb + 32);
                half8 aB0 = *(const half8*)(wb + 16 * 72);
                half8 aB1 = *(const half8*)(wb + 16 * 72 + 32);
                half8 aE0 = *(const half8*)(wb + 32 * 72);
                half8 aE1 = *(const half8*)(wb + 32 * 72 + 32);
                f32x4 zA = {0,0,0,0}, zB = {0,0,0,0}, zE = {0,0,0,0};
                zA = __builtin_amdgcn_mfma_f32_16x16x32_f16(aA0, b0, zA, 0, 0, 0);
                zA = __builtin_amdgcn_mfma_f32_16x16x32_f16(aA1, b1, zA, 0, 0, 0);
                zB = __builtin_amdgcn_mfma_f32_16x16x32_f16(aB0, b0, zB, 0, 0, 0);
                zB = __builtin_amdgcn_mfma_f32_16x16x32_f16(aB1, b1, zB, 0, 0, 0);
                zE = __builtin_amdgcn_mfma_f32_16x16x32_f16(aE0, b0, zE, 0, 0, 0);
                zE = __builtin_amdgcn_mfma_f32_16x16x32_f16(aE1, b1, zE, 0, 0, 0);
                float o0 = zA[0] + ampv * zB[0] + rampv * zE[0];
                float o1 = zA[1] + ampv * zB[1] + rampv * zE[1];
                float o2 = zA[2] + ampv * zB[2] + rampv * zE[2];
                float o3 = zA[3] + ampv * zB[3] + rampv * zE[3];
                half2v p0; p0[0] = (half_t)o0; p0[1] = (half_t)o1;
                half2v p1; p1[0] = (half_t)o2; p1[1] = (half_t)o3;
                *(half2v*)(ow + t * 16 + g4 * 4) = p0;
                *(half2v*)(ow + t * 16 + g4 * 4 + 2) = p1;
            }
            // phase-2 partial for this dir: accY += WfinT[:, d*64..] @ oT
#pragma unroll
            for (int ks = 0; ks < 2; ++ks) {
                half8 ob = *(const half8*)(ow + ks * 32 + g4 * 8);
#pragma unroll
                for (int ct = 0; ct < 4; ++ct)
                    accY[ct] = __builtin_amdgcn_mfma_f32_16x16x32_f16(wfr[ct][d * 2 + ks], ob, accY[ct], 0, 0, 0);
            }
        }
#pragma unroll
        for (int ks = 0; ks < 2; ++ks)
#pragma unroll
            for (int ct = 0; ct < 4; ++ct)
                accY[ct] = __builtin_amdgcn_mfma_f32_16x16x32_f16(wfr[ct][4 + ks], xbf[ks], accY[ct], 0, 0, 0);
        if (nrow < nN) {
#pragma unroll
            for (int ct = 0; ct < 4; ++ct) {
                float4 st;
                st.x = accY[ct][0] + bf4[ct].x;
                st.y = accY[ct][1] + bf4[ct].y;
                st.z = accY[ct][2] + bf4[ct].z;
                st.w = accY[ct][3] + bf4[ct].w;
                *(float4*)(out + (size_t)nrow * 64 + ct * 16 + g4 * 4) = st;
            }
        }
    }
}

extern "C" void kernel_launch(void* const* d_in, const int* in_sizes, int n_in,
                              void* d_out, int out_size, void* d_ws, size_t ws_size,
                              hipStream_t stream) {
    const float* x      = (const float*)d_in[0];
    const int*   ei     = (const int*)d_in[1];
    const float* alpha  = (const float*)d_in[2];
    const float* Wself  = (const float*)d_in[3];
    const float* bself  = (const float*)d_in[4];
    const float* preW1  = (const float*)d_in[5];
    const float* preb1  = (const float*)d_in[6];
    const float* postW1 = (const float*)d_in[7];
    const float* postb1 = (const float*)d_in[8];
    const float* linW1  = (const float*)d_in[9];
    const float* linb1  = (const float*)d_in[10];
    const float* preW2  = (const float*)d_in[11];
    const float* preb2  = (const float*)d_in[12];
    const float* postW2 = (const float*)d_in[13];
    const float* postb2 = (const float*)d_in[14];
    const float* linW2  = (const float*)d_in[15];
    const float* linb2  = (const float*)d_in[16];
    float* out = (float*)d_out;
    const int nN = in_sizes[0] / 64;
    const int nE = in_sizes[1] / 2;

    char* w = (char*)d_ws;
    size_t ofs = 0;
    auto alloc = [&](size_t bytes) {
        char* p = w + ofs;
        ofs = (ofs + bytes + 255) & ~(size_t)255;
        return p;
    };
    half_t* P1   = (half_t*)alloc((size_t)nN * 64 * 2);
    half_t* P2   = (half_t*)alloc((size_t)nN * 64 * 2);
    half_t* agg1 = (half_t*)alloc((size_t)nN * 256 * 2);
    half_t* agg2 = (half_t*)alloc((size_t)nN * 256 * 2);
    float* amp1  = (float*)alloc((size_t)nN * 4);
    float* ramp1 = (float*)alloc((size_t)nN * 4);
    float* amp2  = (float*)alloc((size_t)nN * 4);
    float* ramp2 = (float*)alloc((size_t)nN * 4);
    half_t* WLg   = (half_t*)alloc(24 * 16 * 72 * 2);
    half_t* WfinT = (half_t*)alloc(64 * 192 * 2);
    float* bfin   = (float*)alloc(64 * 4);
    int* off_dst = (int*)alloc((size_t)(nN + 1) * 4);
    int* off_src = (int*)alloc((size_t)(nN + 1) * 4);
    int* cnt_dst = (int*)alloc((size_t)nN * 4);
    int* cnt_src = (int*)alloc((size_t)nN * 4);
    unsigned short* adj_dst = (unsigned short*)alloc((size_t)nE * 2);
    unsigned short* adj_src = (unsigned short*)alloc((size_t)nE * 2);

    hipMemsetAsync(cnt_dst, 0, (size_t)nN * 4, stream);
    hipMemsetAsync(cnt_src, 0, (size_t)nN * 4, stream);

    k_phase1<<<2176, 256, 0, stream>>>(ei, nE, nN, cnt_dst, cnt_src,
                                       postW1, postW2, linW1, linW2, Wself, bself,
                                       linb1, linb2, postb1, postb2, alpha,
                                       WLg, WfinT, bfin,
                                       x, preW1, preW2, P1, P2);
    k_scan<<<2, 1024, 0, stream>>>(cnt_dst, off_dst, cnt_src, off_src, nN);
    k_scatter<<<1024, 256, 0, stream>>>(ei, nE, nN, cnt_dst, cnt_src, adj_dst, adj_src);
    k_gather<<<2048, 256, 0, stream>>>(x, P1, P2, off_dst, adj_dst, off_src, adj_src,
                                       preW1, preb1, preW2, preb2,
                                       agg1, agg2, amp1, ramp1, amp2, ramp2, nN);
    k_c<<<512, 256, 0, stream>>>(x, agg1, agg2, amp1, ramp1, amp2, ramp2,
                                 WLg, WfinT, bfin, out, nN);
}

// Round 6
// 271.835 us; speedup vs baseline: 7.4468x; 1.2756x over previous
//
#include <hip/hip_runtime.h>
#include <math.h>

// DirPNAConv: N=50000, E=800000, D=64, T=4, FI=FO=16.
// m[e] = Q[recv] + P[send] -> gather-stats of P + per-node Q shift (Q precomputed f16).
// Tower block-diagonality: post layer = per-tower K=64 GEMMs; x@Wx and postb folded
// through lin into Wfin/bfin. k_c: oT = W@aggT per tower (swapped operands),
// wave-private LDS bounce, y^T = WfinT@[o1,o2,x]^T.
// Graph build: packed uint edges (s|d<<16), XCD-ownership count/scatter, 2-level scan.

typedef _Float16 half_t;
typedef __attribute__((ext_vector_type(8))) _Float16 half8;
typedef __attribute__((ext_vector_type(2))) _Float16 half2v;
typedef __attribute__((ext_vector_type(4))) float f32x4;

static __device__ __forceinline__ unsigned pkmin(unsigned a, unsigned b) {
    unsigned r;
    asm("v_pk_min_f16 %0, %1, %2" : "=v"(r) : "v"(a), "v"(b));
    return r;
}
static __device__ __forceinline__ unsigned pkmax(unsigned a, unsigned b) {
    unsigned r;
    asm("v_pk_max_f16 %0, %1, %2" : "=v"(r) : "v"(a), "v"(b));
    return r;
}

// ---- fused: edge pack | weight prep | P,Q,xh projection ----
__global__ __launch_bounds__(256) void k_pre(
    const int* __restrict__ ei, int nE, int nN,
    unsigned* __restrict__ epk,
    const float* __restrict__ postW1, const float* __restrict__ postW2,
    const float* __restrict__ linW1, const float* __restrict__ linW2,
    const float* __restrict__ Wself, const float* __restrict__ bself,
    const float* __restrict__ linb1, const float* __restrict__ linb2,
    const float* __restrict__ postb1, const float* __restrict__ postb2,
    const float* __restrict__ alpha,
    half_t* __restrict__ WLg, half_t* __restrict__ WfinTg, float* __restrict__ bfin,
    const float* __restrict__ x,
    const float* __restrict__ preW1, const float* __restrict__ preW2,
    const float* __restrict__ preb1, const float* __restrict__ preb2,
    half_t* __restrict__ P1, half_t* __restrict__ P2,
    half_t* __restrict__ Q1, half_t* __restrict__ Q2, half_t* __restrict__ xh) {
    int tid = threadIdx.x;
    int b = blockIdx.x;
    if (b < 192) {
        // ---- pack edges: epk[e] = src | dst<<16 ----
        int nquad = (nE + 3) >> 2;
        for (int qi = b * 256 + tid; qi < nquad; qi += 192 * 256) {
            int e = qi << 2;
            if (e + 4 <= nE) {
                int4 sv = *reinterpret_cast<const int4*>(ei + e);
                int4 dv = *reinterpret_cast<const int4*>(ei + nE + e);
                uint4 pk;
                pk.x = (unsigned)sv.x | ((unsigned)dv.x << 16);
                pk.y = (unsigned)sv.y | ((unsigned)dv.y << 16);
                pk.z = (unsigned)sv.z | ((unsigned)dv.z << 16);
                pk.w = (unsigned)sv.w | ((unsigned)dv.w << 16);
                *reinterpret_cast<uint4*>(epk + e) = pk;
            } else {
                for (int k = 0; k < 4 && e + k < nE; ++k)
                    epk[e + k] = (unsigned)ei[e + k] | ((unsigned)ei[nE + e + k] << 16);
            }
        }
    } else if (b < 256) {
        // ---- weight prep ----
        const float a = alpha[0];
        int id = (b - 192) * 256 + tid;
        const int stride = 64 * 256;
        // WL[m][go][k72]: m = d*12 + t*3 + mat (0=id,1=amp,2=att), k = stat*16+g
        for (int i = id; i < 24 * 16 * 72; i += stride) {
            int m = i / (16 * 72);
            int r = i % (16 * 72);
            int go = r / 72, k = r % 72;
            int d = m / 12, t = (m / 3) % 4, mat = m % 3;
            float v = 0.f;
            if (k < 64) {
                int stat = k >> 4, g = k & 15;
                int basep = (mat == 0) ? 1 : (mat == 1 ? 5 : 9);
                const float* pw = d ? postW2 : postW1;
                v = pw[t * 3328 + ((basep + stat) * 16 + g) * 16 + go];
            }
            WLg[i] = (half_t)v;
        }
        // WfinT[out][k=192]: k<64 o1, k<128 o2, k<192 x-block (Wself + Wx@lin folds)
        for (int i = id; i < 64 * 192; i += stride) {
            int o = i / 192, k = i % 192;
            float v;
            if (k < 64)       v = (1.f - a) * linW1[k * 64 + o];
            else if (k < 128) v = a * linW2[(k - 64) * 64 + o];
            else {
                int kx = k - 128, t = kx >> 4, f = kx & 15;
                v = Wself[kx * 64 + o];
                float s1 = 0.f, s2 = 0.f;
                for (int go = 0; go < 16; ++go) {
                    s1 += postW1[t * 3328 + f * 16 + go] * linW1[(t * 16 + go) * 64 + o];
                    s2 += postW2[t * 3328 + f * 16 + go] * linW2[(t * 16 + go) * 64 + o];
                }
                v += (1.f - a) * s1 + a * s2;
            }
            WfinTg[i] = (half_t)v;
        }
        for (int i = id; i < 64; i += stride) {
            float v = bself[i] + (1.f - a) * linb1[i] + a * linb2[i];
            for (int j = 0; j < 64; ++j)
                v += (1.f - a) * postb1[j] * linW1[j * 64 + i]
                   + a * postb2[j] * linW2[j * 64 + i];
            bfin[i] = v;
        }
    } else {
        // ---- P,Q projection + xh: P = x@preW[:,16:32], Q = x@preW[:,0:16] + preb ----
        int vb = b - 256;
        const int lane = tid & 63;
        const int t = lane >> 4, g = lane & 15;
        const int base = t << 4;
        float wsP1[16], wsP2[16], wsQ1[16], wsQ2[16];
#pragma unroll
        for (int f = 0; f < 16; ++f) {
            wsP1[f] = preW1[t * 512 + (16 + f) * 16 + g];
            wsP2[f] = preW2[t * 512 + (16 + f) * 16 + g];
            wsQ1[f] = preW1[t * 512 + f * 16 + g];
            wsQ2[f] = preW2[t * 512 + f * 16 + g];
        }
        const float pb1 = preb1[lane], pb2 = preb2[lane];
        int node = (vb * 256 + tid) >> 6;
        const int stride = (768 * 256) >> 6;
        for (; node < nN; node += stride) {
            float xv = x[(size_t)node * 64 + lane];
            float p1 = 0.f, p2 = 0.f, q1 = pb1, q2 = pb2;
#pragma unroll
            for (int f = 0; f < 16; ++f) {
                float v = __shfl(xv, base + f, 64);
                p1 = fmaf(v, wsP1[f], p1);
                p2 = fmaf(v, wsP2[f], p2);
                q1 = fmaf(v, wsQ1[f], q1);
                q2 = fmaf(v, wsQ2[f], q2);
            }
            size_t o = (size_t)node * 64 + lane;
            P1[o] = (half_t)p1;
            P2[o] = (half_t)p2;
            Q1[o] = (half_t)q1;
            Q2[o] = (half_t)q2;
            xh[o] = (half_t)xv;
        }
    }
}

// XCD-ownership count over packed edges.
__global__ __launch_bounds__(256) void k_count(
    const unsigned* __restrict__ epk, int nE, int nN,
    int* __restrict__ cnt_dst, int* __restrict__ cnt_src) {
    int tid = threadIdx.x;
    int group = blockIdx.x & 7;
    int gblk = blockIdx.x >> 3;
    int rs = (nN + 7) >> 3;
    int lo = group * rs;
    int hi = lo + rs; if (hi > nN) hi = nN;
    unsigned range = (unsigned)(hi - lo);
    int nquad = (nE + 3) >> 2;
    for (int qi = gblk * 256 + tid; qi < nquad; qi += 128 * 256) {
        int e = qi << 2;
        if (e + 4 <= nE) {
            uint4 pv = *reinterpret_cast<const uint4*>(epk + e);
            unsigned pp[4] = {pv.x, pv.y, pv.z, pv.w};
#pragma unroll
            for (int k = 0; k < 4; ++k) {
                int s = (int)(pp[k] & 0xFFFFu), d = (int)(pp[k] >> 16);
                if ((unsigned)(d - lo) < range) atomicAdd(&cnt_dst[d], 1);
                if ((unsigned)(s - lo) < range) atomicAdd(&cnt_src[s], 1);
            }
        } else {
            for (int k = 0; k < 4 && e + k < nE; ++k) {
                unsigned p = epk[e + k];
                int s = (int)(p & 0xFFFFu), d = (int)(p >> 16);
                if ((unsigned)(d - lo) < range) atomicAdd(&cnt_dst[d], 1);
                if ((unsigned)(s - lo) < range) atomicAdd(&cnt_src[s], 1);
            }
        }
    }
}

// Two-level scan. scanA: per-1024 chunk local exclusive scan (into off) + chunk sums.
__global__ __launch_bounds__(256) void k_scanA(
    const int* __restrict__ cnt0, const int* __restrict__ cnt1,
    int* __restrict__ off0, int* __restrict__ off1,
    int* __restrict__ bsum, int n, int nchunk) {
    int arr = blockIdx.x >= nchunk;
    int c = blockIdx.x - (arr ? nchunk : 0);
    const int* cnt = arr ? cnt1 : cnt0;
    int* off = arr ? off1 : off0;
    int tid = threadIdx.x;
    int base = c * 1024 + tid * 4;
    int v[4];
#pragma unroll
    for (int k = 0; k < 4; ++k) { int i = base + k; v[k] = (i < n) ? cnt[i] : 0; }
    int tsum = v[0] + v[1] + v[2] + v[3];
    int lane = tid & 63, wid = tid >> 6;
    int incl = tsum;
#pragma unroll
    for (int d = 1; d < 64; d <<= 1) {
        int t = __shfl_up(incl, d, 64);
        if (lane >= d) incl += t;
    }
    __shared__ int ws[4];
    if (lane == 63) ws[wid] = incl;
    __syncthreads();
    int wpre = 0;
    for (int ww = 0; ww < wid; ++ww) wpre += ws[ww];
    int e = wpre + incl - tsum;
#pragma unroll
    for (int k = 0; k < 4; ++k) { int i = base + k; if (i < n) off[i] = e; e += v[k]; }
    if (tid == 255) bsum[blockIdx.x] = wpre + incl;
}

// scanB: add scanned chunk prefixes; write final off + cursor copy into cnt.
__global__ __launch_bounds__(256) void k_scanB(
    int* __restrict__ off0, int* __restrict__ off1,
    int* __restrict__ cnt0, int* __restrict__ cnt1,
    const int* __restrict__ bsum, int n, int nchunk) {
    int arr = blockIdx.x >= nchunk;
    int c = blockIdx.x - (arr ? nchunk : 0);
    int* off = arr ? off1 : off0;
    int* cw  = arr ? cnt1 : cnt0;
    const int* bs = bsum + (arr ? nchunk : 0);
    __shared__ int pre_s, tot_s;
    int tid = threadIdx.x;
    if (tid < 64) {
        int v = (tid < nchunk) ? bs[tid] : 0;
        int incl = v;
#pragma unroll
        for (int d = 1; d < 64; d <<= 1) {
            int t = __shfl_up(incl, d, 64);
            if (tid >= d) incl += t;
        }
        if (tid == c) pre_s = incl - v;
        if (tid == nchunk - 1) tot_s = incl;
    }
    __syncthreads();
    int pre = pre_s;
    int base = c * 1024 + tid * 4;
#pragma unroll
    for (int k = 0; k < 4; ++k) {
        int i = base + k;
        if (i < n) { int f = off[i] + pre; off[i] = f; cw[i] = f; }
    }
    if (c == 0 && tid == 0) off[n] = tot_s;
}

// XCD-ownership scatter over packed edges: ushort adj writes stay L2-local.
__global__ __launch_bounds__(256) void k_scatter(
    const unsigned* __restrict__ epk, int nE, int nN,
    int* __restrict__ cur_dst, int* __restrict__ cur_src,
    unsigned short* __restrict__ adj_dst, unsigned short* __restrict__ adj_src) {
    int tid = threadIdx.x;
    int group = blockIdx.x & 7;
    int gblk = blockIdx.x >> 3;
    int rs = (nN + 7) >> 3;
    int lo = group * rs;
    int hi = lo + rs; if (hi > nN) hi = nN;
    unsigned range = (unsigned)(hi - lo);
    int nquad = (nE + 3) >> 2;
    for (int qi = gblk * 256 + tid; qi < nquad; qi += 128 * 256) {
        int e = qi << 2;
        if (e + 4 <= nE) {
            uint4 pv = *reinterpret_cast<const uint4*>(epk + e);
            unsigned pp[4] = {pv.x, pv.y, pv.z, pv.w};
#pragma unroll
            for (int k = 0; k < 4; ++k) {
                int s = (int)(pp[k] & 0xFFFFu), d = (int)(pp[k] >> 16);
                if ((unsigned)(d - lo) < range) {
                    int p = atomicAdd(&cur_dst[d], 1);
                    adj_dst[p] = (unsigned short)s;
                }
                if ((unsigned)(s - lo) < range) {
                    int p = atomicAdd(&cur_src[s], 1);
                    adj_src[p] = (unsigned short)d;
                }
            }
        } else {
            for (int k = 0; k < 4 && e + k < nE; ++k) {
                unsigned p = epk[e + k];
                int s = (int)(p & 0xFFFFu), d = (int)(p >> 16);
                if ((unsigned)(d - lo) < range) {
                    int q = atomicAdd(&cur_dst[d], 1);
                    adj_dst[q] = (unsigned short)s;
                }
                if ((unsigned)(s - lo) < range) {
                    int q = atomicAdd(&cur_src[s], 1);
                    adj_src[q] = (unsigned short)d;
                }
            }
        }
    }
}

// Paired gather: lanes 0-31 even neighbors, 32-63 odd; half2 loads; packed f16
// min/max; Q loaded directly (f16) in paired layout; dirs split for L2 locality.
__global__ __launch_bounds__(256) void k_gather(
    const half_t* __restrict__ P1, const half_t* __restrict__ P2,
    const half_t* __restrict__ Q1, const half_t* __restrict__ Q2,
    const int* __restrict__ off1, const unsigned short* __restrict__ adj1,
    const int* __restrict__ off2, const unsigned short* __restrict__ adj2,
    half_t* __restrict__ agg1, half_t* __restrict__ agg2,
    float* __restrict__ amp1, float* __restrict__ ramp1,
    float* __restrict__ amp2, float* __restrict__ ramp2, int nN) {
    int tid = threadIdx.x;
    const int lane = tid & 63;
    const int half_id = lane >> 5;
    const int fl = lane & 31;
    const int fl4 = fl << 2;
    int wstart = (blockIdx.x * blockDim.x + tid) >> 6;
    int wstride = (gridDim.x * blockDim.x) >> 6;
#pragma unroll
    for (int d = 0; d < 2; ++d) {
        const half_t* P = d ? P2 : P1;
        const half_t* Q = d ? Q2 : Q1;
        const int* off = d ? off2 : off1;
        const unsigned short* adj = d ? adj2 : adj1;
        half_t* agg = d ? agg2 : agg1;
        float* ampA = d ? amp2 : amp1;
        float* rampA = d ? ramp2 : ramp1;
        for (int node = wstart; node < nN; node += wstride) {
            int beg = off[node], end = off[node + 1];
            int cnt = end - beg;
            float s0 = 0.f, s1 = 0.f, ss0 = 0.f, ss1 = 0.f;
            unsigned mnP = 0x7C007C00u, mxP = 0xFC00FC00u;
            int j = beg;
            for (; j + 8 <= end; j += 8) {
                int n0 = adj[j + 0 + half_id];
                int n1 = adj[j + 2 + half_id];
                int n2 = adj[j + 4 + half_id];
                int n3 = adj[j + 6 + half_id];
                half2v h0 = *(const half2v*)((const char*)P + n0 * 128 + fl4);
                half2v h1 = *(const half2v*)((const char*)P + n1 * 128 + fl4);
                half2v h2 = *(const half2v*)((const char*)P + n2 * 128 + fl4);
                half2v h3 = *(const half2v*)((const char*)P + n3 * 128 + fl4);
                unsigned b0 = __builtin_bit_cast(unsigned, h0);
                unsigned b1 = __builtin_bit_cast(unsigned, h1);
                unsigned b2 = __builtin_bit_cast(unsigned, h2);
                unsigned b3 = __builtin_bit_cast(unsigned, h3);
                mnP = pkmin(mnP, pkmin(pkmin(b0, b1), pkmin(b2, b3)));
                mxP = pkmax(mxP, pkmax(pkmax(b0, b1), pkmax(b2, b3)));
                float a0 = (float)h0[0], c0 = (float)h0[1];
                float a1 = (float)h1[0], c1 = (float)h1[1];
                float a2 = (float)h2[0], c2 = (float)h2[1];
                float a3 = (float)h3[0], c3 = (float)h3[1];
                s0 += (a0 + a1) + (a2 + a3);
                s1 += (c0 + c1) + (c2 + c3);
                ss0 = fmaf(a0, a0, ss0); ss0 = fmaf(a1, a1, ss0);
                ss0 = fmaf(a2, a2, ss0); ss0 = fmaf(a3, a3, ss0);
                ss1 = fmaf(c0, c0, ss1); ss1 = fmaf(c1, c1, ss1);
                ss1 = fmaf(c2, c2, ss1); ss1 = fmaf(c3, c3, ss1);
            }
            for (; j < end; j += 2) {
                int idx = j + half_id;
                if (idx < end) {
                    int n0 = adj[idx];
                    half2v h0 = *(const half2v*)((const char*)P + n0 * 128 + fl4);
                    unsigned b0 = __builtin_bit_cast(unsigned, h0);
                    mnP = pkmin(mnP, b0);
                    mxP = pkmax(mxP, b0);
                    float a0 = (float)h0[0], c0 = (float)h0[1];
                    s0 += a0; s1 += c0;
                    ss0 = fmaf(a0, a0, ss0); ss1 = fmaf(c0, c0, ss1);
                }
            }
            s0 += __shfl_xor(s0, 32, 64);  s1 += __shfl_xor(s1, 32, 64);
            ss0 += __shfl_xor(ss0, 32, 64); ss1 += __shfl_xor(ss1, 32, 64);
            mnP = pkmin(mnP, (unsigned)__shfl_xor((int)mnP, 32, 64));
            mxP = pkmax(mxP, (unsigned)__shfl_xor((int)mxP, 32, 64));
            half2v mn2 = __builtin_bit_cast(half2v, mnP);
            half2v mx2 = __builtin_bit_cast(half2v, mxP);
            float mn0 = (float)mn2[0], mn1 = (float)mn2[1];
            float mx0 = (float)mx2[0], mx1 = (float)mx2[1];
            half2v qh = *(const half2v*)((const char*)Q + node * 128 + fl4);
            float qa = (float)qh[0], qb = (float)qh[1];
            float deg = (cnt > 0) ? (float)cnt : 1.0f;
            float inv = 1.0f / deg;
            float mean0 = s0 * inv, mean1 = s1 * inv;
            float std0 = sqrtf(fmaxf(ss0 * inv - mean0 * mean0, 0.f) + 1e-5f);
            float std1 = sqrtf(fmaxf(ss1 * inv - mean1 * mean1, 0.f) + 1e-5f);
            float m0, m1, l0, l1, h0v, h1v;
            if (cnt > 0) {
                m0 = qa + mean0; m1 = qb + mean1;
                l0 = qa + mn0;   l1 = qb + mn1;
                h0v = qa + mx0;  h1v = qb + mx1;
            } else {
                m0 = m1 = l0 = l1 = h0v = h1v = 0.f;
                std0 = std1 = 3.1622776601e-3f;
            }
            if (lane < 32) {
                int f0 = fl << 1;
                int tt = f0 >> 4, gg = f0 & 15;
                half_t* arow = agg + (size_t)node * 256 + tt * 64 + gg;
                half2v hm; hm[0] = (half_t)m0;  hm[1] = (half_t)m1;
                half2v hl; hl[0] = (half_t)l0;  hl[1] = (half_t)l1;
                half2v hh; hh[0] = (half_t)h0v; hh[1] = (half_t)h1v;
                half2v hs; hs[0] = (half_t)std0; hs[1] = (half_t)std1;
                *(half2v*)(arow + 0)  = hm;
                *(half2v*)(arow + 16) = hl;
                *(half2v*)(arow + 32) = hh;
                *(half2v*)(arow + 48) = hs;
            }
            if (lane == 0) {
                float ampv = logf(deg + 1.0f) / 2.8332133440562162f;  // log(17)
                ampA[node] = ampv;
                rampA[node] = 1.0f / ampv;
            }
        }
    }
}

// Persistent MFMA pass, swapped operands (as round 5), x read as f16.
__global__ __launch_bounds__(256, 2) void k_c(
    const half_t* __restrict__ xh,
    const half_t* __restrict__ agg1, const half_t* __restrict__ agg2,
    const float* __restrict__ amp1, const float* __restrict__ ramp1,
    const float* __restrict__ amp2, const float* __restrict__ ramp2,
    const half_t* __restrict__ WLg, const half_t* __restrict__ WfinT,
    const float* __restrict__ bfin, float* __restrict__ out, int nN) {
    __shared__ half_t WLs[24 * 16 * 72];
    __shared__ half_t osb[4 * 16 * 72];
    int tid = threadIdx.x;
    {
        const uint4* src = (const uint4*)WLg;
        uint4* dst = (uint4*)WLs;
        for (int i = tid; i < (24 * 16 * 72) / 8; i += 256) dst[i] = src[i];
    }
    __syncthreads();
    int w = tid >> 6, lane = tid & 63;
    int l15 = lane & 15, g4 = lane >> 4;
    half_t* ow = osb + w * (16 * 72) + l15 * 72;
    half8 wfr[4][6];
#pragma unroll
    for (int ct = 0; ct < 4; ++ct)
#pragma unroll
        for (int kk = 0; kk < 6; ++kk)
            wfr[ct][kk] = *(const half8*)(WfinT + (ct * 16 + l15) * 192 + kk * 32 + g4 * 8);
    float4 bf4[4];
#pragma unroll
    for (int ct = 0; ct < 4; ++ct)
        bf4[ct] = *(const float4*)(bfin + ct * 16 + g4 * 4);
    int nwaves = gridDim.x * 4;
    int wgid = blockIdx.x * 4 + w;
    int ntiles = (nN + 15) >> 4;
    for (int tile = wgid; tile < ntiles; tile += nwaves) {
        int nrow = (tile << 4) + l15;
        int nrowc = (nrow < nN) ? nrow : (nN - 1);
        half8 xbf[2];
#pragma unroll
        for (int ks = 0; ks < 2; ++ks)
            xbf[ks] = *(const half8*)(xh + (size_t)nrowc * 64 + ks * 32 + g4 * 8);
        f32x4 accY[4] = {{0,0,0,0},{0,0,0,0},{0,0,0,0},{0,0,0,0}};
#pragma unroll
        for (int d = 0; d < 2; ++d) {
            const half_t* agg = d ? agg2 : agg1;
            float ampv = (d ? amp2 : amp1)[nrowc];
            float rampv = (d ? ramp2 : ramp1)[nrowc];
#pragma unroll
            for (int t = 0; t < 4; ++t) {
                half8 b0 = *(const half8*)(agg + (size_t)nrowc * 256 + t * 64 + g4 * 8);
                half8 b1 = *(const half8*)(agg + (size_t)nrowc * 256 + t * 64 + 32 + g4 * 8);
                const half_t* wb = WLs + ((d * 12 + t * 3) * 16 + l15) * 72 + g4 * 8;
                half8 aA0 = *(const half8*)(wb);
                half8 aA1 = *(const half8*)(wb + 32);
                half8 aB0 = *(const half8*)(wb + 16 * 72);
                half8 aB1 = *(const half8*)(wb + 16 * 72 + 32);
                half8 aE0 = *(const half8*)(wb + 32 * 72);
                half8 aE1 = *(const half8*)(wb + 32 * 72 + 32);
                f32x4 zA = {0,0,0,0}, zB = {0,0,0,0}, zE = {0,0,0,0};
                zA = __builtin_amdgcn_mfma_f32_16x16x32_f16(aA0, b0, zA, 0, 0, 0);
                zA = __builtin_amdgcn_mfma_f32_16x16x32_f16(aA1, b1, zA, 0, 0, 0);
                zB = __builtin_amdgcn_mfma_f32_16x16x32_f16(aB0, b0, zB, 0, 0, 0);
                zB = __builtin_amdgcn_mfma_f32_16x16x32_f16(aB1, b1, zB, 0, 0, 0);
                zE = __builtin_amdgcn_mfma_f32_16x16x32_f16(aE0, b0, zE, 0, 0, 0);
                zE = __builtin_amdgcn_mfma_f32_16x16x32_f16(aE1, b1, zE, 0, 0, 0);
                float o0 = zA[0] + ampv * zB[0] + rampv * zE[0];
                float o1 = zA[1] + ampv * zB[1] + rampv * zE[1];
                float o2 = zA[2] + ampv * zB[2] + rampv * zE[2];
                float o3 = zA[3] + ampv * zB[3] + rampv * zE[3];
                half2v p0; p0[0] = (half_t)o0; p0[1] = (half_t)o1;
                half2v p1; p1[0] = (half_t)o2; p1[1] = (half_t)o3;
                *(half2v*)(ow + t * 16 + g4 * 4) = p0;
                *(half2v*)(ow + t * 16 + g4 * 4 + 2) = p1;
            }
#pragma unroll
            for (int ks = 0; ks < 2; ++ks) {
                half8 ob = *(const half8*)(ow + ks * 32 + g4 * 8);
#pragma unroll
                for (int ct = 0; ct < 4; ++ct)
                    accY[ct] = __builtin_amdgcn_mfma_f32_16x16x32_f16(wfr[ct][d * 2 + ks], ob, accY[ct], 0, 0, 0);
            }
        }
#pragma unroll
        for (int ks = 0; ks < 2; ++ks)
#pragma unroll
            for (int ct = 0; ct < 4; ++ct)
                accY[ct] = __builtin_amdgcn_mfma_f32_16x16x32_f16(wfr[ct][4 + ks], xbf[ks], accY[ct], 0, 0, 0);
        if (nrow < nN) {
#pragma unroll
            for (int ct = 0; ct < 4; ++ct) {
                float4 st;
                st.x = accY[ct][0] + bf4[ct].x;
                st.y = accY[ct][1] + bf4[ct].y;
                st.z = accY[ct][2] + bf4[ct].z;
                st.w = accY[ct][3] + bf4[ct].w;
                *(float4*)(out + (size_t)nrow * 64 + ct * 16 + g4 * 4) = st;
            }
        }
    }
}

extern "C" void kernel_launch(void* const* d_in, const int* in_sizes, int n_in,
                              void* d_out, int out_size, void* d_ws, size_t ws_size,
                              hipStream_t stream) {
    const float* x      = (const float*)d_in[0];
    const int*   ei     = (const int*)d_in[1];
    const float* alpha  = (const float*)d_in[2];
    const float* Wself  = (const float*)d_in[3];
    const float* bself  = (const float*)d_in[4];
    const float* preW1  = (const float*)d_in[5];
    const float* preb1  = (const float*)d_in[6];
    const float* postW1 = (const float*)d_in[7];
    const float* postb1 = (const float*)d_in[8];
    const float* linW1  = (const float*)d_in[9];
    const float* linb1  = (const float*)d_in[10];
    const float* preW2  = (const float*)d_in[11];
    const float* preb2  = (const float*)d_in[12];
    const float* postW2 = (const float*)d_in[13];
    const float* postb2 = (const float*)d_in[14];
    const float* linW2  = (const float*)d_in[15];
    const float* linb2  = (const float*)d_in[16];
    float* out = (float*)d_out;
    const int nN = in_sizes[0] / 64;
    const int nE = in_sizes[1] / 2;

    char* w = (char*)d_ws;
    size_t ofs = 0;
    auto alloc = [&](size_t bytes) {
        char* p = w + ofs;
        ofs = (ofs + bytes + 255) & ~(size_t)255;
        return p;
    };
    half_t* P1   = (half_t*)alloc((size_t)nN * 64 * 2);
    half_t* P2   = (half_t*)alloc((size_t)nN * 64 * 2);
    half_t* Q1   = (half_t*)alloc((size_t)nN * 64 * 2);
    half_t* Q2   = (half_t*)alloc((size_t)nN * 64 * 2);
    half_t* xh   = (half_t*)alloc((size_t)nN * 64 * 2);
    half_t* agg1 = (half_t*)alloc((size_t)nN * 256 * 2);
    half_t* agg2 = (half_t*)alloc((size_t)nN * 256 * 2);
    float* amp1  = (float*)alloc((size_t)nN * 4);
    float* ramp1 = (float*)alloc((size_t)nN * 4);
    float* amp2  = (float*)alloc((size_t)nN * 4);
    float* ramp2 = (float*)alloc((size_t)nN * 4);
    half_t* WLg   = (half_t*)alloc(24 * 16 * 72 * 2);
    half_t* WfinT = (half_t*)alloc(64 * 192 * 2);
    float* bfin   = (float*)alloc(64 * 4);
    int* off_dst = (int*)alloc((size_t)(nN + 1) * 4);
    int* off_src = (int*)alloc((size_t)(nN + 1) * 4);
    int* cnt_dst = (int*)alloc((size_t)nN * 2 * 4);   // cnt_dst | cnt_src contiguous
    int* cnt_src = cnt_dst + nN;
    unsigned* epk = (unsigned*)alloc((size_t)nE * 4);
    unsigned short* adj_dst = (unsigned short*)alloc((size_t)nE * 2);
    unsigned short* adj_src = (unsigned short*)alloc((size_t)nE * 2);
    int nchunk = (nN + 1023) >> 10;
    int* bsum = (int*)alloc((size_t)nchunk * 2 * 4);

    hipMemsetAsync(cnt_dst, 0, (size_t)nN * 2 * 4, stream);

    k_pre<<<1024, 256, 0, stream>>>(ei, nE, nN, epk,
                                    postW1, postW2, linW1, linW2, Wself, bself,
                                    linb1, linb2, postb1, postb2, alpha,
                                    WLg, WfinT, bfin,
                                    x, preW1, preW2, preb1, preb2,
                                    P1, P2, Q1, Q2, xh);
    k_count<<<1024, 256, 0, stream>>>(epk, nE, nN, cnt_dst, cnt_src);
    k_scanA<<<2 * nchunk, 256, 0, stream>>>(cnt_dst, cnt_src, off_dst, off_src, bsum, nN, nchunk);
    k_scanB<<<2 * nchunk, 256, 0, stream>>>(off_dst, off_src, cnt_dst, cnt_src, bsum, nN, nchunk);
    k_scatter<<<1024, 256, 0, stream>>>(epk, nE, nN, cnt_dst, cnt_src, adj_dst, adj_src);
    k_gather<<<2048, 256, 0, stream>>>(P1, P2, Q1, Q2, off_dst, adj_dst, off_src, adj_src,
                                       agg1, agg2, amp1, ramp1, amp2, ramp2, nN);
    k_c<<<512, 256, 0, stream>>>(xh, agg1, agg2, amp1, ramp1, amp2, ramp2,
                                 WLg, WfinT, bfin, out, nN);
}

// Round 7
// 201.265 us; speedup vs baseline: 10.0578x; 1.3506x over previous
//
#include <hip/hip_runtime.h>
#include <math.h>

// DirPNAConv: N=50000, E=800000, D=64, T=4, FI=FO=16.
// m[e] = Q[recv] + P[send] -> gather-stats of P + per-node Q shift (Q precomputed f16).
// Tower block-diagonality: post layer = per-tower K=64 GEMMs; x@Wx and postb folded
// through lin into Wfin/bfin. k_c: oT = W@aggT per tower (swapped operands),
// wave-private LDS bounce, y^T = WfinT@[o1,o2,x]^T.
// Graph build: ATOMIC-FREE counting sort — LDS hist (256 blocks x 256 buckets) ->
// exclusive scan -> binned placement at private cursors -> per-bucket fine sort
// with LDS staging (coalesced adj/off writes). No device-scope atomics anywhere.

typedef _Float16 half_t;
typedef __attribute__((ext_vector_type(8))) _Float16 half8;
typedef __attribute__((ext_vector_type(2))) _Float16 half2v;
typedef __attribute__((ext_vector_type(4))) float f32x4;

#define FCAP 12288

static __device__ __forceinline__ unsigned pkmin(unsigned a, unsigned b) {
    unsigned r;
    asm("v_pk_min_f16 %0, %1, %2" : "=v"(r) : "v"(a), "v"(b));
    return r;
}
static __device__ __forceinline__ unsigned pkmax(unsigned a, unsigned b) {
    unsigned r;
    asm("v_pk_max_f16 %0, %1, %2" : "=v"(r) : "v"(a), "v"(b));
    return r;
}

// ---- fused: LDS edge histogram | weight prep | P,Q,xh projection ----
__global__ __launch_bounds__(256) void k_pre(
    const int* __restrict__ ei, int nE, int nN,
    int* __restrict__ histD, int* __restrict__ histS,
    const float* __restrict__ postW1, const float* __restrict__ postW2,
    const float* __restrict__ linW1, const float* __restrict__ linW2,
    const float* __restrict__ Wself, const float* __restrict__ bself,
    const float* __restrict__ linb1, const float* __restrict__ linb2,
    const float* __restrict__ postb1, const float* __restrict__ postb2,
    const float* __restrict__ alpha,
    half_t* __restrict__ WLg, half_t* __restrict__ WfinTg, float* __restrict__ bfin,
    const float* __restrict__ x,
    const float* __restrict__ preW1, const float* __restrict__ preW2,
    const float* __restrict__ preb1, const float* __restrict__ preb2,
    half_t* __restrict__ P1, half_t* __restrict__ P2,
    half_t* __restrict__ Q1, half_t* __restrict__ Q2, half_t* __restrict__ xh) {
    int tid = threadIdx.x;
    int b = blockIdx.x;
    if (b < 256) {
        // ---- per-chunk LDS histogram over coarse buckets (node>>8), both dirs ----
        __shared__ int hD[256], hS[256];
        hD[tid] = 0; hS[tid] = 0;
        __syncthreads();
        int chunk = (nE + 255) >> 8;
        int lo = b * chunk;
        int hi = lo + chunk; if (hi > nE) hi = nE;
        for (int e = lo + tid; e < hi; e += 256) {
            int s = ei[e], d = ei[nE + e];
            atomicAdd(&hD[d >> 8], 1);
            atomicAdd(&hS[s >> 8], 1);
        }
        __syncthreads();
        histD[tid * 256 + b] = hD[tid];
        histS[tid * 256 + b] = hS[tid];
    } else if (b < 320) {
        // ---- weight prep ----
        const float a = alpha[0];
        int id = (b - 256) * 256 + tid;
        const int stride = 64 * 256;
        // WL[m][go][k72]: m = d*12 + t*3 + mat (0=id,1=amp,2=att), k = stat*16+g
        for (int i = id; i < 24 * 16 * 72; i += stride) {
            int m = i / (16 * 72);
            int r = i % (16 * 72);
            int go = r / 72, k = r % 72;
            int d = m / 12, t = (m / 3) % 4, mat = m % 3;
            float v = 0.f;
            if (k < 64) {
                int stat = k >> 4, g = k & 15;
                int basep = (mat == 0) ? 1 : (mat == 1 ? 5 : 9);
                const float* pw = d ? postW2 : postW1;
                v = pw[t * 3328 + ((basep + stat) * 16 + g) * 16 + go];
            }
            WLg[i] = (half_t)v;
        }
        // WfinT[out][k=192]: k<64 o1, k<128 o2, k<192 x-block (Wself + Wx@lin folds)
        for (int i = id; i < 64 * 192; i += stride) {
            int o = i / 192, k = i % 192;
            float v;
            if (k < 64)       v = (1.f - a) * linW1[k * 64 + o];
            else if (k < 128) v = a * linW2[(k - 64) * 64 + o];
            else {
                int kx = k - 128, t = kx >> 4, f = kx & 15;
                v = Wself[kx * 64 + o];
                float s1 = 0.f, s2 = 0.f;
                for (int go = 0; go < 16; ++go) {
                    s1 += postW1[t * 3328 + f * 16 + go] * linW1[(t * 16 + go) * 64 + o];
                    s2 += postW2[t * 3328 + f * 16 + go] * linW2[(t * 16 + go) * 64 + o];
                }
                v += (1.f - a) * s1 + a * s2;
            }
            WfinTg[i] = (half_t)v;
        }
        for (int i = id; i < 64; i += stride) {
            float v = bself[i] + (1.f - a) * linb1[i] + a * linb2[i];
            for (int j = 0; j < 64; ++j)
                v += (1.f - a) * postb1[j] * linW1[j * 64 + i]
                   + a * postb2[j] * linW2[j * 64 + i];
            bfin[i] = v;
        }
    } else {
        // ---- P,Q projection + xh: P = x@preW[:,16:32], Q = x@preW[:,0:16] + preb ----
        int vb = b - 320;
        const int lane = tid & 63;
        const int t = lane >> 4, g = lane & 15;
        const int base = t << 4;
        float wsP1[16], wsP2[16], wsQ1[16], wsQ2[16];
#pragma unroll
        for (int f = 0; f < 16; ++f) {
            wsP1[f] = preW1[t * 512 + (16 + f) * 16 + g];
            wsP2[f] = preW2[t * 512 + (16 + f) * 16 + g];
            wsQ1[f] = preW1[t * 512 + f * 16 + g];
            wsQ2[f] = preW2[t * 512 + f * 16 + g];
        }
        const float pb1 = preb1[lane], pb2 = preb2[lane];
        int node = (vb * 256 + tid) >> 6;
        const int stride = (768 * 256) >> 6;
        for (; node < nN; node += stride) {
            float xv = x[(size_t)node * 64 + lane];
            float p1 = 0.f, p2 = 0.f, q1 = pb1, q2 = pb2;
#pragma unroll
            for (int f = 0; f < 16; ++f) {
                float v = __shfl(xv, base + f, 64);
                p1 = fmaf(v, wsP1[f], p1);
                p2 = fmaf(v, wsP2[f], p2);
                q1 = fmaf(v, wsQ1[f], q1);
                q2 = fmaf(v, wsQ2[f], q2);
            }
            size_t o = (size_t)node * 64 + lane;
            P1[o] = (half_t)p1;
            P2[o] = (half_t)p2;
            Q1[o] = (half_t)q1;
            Q2[o] = (half_t)q2;
            xh[o] = (half_t)xv;
        }
    }
}

// Exclusive scan of two arrays (block 0 -> a, block 1 -> b), shfl-based.
// Writes off[i]=excl, off[n]=total, cnt[i]=excl.
__global__ __launch_bounds__(1024) void k_scan(int* cnt_a, int* off_a, int* cnt_b, int* off_b, int n) {
    int* cnt = blockIdx.x ? cnt_b : cnt_a;
    int* off = blockIdx.x ? off_b : off_a;
    __shared__ int wsum[16];
    __shared__ int carry_s;
    int tid = threadIdx.x;
    int lane = tid & 63, wid = tid >> 6;
    if (tid == 0) carry_s = 0;
    __syncthreads();
    for (int base = 0; base < n; base += 1024) {
        int i = base + tid;
        int v = (i < n) ? cnt[i] : 0;
        int s = v;
#pragma unroll
        for (int d = 1; d < 64; d <<= 1) {
            int t = __shfl_up(s, d, 64);
            if (lane >= d) s += t;
        }
        if (lane == 63) wsum[wid] = s;
        __syncthreads();
        if (wid == 0) {
            int ws = (lane < 16) ? wsum[lane] : 0;
#pragma unroll
            for (int d = 1; d < 16; d <<= 1) {
                int t = __shfl_up(ws, d, 64);
                if (lane >= d) ws += t;
            }
            if (lane < 16) wsum[lane] = ws;
        }
        __syncthreads();
        int wbase = (wid > 0) ? wsum[wid - 1] : 0;
        int carry = carry_s;
        if (i < n) { int excl = carry + wbase + s - v; off[i] = excl; cnt[i] = excl; }
        __syncthreads();
        if (tid == 0) carry_s = carry + wsum[15];
        __syncthreads();
    }
    if (threadIdx.x == 0) off[n] = carry_s;
}

// Binned placement: each block re-reads its edge chunk, places packed edges at
// LDS-private cursors (from the scan). No global atomics; per-bucket sub-regions
// are block-private and contiguous -> L2 absorbs, ~1x write amplification.
__global__ __launch_bounds__(256) void k_bin(
    const int* __restrict__ ei, int nE, int nbuck,
    const int* __restrict__ curD, const int* __restrict__ curS,
    unsigned* __restrict__ binnedD, unsigned* __restrict__ binnedS) {
    __shared__ int cD[256], cS[256];
    int tid = threadIdx.x;
    int hb = blockIdx.x;
    if (tid < nbuck) {
        cD[tid] = curD[tid * 256 + hb];
        cS[tid] = curS[tid * 256 + hb];
    }
    __syncthreads();
    int chunk = (nE + 255) >> 8;
    int lo = hb * chunk;
    int hi = lo + chunk; if (hi > nE) hi = nE;
    for (int e = lo + tid; e < hi; e += 256) {
        int s = ei[e], d = ei[nE + e];
        unsigned pk = (unsigned)s | ((unsigned)d << 16);
        int p = atomicAdd(&cD[d >> 8], 1);
        binnedD[p] = pk;
        int q = atomicAdd(&cS[s >> 8], 1);
        binnedS[q] = pk;
    }
}

// Fine sort within each (bucket, dir): LDS per-node count -> wave scan -> LDS
// staged placement -> coalesced adj + off writes.
__global__ __launch_bounds__(256) void k_fine(
    const unsigned* __restrict__ binnedD, const unsigned* __restrict__ binnedS,
    const int* __restrict__ curD, const int* __restrict__ curS,
    int* __restrict__ off_dst, int* __restrict__ off_src,
    unsigned short* __restrict__ adj_dst, unsigned short* __restrict__ adj_src,
    int nE, int nN, int nbuck) {
    int bk = blockIdx.x;
    int dd = 0;
    if (bk >= nbuck) { dd = 1; bk -= nbuck; }
    const unsigned* binned = dd ? binnedS : binnedD;
    const int* cur = dd ? curS : curD;
    int* off = dd ? off_src : off_dst;
    unsigned short* adj = dd ? adj_src : adj_dst;
    __shared__ int ncnt[256];
    __shared__ int cur2[256];
    __shared__ unsigned short stage[FCAP];
    int tid = threadIdx.x;
    ncnt[tid] = 0;
    __syncthreads();
    int base = cur[bk * 256];
    int endp = cur[(bk + 1) * 256];   // bk+1==nbuck -> cur[nbuck*256] = nE
    int cntE = endp - base;
    int n0 = bk << 8;
    for (int i = tid; i < cntE; i += 256) {
        unsigned pk = binned[base + i];
        int key = dd ? (int)(pk & 0xFFFFu) : (int)(pk >> 16);
        atomicAdd(&ncnt[key - n0], 1);
    }
    __syncthreads();
    if (tid < 64) {
        int i4 = tid << 2;
        int v0 = ncnt[i4], v1 = ncnt[i4 + 1], v2 = ncnt[i4 + 2], v3 = ncnt[i4 + 3];
        int tsum = v0 + v1 + v2 + v3;
        int incl = tsum;
#pragma unroll
        for (int d = 1; d < 64; d <<= 1) {
            int t = __shfl_up(incl, d, 64);
            if (tid >= d) incl += t;
        }
        int excl = incl - tsum;
        ncnt[i4] = excl;
        ncnt[i4 + 1] = excl + v0;
        ncnt[i4 + 2] = excl + v0 + v1;
        ncnt[i4 + 3] = excl + v0 + v1 + v2;
    }
    __syncthreads();
    cur2[tid] = ncnt[tid];
    int node = n0 + tid;
    if (node < nN) off[node] = base + ncnt[tid];
    if (bk == nbuck - 1 && tid == 0) off[nN] = nE;
    __syncthreads();
    for (int i = tid; i < cntE; i += 256) {
        unsigned pk = binned[base + i];
        int key = dd ? (int)(pk & 0xFFFFu) : (int)(pk >> 16);
        int oth = dd ? (int)(pk >> 16) : (int)(pk & 0xFFFFu);
        int pos = atomicAdd(&cur2[key - n0], 1);
        if (pos < FCAP) stage[pos] = (unsigned short)oth;
        else adj[base + pos] = (unsigned short)oth;   // overflow fallback (never in practice)
    }
    __syncthreads();
    int lim = cntE < FCAP ? cntE : FCAP;
    for (int i = tid; i < lim; i += 256) adj[base + i] = stage[i];
}

// Paired gather: lanes 0-31 even neighbors, 32-63 odd; half2 loads; packed f16
// min/max; Q loaded directly (f16) in paired layout; dirs split for L2 locality.
__global__ __launch_bounds__(256) void k_gather(
    const half_t* __restrict__ P1, const half_t* __restrict__ P2,
    const half_t* __restrict__ Q1, const half_t* __restrict__ Q2,
    const int* __restrict__ off1, const unsigned short* __restrict__ adj1,
    const int* __restrict__ off2, const unsigned short* __restrict__ adj2,
    half_t* __restrict__ agg1, half_t* __restrict__ agg2,
    float* __restrict__ amp1, float* __restrict__ ramp1,
    float* __restrict__ amp2, float* __restrict__ ramp2, int nN) {
    int tid = threadIdx.x;
    const int lane = tid & 63;
    const int half_id = lane >> 5;
    const int fl = lane & 31;
    const int fl4 = fl << 2;
    int wstart = (blockIdx.x * blockDim.x + tid) >> 6;
    int wstride = (gridDim.x * blockDim.x) >> 6;
#pragma unroll
    for (int d = 0; d < 2; ++d) {
        const half_t* P = d ? P2 : P1;
        const half_t* Q = d ? Q2 : Q1;
        const int* off = d ? off2 : off1;
        const unsigned short* adj = d ? adj2 : adj1;
        half_t* agg = d ? agg2 : agg1;
        float* ampA = d ? amp2 : amp1;
        float* rampA = d ? ramp2 : ramp1;
        for (int node = wstart; node < nN; node += wstride) {
            int beg = off[node], end = off[node + 1];
            int cnt = end - beg;
            float s0 = 0.f, s1 = 0.f, ss0 = 0.f, ss1 = 0.f;
            unsigned mnP = 0x7C007C00u, mxP = 0xFC00FC00u;
            int j = beg;
            for (; j + 8 <= end; j += 8) {
                int n0 = adj[j + 0 + half_id];
                int n1 = adj[j + 2 + half_id];
                int n2 = adj[j + 4 + half_id];
                int n3 = adj[j + 6 + half_id];
                half2v h0 = *(const half2v*)((const char*)P + n0 * 128 + fl4);
                half2v h1 = *(const half2v*)((const char*)P + n1 * 128 + fl4);
                half2v h2 = *(const half2v*)((const char*)P + n2 * 128 + fl4);
                half2v h3 = *(const half2v*)((const char*)P + n3 * 128 + fl4);
                unsigned b0 = __builtin_bit_cast(unsigned, h0);
                unsigned b1 = __builtin_bit_cast(unsigned, h1);
                unsigned b2 = __builtin_bit_cast(unsigned, h2);
                unsigned b3 = __builtin_bit_cast(unsigned, h3);
                mnP = pkmin(mnP, pkmin(pkmin(b0, b1), pkmin(b2, b3)));
                mxP = pkmax(mxP, pkmax(pkmax(b0, b1), pkmax(b2, b3)));
                float a0 = (float)h0[0], c0 = (float)h0[1];
                float a1 = (float)h1[0], c1 = (float)h1[1];
                float a2 = (float)h2[0], c2 = (float)h2[1];
                float a3 = (float)h3[0], c3 = (float)h3[1];
                s0 += (a0 + a1) + (a2 + a3);
                s1 += (c0 + c1) + (c2 + c3);
                ss0 = fmaf(a0, a0, ss0); ss0 = fmaf(a1, a1, ss0);
                ss0 = fmaf(a2, a2, ss0); ss0 = fmaf(a3, a3, ss0);
                ss1 = fmaf(c0, c0, ss1); ss1 = fmaf(c1, c1, ss1);
                ss1 = fmaf(c2, c2, ss1); ss1 = fmaf(c3, c3, ss1);
            }
            for (; j < end; j += 2) {
                int idx = j + half_id;
                if (idx < end) {
                    int n0 = adj[idx];
                    half2v h0 = *(const half2v*)((const char*)P + n0 * 128 + fl4);
                    unsigned b0 = __builtin_bit_cast(unsigned, h0);
                    mnP = pkmin(mnP, b0);
                    mxP = pkmax(mxP, b0);
                    float a0 = (float)h0[0], c0 = (float)h0[1];
                    s0 += a0; s1 += c0;
                    ss0 = fmaf(a0, a0, ss0); ss1 = fmaf(c0, c0, ss1);
                }
            }
            s0 += __shfl_xor(s0, 32, 64);  s1 += __shfl_xor(s1, 32, 64);
            ss0 += __shfl_xor(ss0, 32, 64); ss1 += __shfl_xor(ss1, 32, 64);
            mnP = pkmin(mnP, (unsigned)__shfl_xor((int)mnP, 32, 64));
            mxP = pkmax(mxP, (unsigned)__shfl_xor((int)mxP, 32, 64));
            half2v mn2 = __builtin_bit_cast(half2v, mnP);
            half2v mx2 = __builtin_bit_cast(half2v, mxP);
            float mn0 = (float)mn2[0], mn1 = (float)mn2[1];
            float mx0 = (float)mx2[0], mx1 = (float)mx2[1];
            half2v qh = *(const half2v*)((const char*)Q + node * 128 + fl4);
            float qa = (float)qh[0], qb = (float)qh[1];
            float deg = (cnt > 0) ? (float)cnt : 1.0f;
            float inv = 1.0f / deg;
            float mean0 = s0 * inv, mean1 = s1 * inv;
            float std0 = sqrtf(fmaxf(ss0 * inv - mean0 * mean0, 0.f) + 1e-5f);
            float std1 = sqrtf(fmaxf(ss1 * inv - mean1 * mean1, 0.f) + 1e-5f);
            float m0, m1, l0, l1, h0v, h1v;
            if (cnt > 0) {
                m0 = qa + mean0; m1 = qb + mean1;
                l0 = qa + mn0;   l1 = qb + mn1;
                h0v = qa + mx0;  h1v = qb + mx1;
            } else {
                m0 = m1 = l0 = l1 = h0v = h1v = 0.f;
                std0 = std1 = 3.1622776601e-3f;
            }
            if (lane < 32) {
                int f0 = fl << 1;
                int tt = f0 >> 4, gg = f0 & 15;
                half_t* arow = agg + (size_t)node * 256 + tt * 64 + gg;
                half2v hm; hm[0] = (half_t)m0;  hm[1] = (half_t)m1;
                half2v hl; hl[0] = (half_t)l0;  hl[1] = (half_t)l1;
                half2v hh; hh[0] = (half_t)h0v; hh[1] = (half_t)h1v;
                half2v hs; hs[0] = (half_t)std0; hs[1] = (half_t)std1;
                *(half2v*)(arow + 0)  = hm;
                *(half2v*)(arow + 16) = hl;
                *(half2v*)(arow + 32) = hh;
                *(half2v*)(arow + 48) = hs;
            }
            if (lane == 0) {
                float ampv = logf(deg + 1.0f) / 2.8332133440562162f;  // log(17)
                ampA[node] = ampv;
                rampA[node] = 1.0f / ampv;
            }
        }
    }
}

// Persistent MFMA pass, swapped operands, x read as f16.
__global__ __launch_bounds__(256, 2) void k_c(
    const half_t* __restrict__ xh,
    const half_t* __restrict__ agg1, const half_t* __restrict__ agg2,
    const float* __restrict__ amp1, const float* __restrict__ ramp1,
    const float* __restrict__ amp2, const float* __restrict__ ramp2,
    const half_t* __restrict__ WLg, const half_t* __restrict__ WfinT,
    const float* __restrict__ bfin, float* __restrict__ out, int nN) {
    __shared__ half_t WLs[24 * 16 * 72];
    __shared__ half_t osb[4 * 16 * 72];
    int tid = threadIdx.x;
    {
        const uint4* src = (const uint4*)WLg;
        uint4* dst = (uint4*)WLs;
        for (int i = tid; i < (24 * 16 * 72) / 8; i += 256) dst[i] = src[i];
    }
    __syncthreads();
    int w = tid >> 6, lane = tid & 63;
    int l15 = lane & 15, g4 = lane >> 4;
    half_t* ow = osb + w * (16 * 72) + l15 * 72;
    half8 wfr[4][6];
#pragma unroll
    for (int ct = 0; ct < 4; ++ct)
#pragma unroll
        for (int kk = 0; kk < 6; ++kk)
            wfr[ct][kk] = *(const half8*)(WfinT + (ct * 16 + l15) * 192 + kk * 32 + g4 * 8);
    float4 bf4[4];
#pragma unroll
    for (int ct = 0; ct < 4; ++ct)
        bf4[ct] = *(const float4*)(bfin + ct * 16 + g4 * 4);
    int nwaves = gridDim.x * 4;
    int wgid = blockIdx.x * 4 + w;
    int ntiles = (nN + 15) >> 4;
    for (int tile = wgid; tile < ntiles; tile += nwaves) {
        int nrow = (tile << 4) + l15;
        int nrowc = (nrow < nN) ? nrow : (nN - 1);
        half8 xbf[2];
#pragma unroll
        for (int ks = 0; ks < 2; ++ks)
            xbf[ks] = *(const half8*)(xh + (size_t)nrowc * 64 + ks * 32 + g4 * 8);
        f32x4 accY[4] = {{0,0,0,0},{0,0,0,0},{0,0,0,0},{0,0,0,0}};
#pragma unroll
        for (int d = 0; d < 2; ++d) {
            const half_t* agg = d ? agg2 : agg1;
            float ampv = (d ? amp2 : amp1)[nrowc];
            float rampv = (d ? ramp2 : ramp1)[nrowc];
#pragma unroll
            for (int t = 0; t < 4; ++t) {
                half8 b0 = *(const half8*)(agg + (size_t)nrowc * 256 + t * 64 + g4 * 8);
                half8 b1 = *(const half8*)(agg + (size_t)nrowc * 256 + t * 64 + 32 + g4 * 8);
                const half_t* wb = WLs + ((d * 12 + t * 3) * 16 + l15) * 72 + g4 * 8;
                half8 aA0 = *(const half8*)(wb);
                half8 aA1 = *(const half8*)(wb + 32);
                half8 aB0 = *(const half8*)(wb + 16 * 72);
                half8 aB1 = *(const half8*)(wb + 16 * 72 + 32);
                half8 aE0 = *(const half8*)(wb + 32 * 72);
                half8 aE1 = *(const half8*)(wb + 32 * 72 + 32);
                f32x4 zA = {0,0,0,0}, zB = {0,0,0,0}, zE = {0,0,0,0};
                zA = __builtin_amdgcn_mfma_f32_16x16x32_f16(aA0, b0, zA, 0, 0, 0);
                zA = __builtin_amdgcn_mfma_f32_16x16x32_f16(aA1, b1, zA, 0, 0, 0);
                zB = __builtin_amdgcn_mfma_f32_16x16x32_f16(aB0, b0, zB, 0, 0, 0);
                zB = __builtin_amdgcn_mfma_f32_16x16x32_f16(aB1, b1, zB, 0, 0, 0);
                zE = __builtin_amdgcn_mfma_f32_16x16x32_f16(aE0, b0, zE, 0, 0, 0);
                zE = __builtin_amdgcn_mfma_f32_16x16x32_f16(aE1, b1, zE, 0, 0, 0);
                float o0 = zA[0] + ampv * zB[0] + rampv * zE[0];
                float o1 = zA[1] + ampv * zB[1] + rampv * zE[1];
                float o2 = zA[2] + ampv * zB[2] + rampv * zE[2];
                float o3 = zA[3] + ampv * zB[3] + rampv * zE[3];
                half2v p0; p0[0] = (half_t)o0; p0[1] = (half_t)o1;
                half2v p1; p1[0] = (half_t)o2; p1[1] = (half_t)o3;
                *(half2v*)(ow + t * 16 + g4 * 4) = p0;
                *(half2v*)(ow + t * 16 + g4 * 4 + 2) = p1;
            }
#pragma unroll
            for (int ks = 0; ks < 2; ++ks) {
                half8 ob = *(const half8*)(ow + ks * 32 + g4 * 8);
#pragma unroll
                for (int ct = 0; ct < 4; ++ct)
                    accY[ct] = __builtin_amdgcn_mfma_f32_16x16x32_f16(wfr[ct][d * 2 + ks], ob, accY[ct], 0, 0, 0);
            }
        }
#pragma unroll
        for (int ks = 0; ks < 2; ++ks)
#pragma unroll
            for (int ct = 0; ct < 4; ++ct)
                accY[ct] = __builtin_amdgcn_mfma_f32_16x16x32_f16(wfr[ct][4 + ks], xbf[ks], accY[ct], 0, 0, 0);
        if (nrow < nN) {
#pragma unroll
            for (int ct = 0; ct < 4; ++ct) {
                float4 st;
                st.x = accY[ct][0] + bf4[ct].x;
                st.y = accY[ct][1] + bf4[ct].y;
                st.z = accY[ct][2] + bf4[ct].z;
                st.w = accY[ct][3] + bf4[ct].w;
                *(float4*)(out + (size_t)nrow * 64 + ct * 16 + g4 * 4) = st;
            }
        }
    }
}

extern "C" void kernel_launch(void* const* d_in, const int* in_sizes, int n_in,
                              void* d_out, int out_size, void* d_ws, size_t ws_size,
                              hipStream_t stream) {
    const float* x      = (const float*)d_in[0];
    const int*   ei     = (const int*)d_in[1];
    const float* alpha  = (const float*)d_in[2];
    const float* Wself  = (const float*)d_in[3];
    const float* bself  = (const float*)d_in[4];
    const float* preW1  = (const float*)d_in[5];
    const float* preb1  = (const float*)d_in[6];
    const float* postW1 = (const float*)d_in[7];
    const float* postb1 = (const float*)d_in[8];
    const float* linW1  = (const float*)d_in[9];
    const float* linb1  = (const float*)d_in[10];
    const float* preW2  = (const float*)d_in[11];
    const float* preb2  = (const float*)d_in[12];
    const float* postW2 = (const float*)d_in[13];
    const float* postb2 = (const float*)d_in[14];
    const float* linW2  = (const float*)d_in[15];
    const float* linb2  = (const float*)d_in[16];
    float* out = (float*)d_out;
    const int nN = in_sizes[0] / 64;
    const int nE = in_sizes[1] / 2;
    const int nbuck = (nN + 255) >> 8;

    char* w = (char*)d_ws;
    size_t ofs = 0;
    auto alloc = [&](size_t bytes) {
        char* p = w + ofs;
        ofs = (ofs + bytes + 255) & ~(size_t)255;
        return p;
    };
    half_t* P1   = (half_t*)alloc((size_t)nN * 64 * 2);
    half_t* P2   = (half_t*)alloc((size_t)nN * 64 * 2);
    half_t* Q1   = (half_t*)alloc((size_t)nN * 64 * 2);
    half_t* Q2   = (half_t*)alloc((size_t)nN * 64 * 2);
    half_t* xh   = (half_t*)alloc((size_t)nN * 64 * 2);
    half_t* agg1 = (half_t*)alloc((size_t)nN * 256 * 2);
    half_t* agg2 = (half_t*)alloc((size_t)nN * 256 * 2);
    float* amp1  = (float*)alloc((size_t)nN * 4);
    float* ramp1 = (float*)alloc((size_t)nN * 4);
    float* amp2  = (float*)alloc((size_t)nN * 4);
    float* ramp2 = (float*)alloc((size_t)nN * 4);
    half_t* WLg   = (half_t*)alloc(24 * 16 * 72 * 2);
    half_t* WfinT = (half_t*)alloc(64 * 192 * 2);
    float* bfin   = (float*)alloc(64 * 4);
    int* histD = (int*)alloc(256 * 256 * 4);
    int* histS = (int*)alloc(256 * 256 * 4);
    int* curD  = (int*)alloc((256 * 256 + 1) * 4);
    int* curS  = (int*)alloc((256 * 256 + 1) * 4);
    unsigned* binnedD = (unsigned*)alloc((size_t)nE * 4);
    unsigned* binnedS = (unsigned*)alloc((size_t)nE * 4);
    int* off_dst = (int*)alloc((size_t)(nN + 1) * 4);
    int* off_src = (int*)alloc((size_t)(nN + 1) * 4);
    unsigned short* adj_dst = (unsigned short*)alloc((size_t)nE * 2);
    unsigned short* adj_src = (unsigned short*)alloc((size_t)nE * 2);

    k_pre<<<1088, 256, 0, stream>>>(ei, nE, nN, histD, histS,
                                    postW1, postW2, linW1, linW2, Wself, bself,
                                    linb1, linb2, postb1, postb2, alpha,
                                    WLg, WfinT, bfin,
                                    x, preW1, preW2, preb1, preb2,
                                    P1, P2, Q1, Q2, xh);
    k_scan<<<2, 1024, 0, stream>>>(histD, curD, histS, curS, nbuck * 256);
    k_bin<<<256, 256, 0, stream>>>(ei, nE, nbuck, curD, curS, binnedD, binnedS);
    k_fine<<<2 * nbuck, 256, 0, stream>>>(binnedD, binnedS, curD, curS,
                                          off_dst, off_src, adj_dst, adj_src,
                                          nE, nN, nbuck);
    k_gather<<<2048, 256, 0, stream>>>(P1, P2, Q1, Q2, off_dst, adj_dst, off_src, adj_src,
                                       agg1, agg2, amp1, ramp1, amp2, ramp2, nN);
    k_c<<<512, 256, 0, stream>>>(xh, agg1, agg2, amp1, ramp1, amp2, ramp2,
                                 WLg, WfinT, bfin, out, nN);
}

// Round 9
// 156.703 us; speedup vs baseline: 12.9180x; 1.2844x over previous
//
#include <hip/hip_runtime.h>
#include <math.h>

// DirPNAConv: N=50000, E=800000, D=64, T=4, FI=FO=16.
// m[e] = Q[recv] + P[send] -> gather-stats of P + per-node Q shift (Q precomputed f16).
// Tower block-diagonality: post layer = per-tower K=64 GEMMs; x@Wx and postb folded
// through lin into Wfin/bfin. k_c: oT = W@aggT per tower (swapped operands),
// wave-private LDS bounce, y^T = WfinT@[o1,o2,x]^T.
// Graph build: atomic-free counting sort (LDS hist -> parallel 2-level scan ->
// binned placement -> per-bucket fine sort). Gather: half4/lane, reg-resident adj
// via shfl, packed f16 accumulation (sum error diluted by /deg).

typedef _Float16 half_t;
typedef __attribute__((ext_vector_type(8))) _Float16 half8;
typedef __attribute__((ext_vector_type(2))) _Float16 half2v;
typedef __attribute__((ext_vector_type(4))) float f32x4;

#define FCAP 12288

static __device__ __forceinline__ unsigned pkmin(unsigned a, unsigned b) {
    unsigned r;
    asm("v_pk_min_f16 %0, %1, %2" : "=v"(r) : "v"(a), "v"(b));
    return r;
}
static __device__ __forceinline__ unsigned pkmax(unsigned a, unsigned b) {
    unsigned r;
    asm("v_pk_max_f16 %0, %1, %2" : "=v"(r) : "v"(a), "v"(b));
    return r;
}
static __device__ __forceinline__ int h2i(half2v h) { return __builtin_bit_cast(int, h); }
static __device__ __forceinline__ half2v i2h(int i) { return __builtin_bit_cast(half2v, i); }
static __device__ __forceinline__ half2v u2h(unsigned i) { return __builtin_bit_cast(half2v, i); }
static __device__ __forceinline__ half2v pkrtz(float a, float b) {
    return __builtin_bit_cast(half2v, __builtin_amdgcn_cvt_pkrtz(a, b));
}

// ---- fused: LDS edge histogram | weight prep | P,Q,xh projection ----
__global__ __launch_bounds__(256) void k_pre(
    const int* __restrict__ ei, int nE, int nN,
    int* __restrict__ histD, int* __restrict__ histS,
    const float* __restrict__ postW1, const float* __restrict__ postW2,
    const float* __restrict__ linW1, const float* __restrict__ linW2,
    const float* __restrict__ Wself, const float* __restrict__ bself,
    const float* __restrict__ linb1, const float* __restrict__ linb2,
    const float* __restrict__ postb1, const float* __restrict__ postb2,
    const float* __restrict__ alpha,
    half_t* __restrict__ WLg, half_t* __restrict__ WfinTg, float* __restrict__ bfin,
    const float* __restrict__ x,
    const float* __restrict__ preW1, const float* __restrict__ preW2,
    const float* __restrict__ preb1, const float* __restrict__ preb2,
    half_t* __restrict__ P1, half_t* __restrict__ P2,
    half_t* __restrict__ Q1, half_t* __restrict__ Q2, half_t* __restrict__ xh) {
    int tid = threadIdx.x;
    int b = blockIdx.x;
    if (b < 256) {
        __shared__ int hD[256], hS[256];
        hD[tid] = 0; hS[tid] = 0;
        __syncthreads();
        int chunk = (nE + 255) >> 8;
        int lo = b * chunk;
        int hi = lo + chunk; if (hi > nE) hi = nE;
        for (int e = lo + tid; e < hi; e += 256) {
            int s = ei[e], d = ei[nE + e];
            atomicAdd(&hD[d >> 8], 1);
            atomicAdd(&hS[s >> 8], 1);
        }
        __syncthreads();
        histD[tid * 256 + b] = hD[tid];
        histS[tid * 256 + b] = hS[tid];
    } else if (b < 320) {
        const float a = alpha[0];
        int id = (b - 256) * 256 + tid;
        const int stride = 64 * 256;
        for (int i = id; i < 24 * 16 * 72; i += stride) {
            int m = i / (16 * 72);
            int r = i % (16 * 72);
            int go = r / 72, k = r % 72;
            int d = m / 12, t = (m / 3) % 4, mat = m % 3;
            float v = 0.f;
            if (k < 64) {
                int stat = k >> 4, g = k & 15;
                int basep = (mat == 0) ? 1 : (mat == 1 ? 5 : 9);
                const float* pw = d ? postW2 : postW1;
                v = pw[t * 3328 + ((basep + stat) * 16 + g) * 16 + go];
            }
            WLg[i] = (half_t)v;
        }
        for (int i = id; i < 64 * 192; i += stride) {
            int o = i / 192, k = i % 192;
            float v;
            if (k < 64)       v = (1.f - a) * linW1[k * 64 + o];
            else if (k < 128) v = a * linW2[(k - 64) * 64 + o];
            else {
                int kx = k - 128, t = kx >> 4, f = kx & 15;
                v = Wself[kx * 64 + o];
                float s1 = 0.f, s2 = 0.f;
                for (int go = 0; go < 16; ++go) {
                    s1 += postW1[t * 3328 + f * 16 + go] * linW1[(t * 16 + go) * 64 + o];
                    s2 += postW2[t * 3328 + f * 16 + go] * linW2[(t * 16 + go) * 64 + o];
                }
                v += (1.f - a) * s1 + a * s2;
            }
            WfinTg[i] = (half_t)v;
        }
        for (int i = id; i < 64; i += stride) {
            float v = bself[i] + (1.f - a) * linb1[i] + a * linb2[i];
            for (int j = 0; j < 64; ++j)
                v += (1.f - a) * postb1[j] * linW1[j * 64 + i]
                   + a * postb2[j] * linW2[j * 64 + i];
            bfin[i] = v;
        }
    } else {
        int vb = b - 320;
        const int lane = tid & 63;
        const int t = lane >> 4, g = lane & 15;
        const int base = t << 4;
        float wsP1[16], wsP2[16], wsQ1[16], wsQ2[16];
#pragma unroll
        for (int f = 0; f < 16; ++f) {
            wsP1[f] = preW1[t * 512 + (16 + f) * 16 + g];
            wsP2[f] = preW2[t * 512 + (16 + f) * 16 + g];
            wsQ1[f] = preW1[t * 512 + f * 16 + g];
            wsQ2[f] = preW2[t * 512 + f * 16 + g];
        }
        const float pb1 = preb1[lane], pb2 = preb2[lane];
        int node = (vb * 256 + tid) >> 6;
        const int stride = (768 * 256) >> 6;
        for (; node < nN; node += stride) {
            float xv = x[(size_t)node * 64 + lane];
            float p1 = 0.f, p2 = 0.f, q1 = pb1, q2 = pb2;
#pragma unroll
            for (int f = 0; f < 16; ++f) {
                float v = __shfl(xv, base + f, 64);
                p1 = fmaf(v, wsP1[f], p1);
                p2 = fmaf(v, wsP2[f], p2);
                q1 = fmaf(v, wsQ1[f], q1);
                q2 = fmaf(v, wsQ2[f], q2);
            }
            size_t o = (size_t)node * 64 + lane;
            P1[o] = (half_t)p1;
            P2[o] = (half_t)p2;
            Q1[o] = (half_t)q1;
            Q2[o] = (half_t)q2;
            xh[o] = (half_t)xv;
        }
    }
}

// Two-level scan. scanA: per-1024 chunk local exclusive scan + chunk sums.
__global__ __launch_bounds__(256) void k_scanA(
    const int* __restrict__ cnt0, const int* __restrict__ cnt1,
    int* __restrict__ off0, int* __restrict__ off1,
    int* __restrict__ bsum, int n, int nchunk) {
    int arr = blockIdx.x >= nchunk;
    int c = blockIdx.x - (arr ? nchunk : 0);
    const int* cnt = arr ? cnt1 : cnt0;
    int* off = arr ? off1 : off0;
    int tid = threadIdx.x;
    int base = c * 1024 + tid * 4;
    int v[4];
#pragma unroll
    for (int k = 0; k < 4; ++k) { int i = base + k; v[k] = (i < n) ? cnt[i] : 0; }
    int tsum = v[0] + v[1] + v[2] + v[3];
    int lane = tid & 63, wid = tid >> 6;
    int incl = tsum;
#pragma unroll
    for (int d = 1; d < 64; d <<= 1) {
        int t = __shfl_up(incl, d, 64);
        if (lane >= d) incl += t;
    }
    __shared__ int ws[4];
    if (lane == 63) ws[wid] = incl;
    __syncthreads();
    int wpre = 0;
    for (int ww = 0; ww < wid; ++ww) wpre += ws[ww];
    int e = wpre + incl - tsum;
#pragma unroll
    for (int k = 0; k < 4; ++k) { int i = base + k; if (i < n) off[i] = e; e += v[k]; }
    if (tid == 255) bsum[blockIdx.x] = wpre + incl;
}

// scanB: add scanned chunk prefixes; write sentinel off[n]=total.
__global__ __launch_bounds__(256) void k_scanB(
    int* __restrict__ off0, int* __restrict__ off1,
    const int* __restrict__ bsum, int n, int nchunk) {
    int arr = blockIdx.x >= nchunk;
    int c = blockIdx.x - (arr ? nchunk : 0);
    int* off = arr ? off1 : off0;
    const int* bs = bsum + (arr ? nchunk : 0);
    __shared__ int pre_s, tot_s;
    int tid = threadIdx.x;
    if (tid < 64) {
        int v = (tid < nchunk) ? bs[tid] : 0;
        int incl = v;
#pragma unroll
        for (int d = 1; d < 64; d <<= 1) {
            int t = __shfl_up(incl, d, 64);
            if (tid >= d) incl += t;
        }
        if (tid == c) pre_s = incl - v;
        if (tid == nchunk - 1) tot_s = incl;
    }
    __syncthreads();
    int pre = pre_s;
    int base = c * 1024 + tid * 4;
#pragma unroll
    for (int k = 0; k < 4; ++k) {
        int i = base + k;
        if (i < n) off[i] += pre;
    }
    if (c == 0 && tid == 0) off[n] = tot_s;
}

// Binned placement at LDS-private cursors (block-private contiguous sub-regions).
__global__ __launch_bounds__(256) void k_bin(
    const int* __restrict__ ei, int nE, int nbuck,
    const int* __restrict__ curD, const int* __restrict__ curS,
    unsigned* __restrict__ binnedD, unsigned* __restrict__ binnedS) {
    __shared__ int cD[256], cS[256];
    int tid = threadIdx.x;
    int hb = blockIdx.x;
    if (tid < nbuck) {
        cD[tid] = curD[tid * 256 + hb];
        cS[tid] = curS[tid * 256 + hb];
    }
    __syncthreads();
    int chunk = (nE + 255) >> 8;
    int lo = hb * chunk;
    int hi = lo + chunk; if (hi > nE) hi = nE;
    for (int e = lo + tid; e < hi; e += 256) {
        int s = ei[e], d = ei[nE + e];
        unsigned pk = (unsigned)s | ((unsigned)d << 16);
        int p = atomicAdd(&cD[d >> 8], 1);
        binnedD[p] = pk;
        int q = atomicAdd(&cS[s >> 8], 1);
        binnedS[q] = pk;
    }
}

// Fine sort within each (bucket, dir): LDS count -> scan -> staged placement.
__global__ __launch_bounds__(256) void k_fine(
    const unsigned* __restrict__ binnedD, const unsigned* __restrict__ binnedS,
    const int* __restrict__ curD, const int* __restrict__ curS,
    int* __restrict__ off_dst, int* __restrict__ off_src,
    unsigned short* __restrict__ adj_dst, unsigned short* __restrict__ adj_src,
    int nE, int nN, int nbuck) {
    int bk = blockIdx.x;
    int dd = 0;
    if (bk >= nbuck) { dd = 1; bk -= nbuck; }
    const unsigned* binned = dd ? binnedS : binnedD;
    const int* cur = dd ? curS : curD;
    int* off = dd ? off_src : off_dst;
    unsigned short* adj = dd ? adj_src : adj_dst;
    __shared__ int ncnt[256];
    __shared__ int cur2[256];
    __shared__ unsigned short stage[FCAP];
    int tid = threadIdx.x;
    ncnt[tid] = 0;
    __syncthreads();
    int base = cur[bk * 256];
    int endp = cur[(bk + 1) * 256];
    int cntE = endp - base;
    int n0 = bk << 8;
    for (int i = tid; i < cntE; i += 256) {
        unsigned pk = binned[base + i];
        int key = dd ? (int)(pk & 0xFFFFu) : (int)(pk >> 16);
        atomicAdd(&ncnt[key - n0], 1);
    }
    __syncthreads();
    if (tid < 64) {
        int i4 = tid << 2;
        int v0 = ncnt[i4], v1 = ncnt[i4 + 1], v2 = ncnt[i4 + 2], v3 = ncnt[i4 + 3];
        int tsum = v0 + v1 + v2 + v3;
        int incl = tsum;
#pragma unroll
        for (int d = 1; d < 64; d <<= 1) {
            int t = __shfl_up(incl, d, 64);
            if (tid >= d) incl += t;
        }
        int excl = incl - tsum;
        ncnt[i4] = excl;
        ncnt[i4 + 1] = excl + v0;
        ncnt[i4 + 2] = excl + v0 + v1;
        ncnt[i4 + 3] = excl + v0 + v1 + v2;
    }
    __syncthreads();
    cur2[tid] = ncnt[tid];
    int node = n0 + tid;
    if (node < nN) off[node] = base + ncnt[tid];
    if (bk == nbuck - 1 && tid == 0) off[nN] = nE;
    __syncthreads();
    for (int i = tid; i < cntE; i += 256) {
        unsigned pk = binned[base + i];
        int key = dd ? (int)(pk & 0xFFFFu) : (int)(pk >> 16);
        int oth = dd ? (int)(pk >> 16) : (int)(pk & 0xFFFFu);
        int pos = atomicAdd(&cur2[key - n0], 1);
        if (pos < FCAP) stage[pos] = (unsigned short)oth;
        else adj[base + pos] = (unsigned short)oth;
    }
    __syncthreads();
    int lim = cntE < FCAP ? cntE : FCAP;
    for (int i = tid; i < lim; i += 256) adj[base + i] = stage[i];
}

// Gather: 16 lanes/neighbor x 4 features (half4/lane), 4 neighbors per wave-load.
// Adjacency register-resident (one ushort load + shfl broadcast); packed f16
// sum/sumsq accumulation; exact packed f16 min/max.
__global__ __launch_bounds__(256) void k_gather(
    const half_t* __restrict__ P1, const half_t* __restrict__ P2,
    const half_t* __restrict__ Q1, const half_t* __restrict__ Q2,
    const int* __restrict__ off1, const unsigned short* __restrict__ adj1,
    const int* __restrict__ off2, const unsigned short* __restrict__ adj2,
    half_t* __restrict__ agg1, half_t* __restrict__ agg2,
    float* __restrict__ amp1, float* __restrict__ ramp1,
    float* __restrict__ amp2, float* __restrict__ ramp2, int nN, int nE) {
    int tid = threadIdx.x;
    const int lane = tid & 63;
    const int grp = lane >> 4;       // neighbor slot 0..3
    const int fl = lane & 15;        // feature quad: features 4*fl..4*fl+3
    const int fl8 = fl << 3;         // byte offset into 128B P row
    int wstart = (blockIdx.x * blockDim.x + tid) >> 6;
    int wstride = (gridDim.x * blockDim.x) >> 6;
#pragma unroll
    for (int d = 0; d < 2; ++d) {
        const char* Pc = (const char*)(d ? P2 : P1);
        const char* Qc = (const char*)(d ? Q2 : Q1);
        const int* off = d ? off2 : off1;
        const unsigned short* adj = d ? adj2 : adj1;
        char* aggc = (char*)(d ? agg2 : agg1);
        float* ampA = d ? amp2 : amp1;
        float* rampA = d ? ramp2 : ramp1;
        for (int node = wstart; node < nN; node += wstride) {
            int beg = off[node], end = off[node + 1];
            int cnt = end - beg;
            int li = beg + lane;
            int adjv = adj[li < nE ? li : 0];
            half2v s01 = {(half_t)0, (half_t)0}, s23 = {(half_t)0, (half_t)0};
            half2v ss01 = {(half_t)0, (half_t)0}, ss23 = {(half_t)0, (half_t)0};
            unsigned mn0 = 0x7C007C00u, mn1 = 0x7C007C00u;
            unsigned mx0 = 0xFC00FC00u, mx1 = 0xFC00FC00u;
            int jm = (cnt < 64) ? (cnt & ~7) : 64;
            int j = 0;
            for (; j + 8 <= jm; j += 8) {
                int na = __shfl(adjv, j + grp, 64);
                int nb = __shfl(adjv, j + 4 + grp, 64);
                uint2 ua = *(const uint2*)(Pc + na * 128 + fl8);
                uint2 ub = *(const uint2*)(Pc + nb * 128 + fl8);
                half2v a0 = u2h(ua.x), a1 = u2h(ua.y);
                half2v b0 = u2h(ub.x), b1 = u2h(ub.y);
                s01 += a0 + b0; s23 += a1 + b1;
                ss01 += a0 * a0; ss23 += a1 * a1;
                ss01 += b0 * b0; ss23 += b1 * b1;
                mn0 = pkmin(mn0, pkmin(ua.x, ub.x));
                mn1 = pkmin(mn1, pkmin(ua.y, ub.y));
                mx0 = pkmax(mx0, pkmax(ua.x, ub.x));
                mx1 = pkmax(mx1, pkmax(ua.y, ub.y));
            }
            for (int jj = beg + j; jj < end; jj += 4) {
                int idx = jj + grp;
                if (idx < end) {
                    int nc = adj[idx];
                    uint2 uc = *(const uint2*)(Pc + nc * 128 + fl8);
                    half2v c0 = u2h(uc.x), c1 = u2h(uc.y);
                    s01 += c0; s23 += c1;
                    ss01 += c0 * c0; ss23 += c1 * c1;
                    mn0 = pkmin(mn0, uc.x); mn1 = pkmin(mn1, uc.y);
                    mx0 = pkmax(mx0, uc.x); mx1 = pkmax(mx1, uc.y);
                }
            }
#pragma unroll
            for (int sh = 16; sh <= 32; sh <<= 1) {
                s01 += i2h(__shfl_xor(h2i(s01), sh, 64));
                s23 += i2h(__shfl_xor(h2i(s23), sh, 64));
                ss01 += i2h(__shfl_xor(h2i(ss01), sh, 64));
                ss23 += i2h(__shfl_xor(h2i(ss23), sh, 64));
                mn0 = pkmin(mn0, (unsigned)__shfl_xor((int)mn0, sh, 64));
                mn1 = pkmin(mn1, (unsigned)__shfl_xor((int)mn1, sh, 64));
                mx0 = pkmax(mx0, (unsigned)__shfl_xor((int)mx0, sh, 64));
                mx1 = pkmax(mx1, (unsigned)__shfl_xor((int)mx1, sh, 64));
            }
            float deg = (cnt > 0) ? (float)cnt : 1.0f;
            float inv = 1.0f / deg;
            float se0 = (float)s01[0], se1 = (float)s01[1];
            float se2 = (float)s23[0], se3 = (float)s23[1];
            float sq0 = (float)ss01[0], sq1 = (float)ss01[1];
            float sq2 = (float)ss23[0], sq3 = (float)ss23[1];
            float me0 = se0 * inv, me1 = se1 * inv, me2 = se2 * inv, me3 = se3 * inv;
            float st0 = sqrtf(fmaxf(fmaf(-me0, me0, sq0 * inv), 0.f) + 1e-5f);
            float st1 = sqrtf(fmaxf(fmaf(-me1, me1, sq1 * inv), 0.f) + 1e-5f);
            float st2 = sqrtf(fmaxf(fmaf(-me2, me2, sq2 * inv), 0.f) + 1e-5f);
            float st3 = sqrtf(fmaxf(fmaf(-me3, me3, sq3 * inv), 0.f) + 1e-5f);
            uint2 qu = *(const uint2*)(Qc + node * 128 + fl8);
            half2v q01 = u2h(qu.x), q23 = u2h(qu.y);
            half2v hm01, hm23, hl01, hl23, hh01, hh23;
            if (cnt > 0) {
                hm01 = q01 + pkrtz(me0, me1);
                hm23 = q23 + pkrtz(me2, me3);
                hl01 = q01 + u2h(mn0); hl23 = q23 + u2h(mn1);
                hh01 = q01 + u2h(mx0); hh23 = q23 + u2h(mx1);
            } else {
                half2v z = {(half_t)0, (half_t)0};
                hm01 = z; hm23 = z; hl01 = z; hl23 = z; hh01 = z; hh23 = z;
            }
            half2v hs01 = pkrtz(st0, st1);
            half2v hs23 = pkrtz(st2, st3);
            if (lane < 16) {
                char* ab = aggc + (size_t)node * 512 + (fl >> 2) * 128 + (fl & 3) * 8;
                uint2 w0; w0.x = (unsigned)h2i(hm01); w0.y = (unsigned)h2i(hm23);
                uint2 w1; w1.x = (unsigned)h2i(hl01); w1.y = (unsigned)h2i(hl23);
                uint2 w2; w2.x = (unsigned)h2i(hh01); w2.y = (unsigned)h2i(hh23);
                uint2 w3; w3.x = (unsigned)h2i(hs01); w3.y = (unsigned)h2i(hs23);
                *(uint2*)(ab)      = w0;
                *(uint2*)(ab + 32) = w1;
                *(uint2*)(ab + 64) = w2;
                *(uint2*)(ab + 96) = w3;
            }
            if (lane == 0) {
                float ampv = __log2f(deg + 1.0f) * 0.24465054f;  // 1/log2(17)
                ampA[node] = ampv;
                rampA[node] = 1.0f / ampv;
            }
        }
    }
}

// Persistent MFMA pass, swapped operands, x read as f16.
__global__ __launch_bounds__(256, 2) void k_c(
    const half_t* __restrict__ xh,
    const half_t* __restrict__ agg1, const half_t* __restrict__ agg2,
    const float* __restrict__ amp1, const float* __restrict__ ramp1,
    const float* __restrict__ amp2, const float* __restrict__ ramp2,
    const half_t* __restrict__ WLg, const half_t* __restrict__ WfinT,
    const float* __restrict__ bfin, float* __restrict__ out, int nN) {
    __shared__ half_t WLs[24 * 16 * 72];
    __shared__ half_t osb[4 * 16 * 72];
    int tid = threadIdx.x;
    {
        const uint4* src = (const uint4*)WLg;
        uint4* dst = (uint4*)WLs;
        for (int i = tid; i < (24 * 16 * 72) / 8; i += 256) dst[i] = src[i];
    }
    __syncthreads();
    int w = tid >> 6, lane = tid & 63;
    int l15 = lane & 15, g4 = lane >> 4;
    half_t* ow = osb + w * (16 * 72) + l15 * 72;
    half8 wfr[4][6];
#pragma unroll
    for (int ct = 0; ct < 4; ++ct)
#pragma unroll
        for (int kk = 0; kk < 6; ++kk)
            wfr[ct][kk] = *(const half8*)(WfinT + (ct * 16 + l15) * 192 + kk * 32 + g4 * 8);
    float4 bf4[4];
#pragma unroll
    for (int ct = 0; ct < 4; ++ct)
        bf4[ct] = *(const float4*)(bfin + ct * 16 + g4 * 4);
    int nwaves = gridDim.x * 4;
    int wgid = blockIdx.x * 4 + w;
    int ntiles = (nN + 15) >> 4;
    for (int tile = wgid; tile < ntiles; tile += nwaves) {
        int nrow = (tile << 4) + l15;
        int nrowc = (nrow < nN) ? nrow : (nN - 1);
        half8 xbf[2];
#pragma unroll
        for (int ks = 0; ks < 2; ++ks)
            xbf[ks] = *(const half8*)(xh + (size_t)nrowc * 64 + ks * 32 + g4 * 8);
        f32x4 accY[4] = {{0,0,0,0},{0,0,0,0},{0,0,0,0},{0,0,0,0}};
#pragma unroll
        for (int d = 0; d < 2; ++d) {
            const half_t* agg = d ? agg2 : agg1;
            float ampv = (d ? amp2 : amp1)[nrowc];
            float rampv = (d ? ramp2 : ramp1)[nrowc];
#pragma unroll
            for (int t = 0; t < 4; ++t) {
                half8 b0 = *(const half8*)(agg + (size_t)nrowc * 256 + t * 64 + g4 * 8);
                half8 b1 = *(const half8*)(agg + (size_t)nrowc * 256 + t * 64 + 32 + g4 * 8);
                const half_t* wb = WLs + ((d * 12 + t * 3) * 16 + l15) * 72 + g4 * 8;
                half8 aA0 = *(const half8*)(wb);
                half8 aA1 = *(const half8*)(wb + 32);
                half8 aB0 = *(const half8*)(wb + 16 * 72);
                half8 aB1 = *(const half8*)(wb + 16 * 72 + 32);
                half8 aE0 = *(const half8*)(wb + 32 * 72);
                half8 aE1 = *(const half8*)(wb + 32 * 72 + 32);
                f32x4 zA = {0,0,0,0}, zB = {0,0,0,0}, zE = {0,0,0,0};
                zA = __builtin_amdgcn_mfma_f32_16x16x32_f16(aA0, b0, zA, 0, 0, 0);
                zA = __builtin_amdgcn_mfma_f32_16x16x32_f16(aA1, b1, zA, 0, 0, 0);
                zB = __builtin_amdgcn_mfma_f32_16x16x32_f16(aB0, b0, zB, 0, 0, 0);
                zB = __builtin_amdgcn_mfma_f32_16x16x32_f16(aB1, b1, zB, 0, 0, 0);
                zE = __builtin_amdgcn_mfma_f32_16x16x32_f16(aE0, b0, zE, 0, 0, 0);
                zE = __builtin_amdgcn_mfma_f32_16x16x32_f16(aE1, b1, zE, 0, 0, 0);
                float o0 = zA[0] + ampv * zB[0] + rampv * zE[0];
                float o1 = zA[1] + ampv * zB[1] + rampv * zE[1];
                float o2 = zA[2] + ampv * zB[2] + rampv * zE[2];
                float o3 = zA[3] + ampv * zB[3] + rampv * zE[3];
                half2v p0; p0[0] = (half_t)o0; p0[1] = (half_t)o1;
                half2v p1; p1[0] = (half_t)o2; p1[1] = (half_t)o3;
                *(half2v*)(ow + t * 16 + g4 * 4) = p0;
                *(half2v*)(ow + t * 16 + g4 * 4 + 2) = p1;
            }
#pragma unroll
            for (int ks = 0; ks < 2; ++ks) {
                half8 ob = *(const half8*)(ow + ks * 32 + g4 * 8);
#pragma unroll
                for (int ct = 0; ct < 4; ++ct)
                    accY[ct] = __builtin_amdgcn_mfma_f32_16x16x32_f16(wfr[ct][d * 2 + ks], ob, accY[ct], 0, 0, 0);
            }
        }
#pragma unroll
        for (int ks = 0; ks < 2; ++ks)
#pragma unroll
            for (int ct = 0; ct < 4; ++ct)
                accY[ct] = __builtin_amdgcn_mfma_f32_16x16x32_f16(wfr[ct][4 + ks], xbf[ks], accY[ct], 0, 0, 0);
        if (nrow < nN) {
#pragma unroll
            for (int ct = 0; ct < 4; ++ct) {
                float4 st;
                st.x = accY[ct][0] + bf4[ct].x;
                st.y = accY[ct][1] + bf4[ct].y;
                st.z = accY[ct][2] + bf4[ct].z;
                st.w = accY[ct][3] + bf4[ct].w;
                *(float4*)(out + (size_t)nrow * 64 + ct * 16 + g4 * 4) = st;
            }
        }
    }
}

extern "C" void kernel_launch(void* const* d_in, const int* in_sizes, int n_in,
                              void* d_out, int out_size, void* d_ws, size_t ws_size,
                              hipStream_t stream) {
    const float* x      = (const float*)d_in[0];
    const int*   ei     = (const int*)d_in[1];
    const float* alpha  = (const float*)d_in[2];
    const float* Wself  = (const float*)d_in[3];
    const float* bself  = (const float*)d_in[4];
    const float* preW1  = (const float*)d_in[5];
    const float* preb1  = (const float*)d_in[6];
    const float* postW1 = (const float*)d_in[7];
    const float* postb1 = (const float*)d_in[8];
    const float* linW1  = (const float*)d_in[9];
    const float* linb1  = (const float*)d_in[10];
    const float* preW2  = (const float*)d_in[11];
    const float* preb2  = (const float*)d_in[12];
    const float* postW2 = (const float*)d_in[13];
    const float* postb2 = (const float*)d_in[14];
    const float* linW2  = (const float*)d_in[15];
    const float* linb2  = (const float*)d_in[16];
    float* out = (float*)d_out;
    const int nN = in_sizes[0] / 64;
    const int nE = in_sizes[1] / 2;
    const int nbuck = (nN + 255) >> 8;
    const int nH = nbuck * 256;
    const int nchunk = (nH + 1023) >> 10;

    char* w = (char*)d_ws;
    size_t ofs = 0;
    auto alloc = [&](size_t bytes) {
        char* p = w + ofs;
        ofs = (ofs + bytes + 255) & ~(size_t)255;
        return p;
    };
    half_t* P1   = (half_t*)alloc((size_t)nN * 64 * 2);
    half_t* P2   = (half_t*)alloc((size_t)nN * 64 * 2);
    half_t* Q1   = (half_t*)alloc((size_t)nN * 64 * 2);
    half_t* Q2   = (half_t*)alloc((size_t)nN * 64 * 2);
    half_t* xh   = (half_t*)alloc((size_t)nN * 64 * 2);
    half_t* agg1 = (half_t*)alloc((size_t)nN * 256 * 2);
    half_t* agg2 = (half_t*)alloc((size_t)nN * 256 * 2);
    float* amp1  = (float*)alloc((size_t)nN * 4);
    float* ramp1 = (float*)alloc((size_t)nN * 4);
    float* amp2  = (float*)alloc((size_t)nN * 4);
    float* ramp2 = (float*)alloc((size_t)nN * 4);
    half_t* WLg   = (half_t*)alloc(24 * 16 * 72 * 2);
    half_t* WfinT = (half_t*)alloc(64 * 192 * 2);
    float* bfin   = (float*)alloc(64 * 4);
    int* histD = (int*)alloc(256 * 256 * 4);
    int* histS = (int*)alloc(256 * 256 * 4);
    int* curD  = (int*)alloc((256 * 256 + 1) * 4);
    int* curS  = (int*)alloc((256 * 256 + 1) * 4);
    unsigned* binnedD = (unsigned*)alloc((size_t)nE * 4);
    unsigned* binnedS = (unsigned*)alloc((size_t)nE * 4);
    int* off_dst = (int*)alloc((size_t)(nN + 1) * 4);
    int* off_src = (int*)alloc((size_t)(nN + 1) * 4);
    unsigned short* adj_dst = (unsigned short*)alloc((size_t)nE * 2);
    unsigned short* adj_src = (unsigned short*)alloc((size_t)nE * 2);
    int* bsum = (int*)alloc(2 * 64 * 4);

    k_pre<<<1088, 256, 0, stream>>>(ei, nE, nN, histD, histS,
                                    postW1, postW2, linW1, linW2, Wself, bself,
                                    linb1, linb2, postb1, postb2, alpha,
                                    WLg, WfinT, bfin,
                                    x, preW1, preW2, preb1, preb2,
                                    P1, P2, Q1, Q2, xh);
    k_scanA<<<2 * nchunk, 256, 0, stream>>>(histD, histS, curD, curS, bsum, nH, nchunk);
    k_scanB<<<2 * nchunk, 256, 0, stream>>>(curD, curS, bsum, nH, nchunk);
    k_bin<<<256, 256, 0, stream>>>(ei, nE, nbuck, curD, curS, binnedD, binnedS);
    k_fine<<<2 * nbuck, 256, 0, stream>>>(binnedD, binnedS, curD, curS,
                                          off_dst, off_src, adj_dst, adj_src,
                                          nE, nN, nbuck);
    k_gather<<<2048, 256, 0, stream>>>(P1, P2, Q1, Q2, off_dst, adj_dst, off_src, adj_src,
                                       agg1, agg2, amp1, ramp1, amp2, ramp2, nN, nE);
    k_c<<<512, 256, 0, stream>>>(xh, agg1, agg2, amp1, ramp1, amp2, ramp2,
                                 WLg, WfinT, bfin, out, nN);
}

// Round 10
// 138.737 us; speedup vs baseline: 14.5909x; 1.1295x over previous
//
#include <hip/hip_runtime.h>
#include <math.h>

// DirPNAConv: N=50000, E=800000, D=64, T=4, FI=FO=16.
// m[e] = Q[recv] + P[send] -> gather-stats of P + per-node Q shift (Q precomputed f16).
// Tower block-diagonality: post layer = per-tower K=64 GEMMs; x@Wx and postb folded
// through lin into Wfin/bfin. k_c: oT = W@aggT per tower (swapped operands),
// wave-private LDS bounce, y^T = WfinT@[o1,o2,x]^T.
// Graph build: atomic-free counting sort. Gather: 16-lane-group-per-node (no
// cross-lane reduction, no shfl broadcast, fully-useful epilogue), packed f16 accum.

typedef _Float16 half_t;
typedef __attribute__((ext_vector_type(8))) _Float16 half8;
typedef __attribute__((ext_vector_type(2))) _Float16 half2v;
typedef __attribute__((ext_vector_type(4))) float f32x4;

#define FCAP 12288

static __device__ __forceinline__ unsigned pkmin(unsigned a, unsigned b) {
    unsigned r;
    asm("v_pk_min_f16 %0, %1, %2" : "=v"(r) : "v"(a), "v"(b));
    return r;
}
static __device__ __forceinline__ unsigned pkmax(unsigned a, unsigned b) {
    unsigned r;
    asm("v_pk_max_f16 %0, %1, %2" : "=v"(r) : "v"(a), "v"(b));
    return r;
}
static __device__ __forceinline__ int h2i(half2v h) { return __builtin_bit_cast(int, h); }
static __device__ __forceinline__ half2v u2h(unsigned i) { return __builtin_bit_cast(half2v, i); }
static __device__ __forceinline__ half2v pkrtz(float a, float b) {
    return __builtin_bit_cast(half2v, __builtin_amdgcn_cvt_pkrtz(a, b));
}

// ---- fused: LDS edge histogram | weight prep | P,Q,xh projection ----
__global__ __launch_bounds__(256) void k_pre(
    const int* __restrict__ ei, int nE, int nN,
    int* __restrict__ histD, int* __restrict__ histS,
    const float* __restrict__ postW1, const float* __restrict__ postW2,
    const float* __restrict__ linW1, const float* __restrict__ linW2,
    const float* __restrict__ Wself, const float* __restrict__ bself,
    const float* __restrict__ linb1, const float* __restrict__ linb2,
    const float* __restrict__ postb1, const float* __restrict__ postb2,
    const float* __restrict__ alpha,
    half_t* __restrict__ WLg, half_t* __restrict__ WfinTg, float* __restrict__ bfin,
    const float* __restrict__ x,
    const float* __restrict__ preW1, const float* __restrict__ preW2,
    const float* __restrict__ preb1, const float* __restrict__ preb2,
    half_t* __restrict__ P1, half_t* __restrict__ P2,
    half_t* __restrict__ Q1, half_t* __restrict__ Q2, half_t* __restrict__ xh) {
    int tid = threadIdx.x;
    int b = blockIdx.x;
    if (b < 256) {
        __shared__ int hD[256], hS[256];
        hD[tid] = 0; hS[tid] = 0;
        __syncthreads();
        int chunk = (nE + 255) >> 8;
        int lo = b * chunk;
        int hi = lo + chunk; if (hi > nE) hi = nE;
        for (int e = lo + tid; e < hi; e += 256) {
            int s = ei[e], d = ei[nE + e];
            atomicAdd(&hD[d >> 8], 1);
            atomicAdd(&hS[s >> 8], 1);
        }
        __syncthreads();
        histD[tid * 256 + b] = hD[tid];
        histS[tid * 256 + b] = hS[tid];
    } else if (b < 320) {
        const float a = alpha[0];
        int id = (b - 256) * 256 + tid;
        const int stride = 64 * 256;
        for (int i = id; i < 24 * 16 * 72; i += stride) {
            int m = i / (16 * 72);
            int r = i % (16 * 72);
            int go = r / 72, k = r % 72;
            int d = m / 12, t = (m / 3) % 4, mat = m % 3;
            float v = 0.f;
            if (k < 64) {
                int stat = k >> 4, g = k & 15;
                int basep = (mat == 0) ? 1 : (mat == 1 ? 5 : 9);
                const float* pw = d ? postW2 : postW1;
                v = pw[t * 3328 + ((basep + stat) * 16 + g) * 16 + go];
            }
            WLg[i] = (half_t)v;
        }
        for (int i = id; i < 64 * 192; i += stride) {
            int o = i / 192, k = i % 192;
            float v;
            if (k < 64)       v = (1.f - a) * linW1[k * 64 + o];
            else if (k < 128) v = a * linW2[(k - 64) * 64 + o];
            else {
                int kx = k - 128, t = kx >> 4, f = kx & 15;
                v = Wself[kx * 64 + o];
                float s1 = 0.f, s2 = 0.f;
                for (int go = 0; go < 16; ++go) {
                    s1 += postW1[t * 3328 + f * 16 + go] * linW1[(t * 16 + go) * 64 + o];
                    s2 += postW2[t * 3328 + f * 16 + go] * linW2[(t * 16 + go) * 64 + o];
                }
                v += (1.f - a) * s1 + a * s2;
            }
            WfinTg[i] = (half_t)v;
        }
        for (int i = id; i < 64; i += stride) {
            float v = bself[i] + (1.f - a) * linb1[i] + a * linb2[i];
            for (int j = 0; j < 64; ++j)
                v += (1.f - a) * postb1[j] * linW1[j * 64 + i]
                   + a * postb2[j] * linW2[j * 64 + i];
            bfin[i] = v;
        }
    } else {
        int vb = b - 320;
        const int lane = tid & 63;
        const int t = lane >> 4, g = lane & 15;
        const int base = t << 4;
        float wsP1[16], wsP2[16], wsQ1[16], wsQ2[16];
#pragma unroll
        for (int f = 0; f < 16; ++f) {
            wsP1[f] = preW1[t * 512 + (16 + f) * 16 + g];
            wsP2[f] = preW2[t * 512 + (16 + f) * 16 + g];
            wsQ1[f] = preW1[t * 512 + f * 16 + g];
            wsQ2[f] = preW2[t * 512 + f * 16 + g];
        }
        const float pb1 = preb1[lane], pb2 = preb2[lane];
        int node = (vb * 256 + tid) >> 6;
        const int stride = (768 * 256) >> 6;
        for (; node < nN; node += stride) {
            float xv = x[(size_t)node * 64 + lane];
            float p1 = 0.f, p2 = 0.f, q1 = pb1, q2 = pb2;
#pragma unroll
            for (int f = 0; f < 16; ++f) {
                float v = __shfl(xv, base + f, 64);
                p1 = fmaf(v, wsP1[f], p1);
                p2 = fmaf(v, wsP2[f], p2);
                q1 = fmaf(v, wsQ1[f], q1);
                q2 = fmaf(v, wsQ2[f], q2);
            }
            size_t o = (size_t)node * 64 + lane;
            P1[o] = (half_t)p1;
            P2[o] = (half_t)p2;
            Q1[o] = (half_t)q1;
            Q2[o] = (half_t)q2;
            xh[o] = (half_t)xv;
        }
    }
}

// Two-level scan. scanA: per-1024 chunk local exclusive scan + chunk sums.
__global__ __launch_bounds__(256) void k_scanA(
    const int* __restrict__ cnt0, const int* __restrict__ cnt1,
    int* __restrict__ off0, int* __restrict__ off1,
    int* __restrict__ bsum, int n, int nchunk) {
    int arr = blockIdx.x >= nchunk;
    int c = blockIdx.x - (arr ? nchunk : 0);
    const int* cnt = arr ? cnt1 : cnt0;
    int* off = arr ? off1 : off0;
    int tid = threadIdx.x;
    int base = c * 1024 + tid * 4;
    int v[4];
#pragma unroll
    for (int k = 0; k < 4; ++k) { int i = base + k; v[k] = (i < n) ? cnt[i] : 0; }
    int tsum = v[0] + v[1] + v[2] + v[3];
    int lane = tid & 63, wid = tid >> 6;
    int incl = tsum;
#pragma unroll
    for (int d = 1; d < 64; d <<= 1) {
        int t = __shfl_up(incl, d, 64);
        if (lane >= d) incl += t;
    }
    __shared__ int ws[4];
    if (lane == 63) ws[wid] = incl;
    __syncthreads();
    int wpre = 0;
    for (int ww = 0; ww < wid; ++ww) wpre += ws[ww];
    int e = wpre + incl - tsum;
#pragma unroll
    for (int k = 0; k < 4; ++k) { int i = base + k; if (i < n) off[i] = e; e += v[k]; }
    if (tid == 255) bsum[blockIdx.x] = wpre + incl;
}

// scanB: add scanned chunk prefixes; write sentinel off[n]=total.
__global__ __launch_bounds__(256) void k_scanB(
    int* __restrict__ off0, int* __restrict__ off1,
    const int* __restrict__ bsum, int n, int nchunk) {
    int arr = blockIdx.x >= nchunk;
    int c = blockIdx.x - (arr ? nchunk : 0);
    int* off = arr ? off1 : off0;
    const int* bs = bsum + (arr ? nchunk : 0);
    __shared__ int pre_s, tot_s;
    int tid = threadIdx.x;
    if (tid < 64) {
        int v = (tid < nchunk) ? bs[tid] : 0;
        int incl = v;
#pragma unroll
        for (int d = 1; d < 64; d <<= 1) {
            int t = __shfl_up(incl, d, 64);
            if (tid >= d) incl += t;
        }
        if (tid == c) pre_s = incl - v;
        if (tid == nchunk - 1) tot_s = incl;
    }
    __syncthreads();
    int pre = pre_s;
    int base = c * 1024 + tid * 4;
#pragma unroll
    for (int k = 0; k < 4; ++k) {
        int i = base + k;
        if (i < n) off[i] += pre;
    }
    if (c == 0 && tid == 0) off[n] = tot_s;
}

// Binned placement at LDS-private cursors (block-private contiguous sub-regions).
__global__ __launch_bounds__(256) void k_bin(
    const int* __restrict__ ei, int nE, int nbuck,
    const int* __restrict__ curD, const int* __restrict__ curS,
    unsigned* __restrict__ binnedD, unsigned* __restrict__ binnedS) {
    __shared__ int cD[256], cS[256];
    int tid = threadIdx.x;
    int hb = blockIdx.x;
    if (tid < nbuck) {
        cD[tid] = curD[tid * 256 + hb];
        cS[tid] = curS[tid * 256 + hb];
    }
    __syncthreads();
    int chunk = (nE + 255) >> 8;
    int lo = hb * chunk;
    int hi = lo + chunk; if (hi > nE) hi = nE;
    for (int e = lo + tid; e < hi; e += 256) {
        int s = ei[e], d = ei[nE + e];
        unsigned pk = (unsigned)s | ((unsigned)d << 16);
        int p = atomicAdd(&cD[d >> 8], 1);
        binnedD[p] = pk;
        int q = atomicAdd(&cS[s >> 8], 1);
        binnedS[q] = pk;
    }
}

// Fine sort within each (bucket, dir): LDS count -> scan -> staged placement.
__global__ __launch_bounds__(256) void k_fine(
    const unsigned* __restrict__ binnedD, const unsigned* __restrict__ binnedS,
    const int* __restrict__ curD, const int* __restrict__ curS,
    int* __restrict__ off_dst, int* __restrict__ off_src,
    unsigned short* __restrict__ adj_dst, unsigned short* __restrict__ adj_src,
    int nE, int nN, int nbuck) {
    int bk = blockIdx.x;
    int dd = 0;
    if (bk >= nbuck) { dd = 1; bk -= nbuck; }
    const unsigned* binned = dd ? binnedS : binnedD;
    const int* cur = dd ? curS : curD;
    int* off = dd ? off_src : off_dst;
    unsigned short* adj = dd ? adj_src : adj_dst;
    __shared__ int ncnt[256];
    __shared__ int cur2[256];
    __shared__ unsigned short stage[FCAP];
    int tid = threadIdx.x;
    ncnt[tid] = 0;
    __syncthreads();
    int base = cur[bk * 256];
    int endp = cur[(bk + 1) * 256];
    int cntE = endp - base;
    int n0 = bk << 8;
    for (int i = tid; i < cntE; i += 256) {
        unsigned pk = binned[base + i];
        int key = dd ? (int)(pk & 0xFFFFu) : (int)(pk >> 16);
        atomicAdd(&ncnt[key - n0], 1);
    }
    __syncthreads();
    if (tid < 64) {
        int i4 = tid << 2;
        int v0 = ncnt[i4], v1 = ncnt[i4 + 1], v2 = ncnt[i4 + 2], v3 = ncnt[i4 + 3];
        int tsum = v0 + v1 + v2 + v3;
        int incl = tsum;
#pragma unroll
        for (int d = 1; d < 64; d <<= 1) {
            int t = __shfl_up(incl, d, 64);
            if (tid >= d) incl += t;
        }
        int excl = incl - tsum;
        ncnt[i4] = excl;
        ncnt[i4 + 1] = excl + v0;
        ncnt[i4 + 2] = excl + v0 + v1;
        ncnt[i4 + 3] = excl + v0 + v1 + v2;
    }
    __syncthreads();
    cur2[tid] = ncnt[tid];
    int node = n0 + tid;
    if (node < nN) off[node] = base + ncnt[tid];
    if (bk == nbuck - 1 && tid == 0) off[nN] = nE;
    __syncthreads();
    for (int i = tid; i < cntE; i += 256) {
        unsigned pk = binned[base + i];
        int key = dd ? (int)(pk & 0xFFFFu) : (int)(pk >> 16);
        int oth = dd ? (int)(pk >> 16) : (int)(pk & 0xFFFFu);
        int pos = atomicAdd(&cur2[key - n0], 1);
        if (pos < FCAP) stage[pos] = (unsigned short)oth;
        else adj[base + pos] = (unsigned short)oth;
    }
    __syncthreads();
    int lim = cntE < FCAP ? cntE : FCAP;
    for (int i = tid; i < lim; i += 256) adj[base + i] = stage[i];
}

// Gather: 16-lane group per node; lane fl holds features 4fl..4fl+3.
// No cross-lane reduction (reduce dim = neighbor loop); no shfl broadcast;
// epilogue fully lane-useful (4 nodes per wave). Packed f16 accumulation.
__global__ __launch_bounds__(256) void k_gather(
    const half_t* __restrict__ P1, const half_t* __restrict__ P2,
    const half_t* __restrict__ Q1, const half_t* __restrict__ Q2,
    const int* __restrict__ off1, const unsigned short* __restrict__ adj1,
    const int* __restrict__ off2, const unsigned short* __restrict__ adj2,
    half_t* __restrict__ agg1, half_t* __restrict__ agg2,
    float* __restrict__ amp1, float* __restrict__ ramp1,
    float* __restrict__ amp2, float* __restrict__ ramp2, int nN, int nE) {
    int tid = threadIdx.x;
    const int lane = tid & 63;
    const int g = lane >> 4;         // node slot within wave (0..3)
    const int fl = lane & 15;        // feature quad: features 4*fl..4*fl+3
    const int fl8 = fl << 3;         // byte offset into 128B P row
    int w4 = (blockIdx.x * 256 + tid) >> 6;      // wave index
    int wstride = (gridDim.x * 256) >> 6;
    int ngroups = (nN + 3) >> 2;
#pragma unroll
    for (int d = 0; d < 2; ++d) {
        const char* Pc = (const char*)(d ? P2 : P1);
        const char* Qc = (const char*)(d ? Q2 : Q1);
        const int* off = d ? off2 : off1;
        const unsigned short* adj = d ? adj2 : adj1;
        char* aggc = (char*)(d ? agg2 : agg1);
        float* ampA = d ? amp2 : amp1;
        float* rampA = d ? ramp2 : ramp1;
        for (int gi = w4; gi < ngroups; gi += wstride) {
            int node = gi * 4 + g;
            bool act = node < nN;
            int nodec = act ? node : (nN - 1);
            int beg = off[nodec], end = off[nodec + 1];
            int cnt = end - beg;
            half2v s01 = {(half_t)0, (half_t)0}, s23 = {(half_t)0, (half_t)0};
            half2v ss01 = {(half_t)0, (half_t)0}, ss23 = {(half_t)0, (half_t)0};
            unsigned mn0 = 0x7C007C00u, mn1 = 0x7C007C00u;
            unsigned mx0 = 0xFC00FC00u, mx1 = 0xFC00FC00u;
            int j = beg;
            for (; j + 4 <= end; j += 4) {
                int n0 = adj[j + 0];
                int n1 = adj[j + 1];
                int n2 = adj[j + 2];
                int n3 = adj[j + 3];
                uint2 u0 = *(const uint2*)(Pc + n0 * 128 + fl8);
                uint2 u1 = *(const uint2*)(Pc + n1 * 128 + fl8);
                uint2 u2 = *(const uint2*)(Pc + n2 * 128 + fl8);
                uint2 u3 = *(const uint2*)(Pc + n3 * 128 + fl8);
                half2v a0 = u2h(u0.x), a1 = u2h(u0.y);
                half2v b0 = u2h(u1.x), b1 = u2h(u1.y);
                half2v c0 = u2h(u2.x), c1 = u2h(u2.y);
                half2v e0 = u2h(u3.x), e1 = u2h(u3.y);
                s01 += (a0 + b0) + (c0 + e0);
                s23 += (a1 + b1) + (c1 + e1);
                ss01 += a0 * a0; ss23 += a1 * a1;
                ss01 += b0 * b0; ss23 += b1 * b1;
                ss01 += c0 * c0; ss23 += c1 * c1;
                ss01 += e0 * e0; ss23 += e1 * e1;
                mn0 = pkmin(mn0, pkmin(pkmin(u0.x, u1.x), pkmin(u2.x, u3.x)));
                mn1 = pkmin(mn1, pkmin(pkmin(u0.y, u1.y), pkmin(u2.y, u3.y)));
                mx0 = pkmax(mx0, pkmax(pkmax(u0.x, u1.x), pkmax(u2.x, u3.x)));
                mx1 = pkmax(mx1, pkmax(pkmax(u0.y, u1.y), pkmax(u2.y, u3.y)));
            }
            for (; j < end; ++j) {
                int n0 = adj[j];
                uint2 u0 = *(const uint2*)(Pc + n0 * 128 + fl8);
                half2v a0 = u2h(u0.x), a1 = u2h(u0.y);
                s01 += a0; s23 += a1;
                ss01 += a0 * a0; ss23 += a1 * a1;
                mn0 = pkmin(mn0, u0.x); mn1 = pkmin(mn1, u0.y);
                mx0 = pkmax(mx0, u0.x); mx1 = pkmax(mx1, u0.y);
            }
            float deg = (cnt > 0) ? (float)cnt : 1.0f;
            float inv = 1.0f / deg;
            float se0 = (float)s01[0], se1 = (float)s01[1];
            float se2 = (float)s23[0], se3 = (float)s23[1];
            float sq0 = (float)ss01[0], sq1 = (float)ss01[1];
            float sq2 = (float)ss23[0], sq3 = (float)ss23[1];
            float me0 = se0 * inv, me1 = se1 * inv, me2 = se2 * inv, me3 = se3 * inv;
            float st0 = sqrtf(fmaxf(fmaf(-me0, me0, sq0 * inv), 0.f) + 1e-5f);
            float st1 = sqrtf(fmaxf(fmaf(-me1, me1, sq1 * inv), 0.f) + 1e-5f);
            float st2 = sqrtf(fmaxf(fmaf(-me2, me2, sq2 * inv), 0.f) + 1e-5f);
            float st3 = sqrtf(fmaxf(fmaf(-me3, me3, sq3 * inv), 0.f) + 1e-5f);
            uint2 qu = *(const uint2*)(Qc + nodec * 128 + fl8);
            half2v q01 = u2h(qu.x), q23 = u2h(qu.y);
            half2v hm01, hm23, hl01, hl23, hh01, hh23;
            if (cnt > 0) {
                hm01 = q01 + pkrtz(me0, me1);
                hm23 = q23 + pkrtz(me2, me3);
                hl01 = q01 + u2h(mn0); hl23 = q23 + u2h(mn1);
                hh01 = q01 + u2h(mx0); hh23 = q23 + u2h(mx1);
            } else {
                half2v z = {(half_t)0, (half_t)0};
                hm01 = z; hm23 = z; hl01 = z; hl23 = z; hh01 = z; hh23 = z;
            }
            half2v hs01 = pkrtz(st0, st1);
            half2v hs23 = pkrtz(st2, st3);
            if (act) {
                // agg row layout: [t*64 + stat*16 + gf]; lane's features are
                // t = fl>>2, gf = (fl&3)*4 .. +3  -> byte t*128 + stat*32 + (fl&3)*8
                char* ab = aggc + (size_t)node * 512 + (fl >> 2) * 128 + (fl & 3) * 8;
                uint2 w0; w0.x = (unsigned)h2i(hm01); w0.y = (unsigned)h2i(hm23);
                uint2 w1; w1.x = (unsigned)h2i(hl01); w1.y = (unsigned)h2i(hl23);
                uint2 w2; w2.x = (unsigned)h2i(hh01); w2.y = (unsigned)h2i(hh23);
                uint2 w3; w3.x = (unsigned)h2i(hs01); w3.y = (unsigned)h2i(hs23);
                *(uint2*)(ab)      = w0;
                *(uint2*)(ab + 32) = w1;
                *(uint2*)(ab + 64) = w2;
                *(uint2*)(ab + 96) = w3;
                if (fl == 0) {
                    float ampv = __log2f(deg + 1.0f) * 0.24465054f;  // 1/log2(17)
                    ampA[node] = ampv;
                    rampA[node] = 1.0f / ampv;
                }
            }
        }
    }
}

// Persistent MFMA pass, swapped operands, x read as f16.
__global__ __launch_bounds__(256, 2) void k_c(
    const half_t* __restrict__ xh,
    const half_t* __restrict__ agg1, const half_t* __restrict__ agg2,
    const float* __restrict__ amp1, const float* __restrict__ ramp1,
    const float* __restrict__ amp2, const float* __restrict__ ramp2,
    const half_t* __restrict__ WLg, const half_t* __restrict__ WfinT,
    const float* __restrict__ bfin, float* __restrict__ out, int nN) {
    __shared__ half_t WLs[24 * 16 * 72];
    __shared__ half_t osb[4 * 16 * 72];
    int tid = threadIdx.x;
    {
        const uint4* src = (const uint4*)WLg;
        uint4* dst = (uint4*)WLs;
        for (int i = tid; i < (24 * 16 * 72) / 8; i += 256) dst[i] = src[i];
    }
    __syncthreads();
    int w = tid >> 6, lane = tid & 63;
    int l15 = lane & 15, g4 = lane >> 4;
    half_t* ow = osb + w * (16 * 72) + l15 * 72;
    half8 wfr[4][6];
#pragma unroll
    for (int ct = 0; ct < 4; ++ct)
#pragma unroll
        for (int kk = 0; kk < 6; ++kk)
            wfr[ct][kk] = *(const half8*)(WfinT + (ct * 16 + l15) * 192 + kk * 32 + g4 * 8);
    float4 bf4[4];
#pragma unroll
    for (int ct = 0; ct < 4; ++ct)
        bf4[ct] = *(const float4*)(bfin + ct * 16 + g4 * 4);
    int nwaves = gridDim.x * 4;
    int wgid = blockIdx.x * 4 + w;
    int ntiles = (nN + 15) >> 4;
    for (int tile = wgid; tile < ntiles; tile += nwaves) {
        int nrow = (tile << 4) + l15;
        int nrowc = (nrow < nN) ? nrow : (nN - 1);
        half8 xbf[2];
#pragma unroll
        for (int ks = 0; ks < 2; ++ks)
            xbf[ks] = *(const half8*)(xh + (size_t)nrowc * 64 + ks * 32 + g4 * 8);
        f32x4 accY[4] = {{0,0,0,0},{0,0,0,0},{0,0,0,0},{0,0,0,0}};
#pragma unroll
        for (int d = 0; d < 2; ++d) {
            const half_t* agg = d ? agg2 : agg1;
            float ampv = (d ? amp2 : amp1)[nrowc];
            float rampv = (d ? ramp2 : ramp1)[nrowc];
#pragma unroll
            for (int t = 0; t < 4; ++t) {
                half8 b0 = *(const half8*)(agg + (size_t)nrowc * 256 + t * 64 + g4 * 8);
                half8 b1 = *(const half8*)(agg + (size_t)nrowc * 256 + t * 64 + 32 + g4 * 8);
                const half_t* wb = WLs + ((d * 12 + t * 3) * 16 + l15) * 72 + g4 * 8;
                half8 aA0 = *(const half8*)(wb);
                half8 aA1 = *(const half8*)(wb + 32);
                half8 aB0 = *(const half8*)(wb + 16 * 72);
                half8 aB1 = *(const half8*)(wb + 16 * 72 + 32);
                half8 aE0 = *(const half8*)(wb + 32 * 72);
                half8 aE1 = *(const half8*)(wb + 32 * 72 + 32);
                f32x4 zA = {0,0,0,0}, zB = {0,0,0,0}, zE = {0,0,0,0};
                zA = __builtin_amdgcn_mfma_f32_16x16x32_f16(aA0, b0, zA, 0, 0, 0);
                zA = __builtin_amdgcn_mfma_f32_16x16x32_f16(aA1, b1, zA, 0, 0, 0);
                zB = __builtin_amdgcn_mfma_f32_16x16x32_f16(aB0, b0, zB, 0, 0, 0);
                zB = __builtin_amdgcn_mfma_f32_16x16x32_f16(aB1, b1, zB, 0, 0, 0);
                zE = __builtin_amdgcn_mfma_f32_16x16x32_f16(aE0, b0, zE, 0, 0, 0);
                zE = __builtin_amdgcn_mfma_f32_16x16x32_f16(aE1, b1, zE, 0, 0, 0);
                float o0 = zA[0] + ampv * zB[0] + rampv * zE[0];
                float o1 = zA[1] + ampv * zB[1] + rampv * zE[1];
                float o2 = zA[2] + ampv * zB[2] + rampv * zE[2];
                float o3 = zA[3] + ampv * zB[3] + rampv * zE[3];
                half2v p0; p0[0] = (half_t)o0; p0[1] = (half_t)o1;
                half2v p1; p1[0] = (half_t)o2; p1[1] = (half_t)o3;
                *(half2v*)(ow + t * 16 + g4 * 4) = p0;
                *(half2v*)(ow + t * 16 + g4 * 4 + 2) = p1;
            }
#pragma unroll
            for (int ks = 0; ks < 2; ++ks) {
                half8 ob = *(const half8*)(ow + ks * 32 + g4 * 8);
#pragma unroll
                for (int ct = 0; ct < 4; ++ct)
                    accY[ct] = __builtin_amdgcn_mfma_f32_16x16x32_f16(wfr[ct][d * 2 + ks], ob, accY[ct], 0, 0, 0);
            }
        }
#pragma unroll
        for (int ks = 0; ks < 2; ++ks)
#pragma unroll
            for (int ct = 0; ct < 4; ++ct)
                accY[ct] = __builtin_amdgcn_mfma_f32_16x16x32_f16(wfr[ct][4 + ks], xbf[ks], accY[ct], 0, 0, 0);
        if (nrow < nN) {
#pragma unroll
            for (int ct = 0; ct < 4; ++ct) {
                float4 st;
                st.x = accY[ct][0] + bf4[ct].x;
                st.y = accY[ct][1] + bf4[ct].y;
                st.z = accY[ct][2] + bf4[ct].z;
                st.w = accY[ct][3] + bf4[ct].w;
                *(float4*)(out + (size_t)nrow * 64 + ct * 16 + g4 * 4) = st;
            }
        }
    }
}

extern "C" void kernel_launch(void* const* d_in, const int* in_sizes, int n_in,
                              void* d_out, int out_size, void* d_ws, size_t ws_size,
                              hipStream_t stream) {
    const float* x      = (const float*)d_in[0];
    const int*   ei     = (const int*)d_in[1];
    const float* alpha  = (const float*)d_in[2];
    const float* Wself  = (const float*)d_in[3];
    const float* bself  = (const float*)d_in[4];
    const float* preW1  = (const float*)d_in[5];
    const float* preb1  = (const float*)d_in[6];
    const float* postW1 = (const float*)d_in[7];
    const float* postb1 = (const float*)d_in[8];
    const float* linW1  = (const float*)d_in[9];
    const float* linb1  = (const float*)d_in[10];
    const float* preW2  = (const float*)d_in[11];
    const float* preb2  = (const float*)d_in[12];
    const float* postW2 = (const float*)d_in[13];
    const float* postb2 = (const float*)d_in[14];
    const float* linW2  = (const float*)d_in[15];
    const float* linb2  = (const float*)d_in[16];
    float* out = (float*)d_out;
    const int nN = in_sizes[0] / 64;
    const int nE = in_sizes[1] / 2;
    const int nbuck = (nN + 255) >> 8;
    const int nH = nbuck * 256;
    const int nchunk = (nH + 1023) >> 10;

    char* w = (char*)d_ws;
    size_t ofs = 0;
    auto alloc = [&](size_t bytes) {
        char* p = w + ofs;
        ofs = (ofs + bytes + 255) & ~(size_t)255;
        return p;
    };
    half_t* P1   = (half_t*)alloc((size_t)nN * 64 * 2);
    half_t* P2   = (half_t*)alloc((size_t)nN * 64 * 2);
    half_t* Q1   = (half_t*)alloc((size_t)nN * 64 * 2);
    half_t* Q2   = (half_t*)alloc((size_t)nN * 64 * 2);
    half_t* xh   = (half_t*)alloc((size_t)nN * 64 * 2);
    half_t* agg1 = (half_t*)alloc((size_t)nN * 256 * 2);
    half_t* agg2 = (half_t*)alloc((size_t)nN * 256 * 2);
    float* amp1  = (float*)alloc((size_t)nN * 4);
    float* ramp1 = (float*)alloc((size_t)nN * 4);
    float* amp2  = (float*)alloc((size_t)nN * 4);
    float* ramp2 = (float*)alloc((size_t)nN * 4);
    half_t* WLg   = (half_t*)alloc(24 * 16 * 72 * 2);
    half_t* WfinT = (half_t*)alloc(64 * 192 * 2);
    float* bfin   = (float*)alloc(64 * 4);
    int* histD = (int*)alloc(256 * 256 * 4);
    int* histS = (int*)alloc(256 * 256 * 4);
    int* curD  = (int*)alloc((256 * 256 + 1) * 4);
    int* curS  = (int*)alloc((256 * 256 + 1) * 4);
    unsigned* binnedD = (unsigned*)alloc((size_t)nE * 4);
    unsigned* binnedS = (unsigned*)alloc((size_t)nE * 4);
    int* off_dst = (int*)alloc((size_t)(nN + 1) * 4);
    int* off_src = (int*)alloc((size_t)(nN + 1) * 4);
    unsigned short* adj_dst = (unsigned short*)alloc((size_t)nE * 2);
    unsigned short* adj_src = (unsigned short*)alloc((size_t)nE * 2);
    int* bsum = (int*)alloc(2 * 64 * 4);

    k_pre<<<1088, 256, 0, stream>>>(ei, nE, nN, histD, histS,
                                    postW1, postW2, linW1, linW2, Wself, bself,
                                    linb1, linb2, postb1, postb2, alpha,
                                    WLg, WfinT, bfin,
                                    x, preW1, preW2, preb1, preb2,
                                    P1, P2, Q1, Q2, xh);
    k_scanA<<<2 * nchunk, 256, 0, stream>>>(histD, histS, curD, curS, bsum, nH, nchunk);
    k_scanB<<<2 * nchunk, 256, 0, stream>>>(curD, curS, bsum, nH, nchunk);
    k_bin<<<256, 256, 0, stream>>>(ei, nE, nbuck, curD, curS, binnedD, binnedS);
    k_fine<<<2 * nbuck, 256, 0, stream>>>(binnedD, binnedS, curD, curS,
                                          off_dst, off_src, adj_dst, adj_src,
                                          nE, nN, nbuck);
    k_gather<<<2048, 256, 0, stream>>>(P1, P2, Q1, Q2, off_dst, adj_dst, off_src, adj_src,
                                       agg1, agg2, amp1, ramp1, amp2, ramp2, nN, nE);
    k_c<<<512, 256, 0, stream>>>(xh, agg1, agg2, amp1, ramp1, amp2, ramp2,
                                 WLg, WfinT, bfin, out, nN);
}